// Round 2
// baseline (1398.982 us; speedup 1.0000x reference)
//
#include <hip/hip_runtime.h>
#include <hip/hip_bf16.h>
#include <math.h>

#define BDIM 256

// ---------------------------------------------------------------- utilities

__global__ void fill_kernel(float* __restrict__ p, float v, int n) {
  int i = blockIdx.x * blockDim.x + threadIdx.x;
  if (i < n) p[i] = v;
}

__device__ __forceinline__ void atomicMaxFloat(float* addr, float v) {
  // Two-path trick: valid for IEEE754 with init to -large.
  if (v >= 0.0f)
    atomicMax((int*)addr, __float_as_int(v));
  else
    atomicMin((unsigned int*)addr, __float_as_uint(v));
}

// ---------------------------------------------------------------- GEMM
// C[N,KOUT] = A[N,KIN] @ W[KIN,KOUT], W staged to LDS.
template <int KIN, int KOUT>
__launch_bounds__(BDIM) __global__
void gemm_small(const float* __restrict__ A, const float* __restrict__ W,
                float* __restrict__ C, int N) {
  constexpr int ROWS = BDIM / KOUT;  // rows per block
  __shared__ float Wl[KIN * KOUT];
  __shared__ float Al[ROWS * KIN];
  for (int i = threadIdx.x; i < KIN * KOUT; i += BDIM) Wl[i] = W[i];
  int row0 = blockIdx.x * ROWS;
  for (int i = threadIdx.x; i < ROWS * KIN; i += BDIM) {
    int r = row0 + i / KIN;
    Al[i] = (r < N) ? A[(size_t)r * KIN + (i % KIN)] : 0.0f;
  }
  __syncthreads();
  int r = threadIdx.x / KOUT;
  int c = threadIdx.x % KOUT;
  int row = row0 + r;
  if (row >= N) return;
  float acc = 0.0f;
#pragma unroll
  for (int k = 0; k < KIN; ++k) acc += Al[r * KIN + k] * Wl[k * KOUT + c];
  C[(size_t)row * KOUT + c] = acc;
}

// ---------------------------------------------------------------- GCN
__global__ void deg_kernel(const int* __restrict__ ei, int E, int N,
                           float* __restrict__ deg) {
  int e = blockIdx.x * blockDim.x + threadIdx.x;
  int tot = E + N;
  if (e >= tot) return;
  int dst = (e < E) ? ei[E + e] : (e - E);
  atomicAdd(&deg[dst], 1.0f);
}

__global__ void rsqrt_kernel(float* __restrict__ deg, int N) {
  int i = blockIdx.x * blockDim.x + threadIdx.x;
  if (i < N) {
    float d = deg[i];
    deg[i] = (d > 0.0f) ? rsqrtf(fmaxf(d, 1e-12f)) : 0.0f;
  }
}

// wave per edge, lane = feature (64 features)
__global__ void gcn_scatter(const float* __restrict__ h, const int* __restrict__ ei,
                            int E, int N, const float* __restrict__ dis,
                            float* __restrict__ out) {
  int idx = blockIdx.x * (BDIM / 64) + (threadIdx.x >> 6);
  int f = threadIdx.x & 63;
  int tot = E + N;
  if (idx >= tot) return;
  int src, dst;
  if (idx < E) { src = ei[idx]; dst = ei[E + idx]; }
  else         { src = dst = idx - E; }
  float norm = dis[src] * dis[dst];
  atomicAdd(&out[(size_t)dst * 64 + f], h[(size_t)src * 64 + f] * norm);
}

// x[i] = act(x[i] + b[i & mask]); F power of two
__global__ void bias_act(float* __restrict__ x, const float* __restrict__ b,
                         int total, int mask, int do_relu) {
  int i = blockIdx.x * blockDim.x + threadIdx.x;
  if (i >= total) return;
  float v = x[i] + b[i & mask];
  if (do_relu) v = fmaxf(v, 0.0f);
  x[i] = v;
}

// ---------------------------------------------------------------- GAT
// wave per (node, head): reduce h[n,hd,:]*a_src and *a_dst
template <int HEADS>
__global__ void att_coef(const float* __restrict__ h,
                         const float* __restrict__ a_src,
                         const float* __restrict__ a_dst, int N,
                         float* __restrict__ al_s, float* __restrict__ al_d) {
  int wid = blockIdx.x * (BDIM / 64) + (threadIdx.x >> 6);
  int lane = threadIdx.x & 63;
  if (wid >= N * HEADS) return;
  int n = wid / HEADS, hd = wid % HEADS;
  float v = h[(size_t)n * (HEADS * 64) + hd * 64 + lane];
  float ps = v * a_src[hd * 64 + lane];
  float pd = v * a_dst[hd * 64 + lane];
#pragma unroll
  for (int off = 32; off > 0; off >>= 1) {
    ps += __shfl_down(ps, off, 64);
    pd += __shfl_down(pd, off, 64);
  }
  if (lane == 0) { al_s[wid] = ps; al_d[wid] = pd; }
}

__device__ __forceinline__ float leaky02(float v) {
  return v >= 0.0f ? v : 0.2f * v;
}

template <int HEADS>
__global__ void gat_max(const int* __restrict__ ei, int E, int N,
                        const float* __restrict__ al_s, const float* __restrict__ al_d,
                        float* __restrict__ emax) {
  int t = blockIdx.x * blockDim.x + threadIdx.x;
  int tot = (E + N) * HEADS;
  if (t >= tot) return;
  int e = t / HEADS, hd = t % HEADS;
  int src, dst;
  if (e < E) { src = ei[e]; dst = ei[E + e]; }
  else       { src = dst = e - E; }
  float v = leaky02(al_s[src * HEADS + hd] + al_d[dst * HEADS + hd]);
  atomicMaxFloat(&emax[dst * HEADS + hd], v);
}

template <int HEADS>
__global__ void gat_expsum(const int* __restrict__ ei, int E, int N,
                           const float* __restrict__ al_s, const float* __restrict__ al_d,
                           const float* __restrict__ emax, float* __restrict__ den) {
  int t = blockIdx.x * blockDim.x + threadIdx.x;
  int tot = (E + N) * HEADS;
  if (t >= tot) return;
  int e = t / HEADS, hd = t % HEADS;
  int src, dst;
  if (e < E) { src = ei[e]; dst = ei[E + e]; }
  else       { src = dst = e - E; }
  float v = leaky02(al_s[src * HEADS + hd] + al_d[dst * HEADS + hd]);
  atomicAdd(&den[dst * HEADS + hd], expf(v - emax[dst * HEADS + hd]));
}

// wave per (edge, head), lane = feature
template <int HEADS>
__global__ void gat_scatter(const float* __restrict__ h, const int* __restrict__ ei,
                            int E, int N, const float* __restrict__ al_s,
                            const float* __restrict__ al_d,
                            const float* __restrict__ emax, const float* __restrict__ den,
                            float* __restrict__ out) {
  int wid = blockIdx.x * (BDIM / 64) + (threadIdx.x >> 6);
  int lane = threadIdx.x & 63;
  int tot = (E + N) * HEADS;
  if (wid >= tot) return;
  int e = wid / HEADS, hd = wid % HEADS;
  int src, dst;
  if (e < E) { src = ei[e]; dst = ei[E + e]; }
  else       { src = dst = e - E; }
  float v = leaky02(al_s[src * HEADS + hd] + al_d[dst * HEADS + hd]);
  float alpha = expf(v - emax[dst * HEADS + hd]) / den[dst * HEADS + hd];
  atomicAdd(&out[(size_t)dst * (HEADS * 64) + hd * 64 + lane],
            h[(size_t)src * (HEADS * 64) + hd * 64 + lane] * alpha);
}

// ---------------------------------------------------------------- pool + head
__global__ void pool_kernel(const float* __restrict__ x3, const int* __restrict__ batch,
                            int N, float* __restrict__ pooled, float* __restrict__ cnts) {
  int wid = blockIdx.x * (BDIM / 64) + (threadIdx.x >> 6);
  int lane = threadIdx.x & 63;
  if (wid >= N) return;
  int g = batch[wid];
  atomicAdd(&pooled[(size_t)g * 64 + lane], x3[(size_t)wid * 64 + lane]);
  if (lane == 0) atomicAdd(&cnts[g], 1.0f);
}

__global__ void final_kernel(const float* __restrict__ pooled, const float* __restrict__ cnts,
                             const float* __restrict__ Wfc,
                             const float* __restrict__ bfc,
                             float* __restrict__ out, int G) {
  int wid = blockIdx.x * (BDIM / 64) + (threadIdx.x >> 6);
  int lane = threadIdx.x & 63;
  if (wid >= G) return;
  float c = fmaxf(cnts[wid], 1.0f);
  float p = pooled[(size_t)wid * 64 + lane] / c;
  float l0 = p * Wfc[lane * 2 + 0];
  float l1 = p * Wfc[lane * 2 + 1];
#pragma unroll
  for (int off = 32; off > 0; off >>= 1) {
    l0 += __shfl_down(l0, off, 64);
    l1 += __shfl_down(l1, off, 64);
  }
  if (lane == 0) {
    l0 += bfc[0];
    l1 += bfc[1];
    float m = fmaxf(l0, l1);
    float ls = m + logf(expf(l0 - m) + expf(l1 - m));
    out[wid * 2 + 0] = l0 - ls;
    out[wid * 2 + 1] = l1 - ls;
  }
}

// ---------------------------------------------------------------- launch

static inline int cdiv(int a, int b) { return (a + b - 1) / b; }

extern "C" void kernel_launch(void* const* d_in, const int* in_sizes, int n_in,
                              void* d_out, int out_size, void* d_ws, size_t ws_size,
                              hipStream_t stream) {
  const float* x      = (const float*)d_in[0];
  const int*   ei     = (const int*)d_in[1];
  const int*   batch  = (const int*)d_in[2];
  const float* W1     = (const float*)d_in[3];
  const float* b1     = (const float*)d_in[4];
  const float* W2     = (const float*)d_in[5];
  const float* a_src2 = (const float*)d_in[6];
  const float* a_dst2 = (const float*)d_in[7];
  const float* b2     = (const float*)d_in[8];
  const float* W3     = (const float*)d_in[9];
  const float* a_src3 = (const float*)d_in[10];
  const float* a_dst3 = (const float*)d_in[11];
  const float* b3     = (const float*)d_in[12];
  const float* Wfc    = (const float*)d_in[13];
  const float* bfc    = (const float*)d_in[14];
  float* out = (float*)d_out;

  const int N = in_sizes[2];       // 50000
  const int E = in_sizes[1] / 2;   // 800000
  const int G = out_size / 2;      // 512
  const int TOT = E + N;           // edges incl. self-loops

  // workspace layout (floats): 2*N*128 + N + 8*N + G*65  ~= 53 MB
  float* ws = (float*)d_ws;
  float* P0     = ws;                       // N*128
  float* P1     = P0 + (size_t)N * 128;     // N*128
  float* deg    = P1 + (size_t)N * 128;     // N (becomes dis)
  float* al_s   = deg + N;                  // N*2
  float* al_d   = al_s + (size_t)N * 2;     // N*2
  float* emax   = al_d + (size_t)N * 2;     // N*2
  float* den    = emax + (size_t)N * 2;     // N*2
  float* pooled = den + (size_t)N * 2;      // G*64
  float* cnts   = pooled + (size_t)G * 64;  // G

  float* h1   = P0;                    // N*64
  float* out1 = P0 + (size_t)N * 64;   // N*64 -> x1 (post relu)

  // ---- GCN layer
  gemm_small<128, 64><<<cdiv(N, 4), BDIM, 0, stream>>>(x, W1, h1, N);
  fill_kernel<<<cdiv(N, BDIM), BDIM, 0, stream>>>(deg, 0.0f, N);
  deg_kernel<<<cdiv(TOT, BDIM), BDIM, 0, stream>>>(ei, E, N, deg);
  rsqrt_kernel<<<cdiv(N, BDIM), BDIM, 0, stream>>>(deg, N);
  fill_kernel<<<cdiv(N * 64, BDIM), BDIM, 0, stream>>>(out1, 0.0f, N * 64);
  gcn_scatter<<<cdiv(TOT, 4), BDIM, 0, stream>>>(h1, ei, E, N, deg, out1);
  bias_act<<<cdiv(N * 64, BDIM), BDIM, 0, stream>>>(out1, b1, N * 64, 63, 1);
  // x1 = out1

  // ---- GAT layer 1 (heads=2, concat)
  float* h2   = P1;  // N*128
  float* out2 = P0;  // N*128 (x1 region is consumed by the gemm below first)
  gemm_small<64, 128><<<cdiv(N, 2), BDIM, 0, stream>>>(out1, W2, h2, N);
  att_coef<2><<<cdiv(N * 2, 4), BDIM, 0, stream>>>(h2, a_src2, a_dst2, N, al_s, al_d);
  fill_kernel<<<cdiv(N * 2, BDIM), BDIM, 0, stream>>>(emax, -1e30f, N * 2);
  fill_kernel<<<cdiv(N * 2, BDIM), BDIM, 0, stream>>>(den, 0.0f, N * 2);
  gat_max<2><<<cdiv(TOT * 2, BDIM), BDIM, 0, stream>>>(ei, E, N, al_s, al_d, emax);
  gat_expsum<2><<<cdiv(TOT * 2, BDIM), BDIM, 0, stream>>>(ei, E, N, al_s, al_d, emax, den);
  fill_kernel<<<cdiv(N * 128, BDIM), BDIM, 0, stream>>>(out2, 0.0f, N * 128);
  gat_scatter<2><<<cdiv(TOT * 2, 4), BDIM, 0, stream>>>(h2, ei, E, N, al_s, al_d, emax, den, out2);
  bias_act<<<cdiv(N * 128, BDIM), BDIM, 0, stream>>>(out2, b2, N * 128, 127, 1);
  // x2 = out2 (N*128)

  // ---- GAT layer 2 (heads=1, average == identity)
  float* h3   = P1;                    // N*64 (h2 dead)
  float* out3 = P1 + (size_t)N * 64;   // N*64
  gemm_small<128, 64><<<cdiv(N, 4), BDIM, 0, stream>>>(out2, W3, h3, N);
  att_coef<1><<<cdiv(N, 4), BDIM, 0, stream>>>(h3, a_src3, a_dst3, N, al_s, al_d);
  fill_kernel<<<cdiv(N, BDIM), BDIM, 0, stream>>>(emax, -1e30f, N);
  fill_kernel<<<cdiv(N, BDIM), BDIM, 0, stream>>>(den, 0.0f, N);
  gat_max<1><<<cdiv(TOT, BDIM), BDIM, 0, stream>>>(ei, E, N, al_s, al_d, emax);
  gat_expsum<1><<<cdiv(TOT, BDIM), BDIM, 0, stream>>>(ei, E, N, al_s, al_d, emax, den);
  fill_kernel<<<cdiv(N * 64, BDIM), BDIM, 0, stream>>>(out3, 0.0f, N * 64);
  gat_scatter<1><<<cdiv(TOT, 4), BDIM, 0, stream>>>(h3, ei, E, N, al_s, al_d, emax, den, out3);
  bias_act<<<cdiv(N * 64, BDIM), BDIM, 0, stream>>>(out3, b3, N * 64, 63, 0);
  // x3 = out3

  // ---- global mean pool + fc + log_softmax
  fill_kernel<<<cdiv(G * 65, BDIM), BDIM, 0, stream>>>(pooled, 0.0f, G * 65);  // pooled+cnts contiguous
  pool_kernel<<<cdiv(N, 4), BDIM, 0, stream>>>(out3, batch, N, pooled, cnts);
  final_kernel<<<cdiv(G, 4), BDIM, 0, stream>>>(pooled, cnts, Wfc, bfc, out, G);
}

// Round 3
// 732.847 us; speedup vs baseline: 1.9090x; 1.9090x over previous
//
#include <hip/hip_runtime.h>
#include <hip/hip_bf16.h>
#include <math.h>

#define BDIM 256

// ---------------------------------------------------------------- utilities

__global__ void fill_kernel(float* __restrict__ p, float v, int n) {
  int i = blockIdx.x * blockDim.x + threadIdx.x;
  if (i < n) p[i] = v;
}

__global__ void fill_int_kernel(int* __restrict__ p, int v, int n) {
  int i = blockIdx.x * blockDim.x + threadIdx.x;
  if (i < n) p[i] = v;
}

// ---------------------------------------------------------------- GEMM
// C[N,KOUT] = A[N,KIN] @ W[KIN,KOUT], W staged to LDS.
template <int KIN, int KOUT>
__launch_bounds__(BDIM) __global__
void gemm_small(const float* __restrict__ A, const float* __restrict__ W,
                float* __restrict__ C, int N) {
  constexpr int ROWS = BDIM / KOUT;  // rows per block
  __shared__ float Wl[KIN * KOUT];
  __shared__ float Al[ROWS * KIN];
  for (int i = threadIdx.x; i < KIN * KOUT; i += BDIM) Wl[i] = W[i];
  int row0 = blockIdx.x * ROWS;
  for (int i = threadIdx.x; i < ROWS * KIN; i += BDIM) {
    int r = row0 + i / KIN;
    Al[i] = (r < N) ? A[(size_t)r * KIN + (i % KIN)] : 0.0f;
  }
  __syncthreads();
  int r = threadIdx.x / KOUT;
  int c = threadIdx.x % KOUT;
  int row = row0 + r;
  if (row >= N) return;
  float acc = 0.0f;
#pragma unroll
  for (int k = 0; k < KIN; ++k) acc += Al[r * KIN + k] * Wl[k * KOUT + c];
  C[(size_t)row * KOUT + c] = acc;
}

// ---------------------------------------------------------------- CSR build
// cnt[dst]++ over all edges incl. self-loops
__global__ void count_kernel(const int* __restrict__ ei, int E, int N,
                             int* __restrict__ cnt) {
  int t = blockIdx.x * blockDim.x + threadIdx.x;
  if (t >= E + N) return;
  int dst = (t < E) ? ei[E + t] : (t - E);
  atomicAdd(&cnt[dst], 1);
}

// dis[i] = 1/sqrt(deg) (deg >= 1 always: self-loops)
__global__ void dis_kernel(const int* __restrict__ cnt, float* __restrict__ dis, int N) {
  int i = blockIdx.x * blockDim.x + threadIdx.x;
  if (i < N) {
    float d = (float)cnt[i];
    dis[i] = (d > 0.0f) ? rsqrtf(fmaxf(d, 1e-12f)) : 0.0f;
  }
}

// single-workgroup hierarchical exclusive scan: cnt[N] -> row_ptr[N+1], cursor[N]
__launch_bounds__(1024) __global__
void scan_kernel(const int* __restrict__ cnt, int N,
                 int* __restrict__ row_ptr, int* __restrict__ cursor) {
  __shared__ int wsum[16], wpre[16];
  __shared__ int carry_s;
  int tid = threadIdx.x, lane = tid & 63, w = tid >> 6;
  if (tid == 0) carry_s = 0;
  __syncthreads();
  for (int base = 0; base < N; base += 1024) {
    int i = base + tid;
    int v = (i < N) ? cnt[i] : 0;
    int incl = v;
#pragma unroll
    for (int off = 1; off < 64; off <<= 1) {
      int t = __shfl_up(incl, off, 64);
      if (lane >= off) incl += t;
    }
    if (lane == 63) wsum[w] = incl;
    __syncthreads();
    if (w == 0 && lane < 16) {
      int s = wsum[lane];
#pragma unroll
      for (int off = 1; off < 16; off <<= 1) {
        int t = __shfl_up(s, off, 64);
        if (lane >= off) s += t;
      }
      wpre[lane] = s - wsum[lane];
    }
    __syncthreads();
    int c = carry_s;
    int excl = c + wpre[w] + incl - v;
    if (i < N) { row_ptr[i] = excl; cursor[i] = excl; }
    __syncthreads();
    if (tid == 1023) carry_s = c + wpre[15] + wsum[15];
    __syncthreads();
  }
  if (tid == 0) row_ptr[N] = carry_s;
}

// scatter edge sources into CSR slots (int atomics on cursors only)
__global__ void csr_fill(const int* __restrict__ ei, int E, int N,
                         int* __restrict__ cursor, int* __restrict__ csr_src) {
  int t = blockIdx.x * blockDim.x + threadIdx.x;
  if (t >= E + N) return;
  int src, dst;
  if (t < E) { src = ei[t]; dst = ei[E + t]; }
  else       { src = dst = t - E; }
  int slot = atomicAdd(&cursor[dst], 1);
  csr_src[slot] = src;
}

// ---------------------------------------------------------------- GCN gather
// wave per dst node, lane = feature; out = relu(dis[dst]*sum(h[src]*dis[src]) + b)
__launch_bounds__(BDIM) __global__
void gcn_gather(const float* __restrict__ h, const int* __restrict__ row_ptr,
                const int* __restrict__ csr_src, const float* __restrict__ dis,
                const float* __restrict__ b, float* __restrict__ out, int N) {
  int wid = blockIdx.x * (BDIM / 64) + (threadIdx.x >> 6);
  int lane = threadIdx.x & 63;
  if (wid >= N) return;
  int beg = row_ptr[wid], end = row_ptr[wid + 1];
  float acc = 0.0f;
  for (int base = beg; base < end; base += 64) {
    int nch = min(64, end - base);
    int   s_l = (lane < nch) ? csr_src[base + lane] : 0;
    float d_l = (lane < nch) ? dis[s_l] : 0.0f;
    for (int j = 0; j < nch; ++j) {
      int   s  = __shfl(s_l, j, 64);
      float ds = __shfl(d_l, j, 64);
      acc += h[(size_t)s * 64 + lane] * ds;
    }
  }
  float v = acc * dis[wid] + b[lane];
  out[(size_t)wid * 64 + lane] = fmaxf(v, 0.0f);
}

// ---------------------------------------------------------------- GAT
// wave per (node, head): al_s/al_d coefficients
template <int HEADS>
__global__ void att_coef(const float* __restrict__ h,
                         const float* __restrict__ a_src,
                         const float* __restrict__ a_dst, int N,
                         float* __restrict__ al_s, float* __restrict__ al_d) {
  int wid = blockIdx.x * (BDIM / 64) + (threadIdx.x >> 6);
  int lane = threadIdx.x & 63;
  if (wid >= N * HEADS) return;
  int n = wid / HEADS, hd = wid % HEADS;
  float v = h[(size_t)n * (HEADS * 64) + hd * 64 + lane];
  float ps = v * a_src[hd * 64 + lane];
  float pd = v * a_dst[hd * 64 + lane];
#pragma unroll
  for (int off = 32; off > 0; off >>= 1) {
    ps += __shfl_down(ps, off, 64);
    pd += __shfl_down(pd, off, 64);
  }
  if (lane == 0) { al_s[wid] = ps; al_d[wid] = pd; }
}

__device__ __forceinline__ float leaky02(float v) {
  return v >= 0.0f ? v : 0.2f * v;
}

// wave per (dst, head), lane = feature; online-softmax gather, bias/relu fused
template <int HEADS>
__launch_bounds__(BDIM) __global__
void gat_gather(const float* __restrict__ h, const int* __restrict__ row_ptr,
                const int* __restrict__ csr_src,
                const float* __restrict__ al_s, const float* __restrict__ al_d,
                const float* __restrict__ b, float* __restrict__ out, int N,
                int relu) {
  int wid = blockIdx.x * (BDIM / 64) + (threadIdx.x >> 6);
  int lane = threadIdx.x & 63;
  if (wid >= N * HEADS) return;
  int dn = wid / HEADS, hd = wid % HEADS;
  float ad = al_d[dn * HEADS + hd];
  int beg = row_ptr[dn], end = row_ptr[dn + 1];
  float m = -3.4e38f, l = 0.0f, acc = 0.0f;
  for (int base = beg; base < end; base += 64) {
    int nch = min(64, end - base);
    int   s_l  = (lane < nch) ? csr_src[base + lane] : 0;
    float as_l = (lane < nch) ? al_s[s_l * HEADS + hd] : 0.0f;
    for (int j = 0; j < nch; ++j) {
      int   s = __shfl(s_l, j, 64);
      float e = leaky02(__shfl(as_l, j, 64) + ad);
      float hv = h[(size_t)s * (HEADS * 64) + hd * 64 + lane];
      float mn = fmaxf(m, e);
      float sc = expf(m - mn);   // first iter: exp(-inf) = 0
      float wgt = expf(e - mn);
      l = l * sc + wgt;
      acc = acc * sc + wgt * hv;
      m = mn;
    }
  }
  float v = acc / l + b[hd * 64 + lane];
  if (relu) v = fmaxf(v, 0.0f);
  out[(size_t)dn * (HEADS * 64) + hd * 64 + lane] = v;
}

// ---------------------------------------------------------------- pool + head
__global__ void pool_kernel(const float* __restrict__ x3, const int* __restrict__ batch,
                            int N, float* __restrict__ pooled, float* __restrict__ cnts) {
  int wid = blockIdx.x * (BDIM / 64) + (threadIdx.x >> 6);
  int lane = threadIdx.x & 63;
  if (wid >= N) return;
  int g = batch[wid];
  atomicAdd(&pooled[(size_t)g * 64 + lane], x3[(size_t)wid * 64 + lane]);
  if (lane == 0) atomicAdd(&cnts[g], 1.0f);
}

__global__ void final_kernel(const float* __restrict__ pooled, const float* __restrict__ cnts,
                             const float* __restrict__ Wfc,
                             const float* __restrict__ bfc,
                             float* __restrict__ out, int G) {
  int wid = blockIdx.x * (BDIM / 64) + (threadIdx.x >> 6);
  int lane = threadIdx.x & 63;
  if (wid >= G) return;
  float c = fmaxf(cnts[wid], 1.0f);
  float p = pooled[(size_t)wid * 64 + lane] / c;
  float l0 = p * Wfc[lane * 2 + 0];
  float l1 = p * Wfc[lane * 2 + 1];
#pragma unroll
  for (int off = 32; off > 0; off >>= 1) {
    l0 += __shfl_down(l0, off, 64);
    l1 += __shfl_down(l1, off, 64);
  }
  if (lane == 0) {
    l0 += bfc[0];
    l1 += bfc[1];
    float m = fmaxf(l0, l1);
    float ls = m + logf(expf(l0 - m) + expf(l1 - m));
    out[wid * 2 + 0] = l0 - ls;
    out[wid * 2 + 1] = l1 - ls;
  }
}

// ---------------------------------------------------------------- launch

static inline int cdiv(int a, int b) { return (a + b - 1) / b; }

extern "C" void kernel_launch(void* const* d_in, const int* in_sizes, int n_in,
                              void* d_out, int out_size, void* d_ws, size_t ws_size,
                              hipStream_t stream) {
  const float* x      = (const float*)d_in[0];
  const int*   ei     = (const int*)d_in[1];
  const int*   batch  = (const int*)d_in[2];
  const float* W1     = (const float*)d_in[3];
  const float* b1     = (const float*)d_in[4];
  const float* W2     = (const float*)d_in[5];
  const float* a_src2 = (const float*)d_in[6];
  const float* a_dst2 = (const float*)d_in[7];
  const float* b2     = (const float*)d_in[8];
  const float* W3     = (const float*)d_in[9];
  const float* a_src3 = (const float*)d_in[10];
  const float* a_dst3 = (const float*)d_in[11];
  const float* b3     = (const float*)d_in[12];
  const float* Wfc    = (const float*)d_in[13];
  const float* bfc    = (const float*)d_in[14];
  float* out = (float*)d_out;

  const int N = in_sizes[2];       // 50000
  const int E = in_sizes[1] / 2;   // 800000
  const int G = out_size / 2;      // 512
  const int TOT = E + N;           // edges incl. self-loops

  // workspace layout: floats then ints, ~56.3 MB total
  float* ws = (float*)d_ws;
  float* P0     = ws;                        // N*128
  float* P1     = P0 + (size_t)N * 128;      // N*128
  float* dis    = P1 + (size_t)N * 128;      // N
  float* al_s   = dis + N;                   // N*2
  float* al_d   = al_s + (size_t)N * 2;      // N*2
  float* pooled = al_d + (size_t)N * 2;      // G*64
  float* cnts   = pooled + (size_t)G * 64;   // G
  int*   cnt     = (int*)(cnts + G);         // N
  int*   row_ptr = cnt + N;                  // N+1
  int*   cursor  = row_ptr + N + 1;          // N
  int*   csr_src = cursor + N;               // E+N

  float* h1   = P0;                    // N*64
  float* out1 = P0 + (size_t)N * 64;   // N*64 -> x1 (post relu)

  // ---- CSR build (reused by all three layers)
  fill_int_kernel<<<cdiv(N, BDIM), BDIM, 0, stream>>>(cnt, 0, N);
  count_kernel<<<cdiv(TOT, BDIM), BDIM, 0, stream>>>(ei, E, N, cnt);
  dis_kernel<<<cdiv(N, BDIM), BDIM, 0, stream>>>(cnt, dis, N);
  scan_kernel<<<1, 1024, 0, stream>>>(cnt, N, row_ptr, cursor);
  csr_fill<<<cdiv(TOT, BDIM), BDIM, 0, stream>>>(ei, E, N, cursor, csr_src);

  // ---- GCN layer (gather, fused bias+relu)
  gemm_small<128, 64><<<cdiv(N, 4), BDIM, 0, stream>>>(x, W1, h1, N);
  gcn_gather<<<cdiv(N, 4), BDIM, 0, stream>>>(h1, row_ptr, csr_src, dis, b1, out1, N);
  // x1 = out1

  // ---- GAT layer 1 (heads=2, concat; online softmax gather)
  float* h2   = P1;  // N*128
  float* out2 = P0;  // N*128 (x1 region consumed by the gemm first)
  gemm_small<64, 128><<<cdiv(N, 2), BDIM, 0, stream>>>(out1, W2, h2, N);
  att_coef<2><<<cdiv(N * 2, 4), BDIM, 0, stream>>>(h2, a_src2, a_dst2, N, al_s, al_d);
  gat_gather<2><<<cdiv(N * 2, 4), BDIM, 0, stream>>>(h2, row_ptr, csr_src, al_s, al_d,
                                                     b2, out2, N, 1);
  // x2 = out2 (N*128)

  // ---- GAT layer 2 (heads=1, mean == identity)
  float* h3   = P1;                    // N*64 (h2 dead)
  float* out3 = P1 + (size_t)N * 64;   // N*64
  gemm_small<128, 64><<<cdiv(N, 4), BDIM, 0, stream>>>(out2, W3, h3, N);
  att_coef<1><<<cdiv(N, 4), BDIM, 0, stream>>>(h3, a_src3, a_dst3, N, al_s, al_d);
  gat_gather<1><<<cdiv(N, 4), BDIM, 0, stream>>>(h3, row_ptr, csr_src, al_s, al_d,
                                                 b3, out3, N, 0);
  // x3 = out3

  // ---- global mean pool + fc + log_softmax
  fill_kernel<<<cdiv(G * 65, BDIM), BDIM, 0, stream>>>(pooled, 0.0f, G * 65);
  pool_kernel<<<cdiv(N, 4), BDIM, 0, stream>>>(out3, batch, N, pooled, cnts);
  final_kernel<<<cdiv(G, 4), BDIM, 0, stream>>>(pooled, cnts, Wfc, bfc, out, G);
}

// Round 4
// 702.693 us; speedup vs baseline: 1.9909x; 1.0429x over previous
//
#include <hip/hip_runtime.h>
#include <hip/hip_bf16.h>
#include <hip/hip_fp16.h>
#include <math.h>

#define BDIM 256

// ---------------------------------------------------------------- utilities

__global__ void fill_int_kernel(int* __restrict__ p, int v, int n) {
  int i = blockIdx.x * blockDim.x + threadIdx.x;
  if (i < n) p[i] = v;
}

__device__ __forceinline__ float wave_max64(float v) {
#pragma unroll
  for (int o = 32; o > 0; o >>= 1) v = fmaxf(v, __shfl_xor(v, o, 64));
  return v;
}
__device__ __forceinline__ float wave_sum64(float v) {
#pragma unroll
  for (int o = 32; o > 0; o >>= 1) v += __shfl_xor(v, o, 64);
  return v;
}

__device__ __forceinline__ void store_o(float v, float* p) { *p = v; }
__device__ __forceinline__ void store_o(float v, __half* p) { *p = __float2half(v); }

__device__ __forceinline__ float leaky02(float v) {
  return v >= 0.0f ? v : 0.2f * v;
}

// ---------------------------------------------------------------- GEMM
// C[N,KOUT] = A[N,KIN] @ W[KIN,KOUT]; W and an A-tile staged to LDS.
template <int KIN, int KOUT, typename OT>
__launch_bounds__(BDIM) __global__
void gemm_small(const float* __restrict__ A, const float* __restrict__ W,
                OT* __restrict__ C, int N) {
  constexpr int ROWS = BDIM / KOUT;
  __shared__ float Wl[KIN * KOUT];
  __shared__ float Al[ROWS * KIN];
  for (int i = threadIdx.x; i < KIN * KOUT; i += BDIM) Wl[i] = W[i];
  int row0 = blockIdx.x * ROWS;
  for (int i = threadIdx.x; i < ROWS * KIN; i += BDIM) {
    int r = row0 + i / KIN;
    Al[i] = (r < N) ? A[(size_t)r * KIN + (i % KIN)] : 0.0f;
  }
  __syncthreads();
  int r = threadIdx.x / KOUT;
  int c = threadIdx.x % KOUT;
  int row = row0 + r;
  if (row >= N) return;
  float acc = 0.0f;
#pragma unroll
  for (int k = 0; k < KIN; ++k) acc += Al[r * KIN + k] * Wl[k * KOUT + c];
  store_o(acc, &C[(size_t)row * KOUT + c]);
}

// ---------------------------------------------------------------- CSR build
__global__ void count_kernel(const int* __restrict__ ei, int E, int N,
                             int* __restrict__ cnt) {
  int t = blockIdx.x * blockDim.x + threadIdx.x;
  if (t >= E + N) return;
  int dst = (t < E) ? ei[E + t] : (t - E);
  atomicAdd(&cnt[dst], 1);
}

__global__ void dis_kernel(const int* __restrict__ cnt, float* __restrict__ dis, int N) {
  int i = blockIdx.x * blockDim.x + threadIdx.x;
  if (i < N) {
    float d = (float)cnt[i];
    dis[i] = (d > 0.0f) ? rsqrtf(fmaxf(d, 1e-12f)) : 0.0f;
  }
}

// single-workgroup hierarchical exclusive scan: cnt[N] -> row_ptr[N+1], cursor[N]
__launch_bounds__(1024) __global__
void scan_kernel(const int* __restrict__ cnt, int N,
                 int* __restrict__ row_ptr, int* __restrict__ cursor) {
  __shared__ int wsum[16], wpre[16];
  __shared__ int carry_s;
  int tid = threadIdx.x, lane = tid & 63, w = tid >> 6;
  if (tid == 0) carry_s = 0;
  __syncthreads();
  for (int base = 0; base < N; base += 1024) {
    int i = base + tid;
    int v = (i < N) ? cnt[i] : 0;
    int incl = v;
#pragma unroll
    for (int off = 1; off < 64; off <<= 1) {
      int t = __shfl_up(incl, off, 64);
      if (lane >= off) incl += t;
    }
    if (lane == 63) wsum[w] = incl;
    __syncthreads();
    if (w == 0 && lane < 16) {
      int s = wsum[lane];
#pragma unroll
      for (int off = 1; off < 16; off <<= 1) {
        int t = __shfl_up(s, off, 64);
        if (lane >= off) s += t;
      }
      wpre[lane] = s - wsum[lane];
    }
    __syncthreads();
    int c = carry_s;
    int excl = c + wpre[w] + incl - v;
    if (i < N) { row_ptr[i] = excl; cursor[i] = excl; }
    __syncthreads();
    if (tid == 1023) carry_s = c + wpre[15] + wsum[15];
    __syncthreads();
  }
  if (tid == 0) row_ptr[N] = carry_s;
}

// scatter sources into CSR slots; also precompute GCN edge weight dis[s]*dis[d]
__global__ void csr_fill(const int* __restrict__ ei, int E, int N,
                         const float* __restrict__ dis,
                         int* __restrict__ cursor, int* __restrict__ csr_src,
                         float* __restrict__ wgcn) {
  int t = blockIdx.x * blockDim.x + threadIdx.x;
  if (t >= E + N) return;
  int src, dst;
  if (t < E) { src = ei[t]; dst = ei[E + t]; }
  else       { src = dst = t - E; }
  int slot = atomicAdd(&cursor[dst], 1);
  csr_src[slot] = src;
  wgcn[slot] = dis[src] * dis[dst];
}

// ---------------------------------------------------------------- GCN gather
// wave per dst node, lane = feature; out = relu(sum(w_e * h[src]) + b)
__launch_bounds__(BDIM) __global__
void gcn_gather(const __half* __restrict__ h, const int* __restrict__ row_ptr,
                const int* __restrict__ csr_src, const float* __restrict__ w,
                const float* __restrict__ b, float* __restrict__ out, int N) {
  int wid = blockIdx.x * (BDIM / 64) + (threadIdx.x >> 6);
  int lane = threadIdx.x & 63;
  if (wid >= N) return;
  int beg = row_ptr[wid], end = row_ptr[wid + 1];
  float acc = 0.0f;
  for (int base = beg; base < end; base += 64) {
    int nch = min(64, end - base);
    int   s_l = (lane < nch) ? csr_src[base + lane] : 0;
    float w_l = (lane < nch) ? w[base + lane] : 0.0f;
    for (int j = 0; j < nch; ++j) {
      int   s  = __shfl(s_l, j, 64);
      float ww = __shfl(w_l, j, 64);
      acc += ww * __half2float(h[(size_t)s * 64 + lane]);
    }
  }
  out[(size_t)wid * 64 + lane] = fmaxf(acc + b[lane], 0.0f);
}

// ---------------------------------------------------------------- GAT
// wave per (node, head): attention coefficients; planar outputs al[hd*N + n]
template <int HEADS>
__launch_bounds__(BDIM) __global__
void att_coef(const __half* __restrict__ h, const float* __restrict__ a_src,
              const float* __restrict__ a_dst, int N,
              float* __restrict__ al_s, float* __restrict__ al_d) {
  int wid = blockIdx.x * (BDIM / 64) + (threadIdx.x >> 6);
  int lane = threadIdx.x & 63;
  if (wid >= N * HEADS) return;
  int n = wid % N, hd = wid / N;
  float v = __half2float(h[(size_t)n * (HEADS * 64) + hd * 64 + lane]);
  float ps = wave_sum64(v * a_src[hd * 64 + lane]);
  float pd = wave_sum64(v * a_dst[hd * 64 + lane]);
  if (lane == 0) { al_s[hd * N + n] = ps; al_d[hd * N + n] = pd; }
}

// wave per (dst, head): segment softmax -> unnormalized alpha per edge + den per dst
template <int HEADS>
__launch_bounds__(BDIM) __global__
void gat_alpha(const int* __restrict__ row_ptr, const int* __restrict__ csr_src,
               const float* __restrict__ al_s, const float* __restrict__ al_d,
               float* __restrict__ alpha, float* __restrict__ den, int N, int TOT) {
  int wid = blockIdx.x * (BDIM / 64) + (threadIdx.x >> 6);
  int lane = threadIdx.x & 63;
  if (wid >= N * HEADS) return;
  int dn = wid % N, hd = wid / N;
  const float* als_p = al_s + (size_t)hd * N;
  float ad = al_d[(size_t)hd * N + dn];
  float* alpha_p = alpha + (size_t)hd * TOT;
  int beg = row_ptr[dn], end = row_ptr[dn + 1];
  int deg = end - beg;
  if (deg <= 64) {  // common case: whole segment in one wave pass
    int   s = (lane < deg) ? csr_src[beg + lane] : 0;
    float e = (lane < deg) ? leaky02(als_p[s] + ad) : -3.4e38f;
    float m = wave_max64(e);
    float ex = (lane < deg) ? expf(e - m) : 0.0f;
    float l = wave_sum64(ex);
    if (lane < deg) alpha_p[beg + lane] = ex;
    if (lane == 0) den[(size_t)hd * N + dn] = l;
  } else {
    float m = -3.4e38f;
    for (int base = beg; base < end; base += 64) {
      int nch = min(64, end - base);
      int   s = (lane < nch) ? csr_src[base + lane] : 0;
      float e = (lane < nch) ? leaky02(als_p[s] + ad) : -3.4e38f;
      m = fmaxf(m, wave_max64(e));
    }
    float l = 0.0f;
    for (int base = beg; base < end; base += 64) {
      int nch = min(64, end - base);
      int   s = (lane < nch) ? csr_src[base + lane] : 0;
      float e = (lane < nch) ? leaky02(als_p[s] + ad) : -3.4e38f;
      float ex = (lane < nch) ? expf(e - m) : 0.0f;
      if (lane < nch) alpha_p[base + lane] = ex;
      l += wave_sum64(ex);
    }
    if (lane == 0) den[(size_t)hd * N + dn] = l;
  }
}

// wave per (dst, head), lane = feature; acc += alpha_e * h[src]; /den, +b, relu
template <int HEADS>
__launch_bounds__(BDIM) __global__
void gat_acc(const __half* __restrict__ h, const int* __restrict__ row_ptr,
             const int* __restrict__ csr_src, const float* __restrict__ alpha,
             const float* __restrict__ den, const float* __restrict__ b,
             float* __restrict__ out, int N, int TOT, int relu) {
  int wid = blockIdx.x * (BDIM / 64) + (threadIdx.x >> 6);
  int lane = threadIdx.x & 63;
  if (wid >= N * HEADS) return;
  int dn = wid % N, hd = wid / N;
  const float* alpha_p = alpha + (size_t)hd * TOT;
  int beg = row_ptr[dn], end = row_ptr[dn + 1];
  float acc = 0.0f;
  for (int base = beg; base < end; base += 64) {
    int nch = min(64, end - base);
    int   s_l = (lane < nch) ? csr_src[base + lane] : 0;
    float a_l = (lane < nch) ? alpha_p[base + lane] : 0.0f;
    for (int j = 0; j < nch; ++j) {
      int   s = __shfl(s_l, j, 64);
      float a = __shfl(a_l, j, 64);
      acc += a * __half2float(h[(size_t)s * (HEADS * 64) + hd * 64 + lane]);
    }
  }
  float v = acc / den[(size_t)hd * N + dn] + b[hd * 64 + lane];
  if (relu) v = fmaxf(v, 0.0f);
  out[(size_t)dn * (HEADS * 64) + hd * 64 + lane] = v;
}

// ---------------------------------------------------------------- pool + head
__device__ __forceinline__ int lower_bound(const int* __restrict__ a, int n, int v) {
  int lo = 0, hi = n;
  while (lo < hi) {
    int mid = (lo + hi) >> 1;
    if (a[mid] < v) lo = mid + 1; else hi = mid;
  }
  return lo;
}

// wave per graph: batch is sorted -> contiguous node range; no atomics
__launch_bounds__(BDIM) __global__
void pool_final(const float* __restrict__ x3, const int* __restrict__ batch,
                const float* __restrict__ Wfc, const float* __restrict__ bfc,
                float* __restrict__ out, int N, int G) {
  int wid = blockIdx.x * (BDIM / 64) + (threadIdx.x >> 6);
  int lane = threadIdx.x & 63;
  if (wid >= G) return;
  int beg = lower_bound(batch, N, wid);
  int end = lower_bound(batch, N, wid + 1);
  float acc = 0.0f;
  for (int n = beg; n < end; ++n) acc += x3[(size_t)n * 64 + lane];
  float p = (end > beg) ? acc / (float)(end - beg) : 0.0f;
  float l0 = wave_sum64(p * Wfc[lane * 2 + 0]);
  float l1 = wave_sum64(p * Wfc[lane * 2 + 1]);
  if (lane == 0) {
    l0 += bfc[0];
    l1 += bfc[1];
    float m = fmaxf(l0, l1);
    float ls = m + logf(expf(l0 - m) + expf(l1 - m));
    out[wid * 2 + 0] = l0 - ls;
    out[wid * 2 + 1] = l1 - ls;
  }
}

// ---------------------------------------------------------------- launch

static inline int cdiv(int a, int b) { return (a + b - 1) / b; }

extern "C" void kernel_launch(void* const* d_in, const int* in_sizes, int n_in,
                              void* d_out, int out_size, void* d_ws, size_t ws_size,
                              hipStream_t stream) {
  const float* x      = (const float*)d_in[0];
  const int*   ei     = (const int*)d_in[1];
  const int*   batch  = (const int*)d_in[2];
  const float* W1     = (const float*)d_in[3];
  const float* b1     = (const float*)d_in[4];
  const float* W2     = (const float*)d_in[5];
  const float* a_src2 = (const float*)d_in[6];
  const float* a_dst2 = (const float*)d_in[7];
  const float* b2     = (const float*)d_in[8];
  const float* W3     = (const float*)d_in[9];
  const float* a_src3 = (const float*)d_in[10];
  const float* a_dst3 = (const float*)d_in[11];
  const float* b3     = (const float*)d_in[12];
  const float* Wfc    = (const float*)d_in[13];
  const float* bfc    = (const float*)d_in[14];
  float* out = (float*)d_out;

  const int N = in_sizes[2];       // 50000
  const int E = in_sizes[1] / 2;   // 800000
  const int G = out_size / 2;      // 512
  const int TOT = E + N;           // edges incl. self-loops

  // workspace layout (~70 MB)
  float* ws = (float*)d_ws;
  float*  out2  = ws;                          // N*128 f32 (x2)
  float*  out1  = out2 + (size_t)N * 128;      // N*64  f32 (x1; reused as out3/x3)
  float*  alpha = out1 + (size_t)N * 64;       // TOT*2 f32 (also GCN edge weights)
  float*  dis   = alpha + (size_t)TOT * 2;     // N
  float*  al_s  = dis + N;                     // N*2 planar
  float*  al_d  = al_s + (size_t)N * 2;        // N*2 planar
  float*  den   = al_d + (size_t)N * 2;        // N*2 planar
  __half* h1    = (__half*)(den + (size_t)N * 2);  // N*64 fp16
  __half* h2    = h1 + (size_t)N * 64;             // N*128 fp16 (reused as h3)
  int* cnt      = (int*)(h2 + (size_t)N * 128);    // N
  int* row_ptr  = cnt + N;                         // N+1
  int* cursor   = row_ptr + N + 1;                 // N
  int* csr_src  = cursor + N;                      // TOT

  // ---- CSR build (reused by all three layers); wgcn fused into csr_fill
  fill_int_kernel<<<cdiv(N, BDIM), BDIM, 0, stream>>>(cnt, 0, N);
  count_kernel<<<cdiv(TOT, BDIM), BDIM, 0, stream>>>(ei, E, N, cnt);
  dis_kernel<<<cdiv(N, BDIM), BDIM, 0, stream>>>(cnt, dis, N);
  scan_kernel<<<1, 1024, 0, stream>>>(cnt, N, row_ptr, cursor);
  csr_fill<<<cdiv(TOT, BDIM), BDIM, 0, stream>>>(ei, E, N, dis, cursor, csr_src, alpha);

  // ---- GCN layer
  gemm_small<128, 64, __half><<<cdiv(N, 4), BDIM, 0, stream>>>(x, W1, h1, N);
  gcn_gather<<<cdiv(N, 4), BDIM, 0, stream>>>(h1, row_ptr, csr_src, alpha, b1, out1, N);

  // ---- GAT layer 1 (heads=2, concat)
  gemm_small<64, 128, __half><<<cdiv(N, 2), BDIM, 0, stream>>>(out1, W2, h2, N);
  att_coef<2><<<cdiv(N * 2, 4), BDIM, 0, stream>>>(h2, a_src2, a_dst2, N, al_s, al_d);
  gat_alpha<2><<<cdiv(N * 2, 4), BDIM, 0, stream>>>(row_ptr, csr_src, al_s, al_d,
                                                    alpha, den, N, TOT);
  gat_acc<2><<<cdiv(N * 2, 4), BDIM, 0, stream>>>(h2, row_ptr, csr_src, alpha, den,
                                                  b2, out2, N, TOT, 1);

  // ---- GAT layer 2 (heads=1, mean == identity)
  __half* h3   = h2;     // h2 dead after gat_acc<2>
  float*  out3 = out1;   // x1 dead after gemm2
  gemm_small<128, 64, __half><<<cdiv(N, 4), BDIM, 0, stream>>>(out2, W3, h3, N);
  att_coef<1><<<cdiv(N, 4), BDIM, 0, stream>>>(h3, a_src3, a_dst3, N, al_s, al_d);
  gat_alpha<1><<<cdiv(N, 4), BDIM, 0, stream>>>(row_ptr, csr_src, al_s, al_d,
                                                alpha, den, N, TOT);
  gat_acc<1><<<cdiv(N, 4), BDIM, 0, stream>>>(h3, row_ptr, csr_src, alpha, den,
                                              b3, out3, N, TOT, 0);

  // ---- global mean pool + fc + log_softmax (atomic-free; batch is sorted)
  pool_final<<<cdiv(G, 4), BDIM, 0, stream>>>(out3, batch, Wfc, bfc, out, N, G);
}

// Round 5
// 592.378 us; speedup vs baseline: 2.3616x; 1.1862x over previous
//
#include <hip/hip_runtime.h>
#include <hip/hip_bf16.h>
#include <hip/hip_fp16.h>
#include <math.h>

#define BDIM 256

// ---------------------------------------------------------------- utilities

__global__ void fill_int_kernel(int* __restrict__ p, int v, int n) {
  int i = blockIdx.x * blockDim.x + threadIdx.x;
  if (i < n) p[i] = v;
}

__device__ __forceinline__ float wave_max64(float v) {
#pragma unroll
  for (int o = 32; o > 0; o >>= 1) v = fmaxf(v, __shfl_xor(v, o, 64));
  return v;
}
__device__ __forceinline__ float wave_sum64(float v) {
#pragma unroll
  for (int o = 32; o > 0; o >>= 1) v += __shfl_xor(v, o, 64);
  return v;
}

__device__ __forceinline__ void store_o(float v, float* p) { *p = v; }
__device__ __forceinline__ void store_o(float v, __half* p) { *p = __float2half(v); }

__device__ __forceinline__ float leaky02(float v) {
  return v >= 0.0f ? v : 0.2f * v;
}

// ---------------------------------------------------------------- GEMM
// C[N,KOUT] = A[N,KIN] @ W[KIN,KOUT]; W and an A-tile staged to LDS.
template <int KIN, int KOUT, typename OT>
__launch_bounds__(BDIM) __global__
void gemm_small(const float* __restrict__ A, const float* __restrict__ W,
                OT* __restrict__ C, int N) {
  constexpr int ROWS = BDIM / KOUT;
  __shared__ float Wl[KIN * KOUT];
  __shared__ float Al[ROWS * KIN];
  for (int i = threadIdx.x; i < KIN * KOUT; i += BDIM) Wl[i] = W[i];
  int row0 = blockIdx.x * ROWS;
  for (int i = threadIdx.x; i < ROWS * KIN; i += BDIM) {
    int r = row0 + i / KIN;
    Al[i] = (r < N) ? A[(size_t)r * KIN + (i % KIN)] : 0.0f;
  }
  __syncthreads();
  int r = threadIdx.x / KOUT;
  int c = threadIdx.x % KOUT;
  int row = row0 + r;
  if (row >= N) return;
  float acc = 0.0f;
#pragma unroll
  for (int k = 0; k < KIN; ++k) acc += Al[r * KIN + k] * Wl[k * KOUT + c];
  store_o(acc, &C[(size_t)row * KOUT + c]);
}

// ---------------------------------------------------------------- CSR build
__global__ void count_kernel(const int* __restrict__ ei, int E, int N,
                             int* __restrict__ cnt) {
  int t = blockIdx.x * blockDim.x + threadIdx.x;
  if (t >= E + N) return;
  int dst = (t < E) ? ei[E + t] : (t - E);
  atomicAdd(&cnt[dst], 1);
}

__global__ void dis_kernel(const int* __restrict__ cnt, float* __restrict__ dis, int N) {
  int i = blockIdx.x * blockDim.x + threadIdx.x;
  if (i < N) {
    float d = (float)cnt[i];
    dis[i] = (d > 0.0f) ? rsqrtf(fmaxf(d, 1e-12f)) : 0.0f;
  }
}

// single-workgroup hierarchical exclusive scan: cnt[N] -> row_ptr[N+1], cursor[N]
__launch_bounds__(1024) __global__
void scan_kernel(const int* __restrict__ cnt, int N,
                 int* __restrict__ row_ptr, int* __restrict__ cursor) {
  __shared__ int wsum[16], wpre[16];
  __shared__ int carry_s;
  int tid = threadIdx.x, lane = tid & 63, w = tid >> 6;
  if (tid == 0) carry_s = 0;
  __syncthreads();
  for (int base = 0; base < N; base += 1024) {
    int i = base + tid;
    int v = (i < N) ? cnt[i] : 0;
    int incl = v;
#pragma unroll
    for (int off = 1; off < 64; off <<= 1) {
      int t = __shfl_up(incl, off, 64);
      if (lane >= off) incl += t;
    }
    if (lane == 63) wsum[w] = incl;
    __syncthreads();
    if (w == 0 && lane < 16) {
      int s = wsum[lane];
#pragma unroll
      for (int off = 1; off < 16; off <<= 1) {
        int t = __shfl_up(s, off, 64);
        if (lane >= off) s += t;
      }
      wpre[lane] = s - wsum[lane];
    }
    __syncthreads();
    int c = carry_s;
    int excl = c + wpre[w] + incl - v;
    if (i < N) { row_ptr[i] = excl; cursor[i] = excl; }
    __syncthreads();
    if (tid == 1023) carry_s = c + wpre[15] + wsum[15];
    __syncthreads();
  }
  if (tid == 0) row_ptr[N] = carry_s;
}

// scatter sources into CSR slots; also precompute GCN edge weight dis[s]*dis[d]
__global__ void csr_fill(const int* __restrict__ ei, int E, int N,
                         const float* __restrict__ dis,
                         int* __restrict__ cursor, int* __restrict__ csr_src,
                         float* __restrict__ wgcn) {
  int t = blockIdx.x * blockDim.x + threadIdx.x;
  if (t >= E + N) return;
  int src, dst;
  if (t < E) { src = ei[t]; dst = ei[E + t]; }
  else       { src = dst = t - E; }
  int slot = atomicAdd(&cursor[dst], 1);
  csr_src[slot] = src;
  wgcn[slot] = dis[src] * dis[dst];
}

// ---------------------------------------------------------------- GCN gather
// wave per dst node, lane = feature; 8-deep batched gather loads for MLP.
__launch_bounds__(BDIM) __global__
void gcn_gather(const __half* __restrict__ h, const int* __restrict__ row_ptr,
                const int* __restrict__ csr_src, const float* __restrict__ w,
                const float* __restrict__ b, float* __restrict__ out, int N) {
  constexpr int U = 8;
  int wid = blockIdx.x * (BDIM / 64) + (threadIdx.x >> 6);
  int lane = threadIdx.x & 63;
  if (wid >= N) return;
  int beg = row_ptr[wid], end = row_ptr[wid + 1];
  float acc = 0.0f;
  for (int base = beg; base < end; base += 64) {
    int nch = min(64, end - base);
    int   s_l = (lane < nch) ? csr_src[base + lane] : 0;  // pad: s=0,w=0 -> adds 0
    float w_l = (lane < nch) ? w[base + lane] : 0.0f;
    int jmax = (nch + U - 1) & ~(U - 1);
    for (int j = 0; j < jmax; j += U) {
      int ss[U]; float ww[U]; __half vv[U];
#pragma unroll
      for (int u = 0; u < U; ++u) {
        ss[u] = __shfl(s_l, j + u, 64);
        ww[u] = __shfl(w_l, j + u, 64);
      }
#pragma unroll
      for (int u = 0; u < U; ++u) vv[u] = h[(size_t)ss[u] * 64 + lane];
#pragma unroll
      for (int u = 0; u < U; ++u) acc += ww[u] * __half2float(vv[u]);
    }
  }
  out[(size_t)wid * 64 + lane] = fmaxf(acc + b[lane], 0.0f);
}

// ---------------------------------------------------------------- GAT
// wave per (node, head): attention coefficients; planar outputs al[hd*N + n]
template <int HEADS>
__launch_bounds__(BDIM) __global__
void att_coef(const __half* __restrict__ h, const float* __restrict__ a_src,
              const float* __restrict__ a_dst, int N,
              float* __restrict__ al_s, float* __restrict__ al_d) {
  int wid = blockIdx.x * (BDIM / 64) + (threadIdx.x >> 6);
  int lane = threadIdx.x & 63;
  if (wid >= N * HEADS) return;
  int n = wid % N, hd = wid / N;
  float v = __half2float(h[(size_t)n * (HEADS * 64) + hd * 64 + lane]);
  float ps = wave_sum64(v * a_src[hd * 64 + lane]);
  float pd = wave_sum64(v * a_dst[hd * 64 + lane]);
  if (lane == 0) { al_s[hd * N + n] = ps; al_d[hd * N + n] = pd; }
}

// wave per (dst, head): segment softmax -> unnormalized alpha per edge + den per dst
// alpha written interleaved: alpha[e*HEADS + hd]
template <int HEADS>
__launch_bounds__(BDIM) __global__
void gat_alpha(const int* __restrict__ row_ptr, const int* __restrict__ csr_src,
               const float* __restrict__ al_s, const float* __restrict__ al_d,
               float* __restrict__ alpha, float* __restrict__ den, int N) {
  int wid = blockIdx.x * (BDIM / 64) + (threadIdx.x >> 6);
  int lane = threadIdx.x & 63;
  if (wid >= N * HEADS) return;
  int dn = wid % N, hd = wid / N;
  const float* als_p = al_s + (size_t)hd * N;
  float ad = al_d[(size_t)hd * N + dn];
  int beg = row_ptr[dn], end = row_ptr[dn + 1];
  int deg = end - beg;
  if (deg <= 64) {  // common case: whole segment in one wave pass
    int   s = (lane < deg) ? csr_src[beg + lane] : 0;
    float e = (lane < deg) ? leaky02(als_p[s] + ad) : -3.4e38f;
    float m = wave_max64(e);
    float ex = (lane < deg) ? expf(e - m) : 0.0f;
    float l = wave_sum64(ex);
    if (lane < deg) alpha[(size_t)(beg + lane) * HEADS + hd] = ex;
    if (lane == 0) den[(size_t)hd * N + dn] = l;
  } else {
    float m = -3.4e38f;
    for (int base = beg; base < end; base += 64) {
      int nch = min(64, end - base);
      int   s = (lane < nch) ? csr_src[base + lane] : 0;
      float e = (lane < nch) ? leaky02(als_p[s] + ad) : -3.4e38f;
      m = fmaxf(m, wave_max64(e));
    }
    float l = 0.0f;
    for (int base = beg; base < end; base += 64) {
      int nch = min(64, end - base);
      int   s = (lane < nch) ? csr_src[base + lane] : 0;
      float e = (lane < nch) ? leaky02(als_p[s] + ad) : -3.4e38f;
      float ex = (lane < nch) ? expf(e - m) : 0.0f;
      if (lane < nch) alpha[(size_t)(base + lane) * HEADS + hd] = ex;
      l += wave_sum64(ex);
    }
    if (lane == 0) den[(size_t)hd * N + dn] = l;
  }
}

// GAT layer-1 accumulate, BOTH heads per wave. Row = 256B (__half2 per lane).
// lane covers combined features (2*lane, 2*lane+1); head = lane>>5.
__launch_bounds__(BDIM) __global__
void gat_acc2(const __half* __restrict__ h, const int* __restrict__ row_ptr,
              const int* __restrict__ csr_src, const float2* __restrict__ alpha2,
              const float* __restrict__ den, const float* __restrict__ b,
              float* __restrict__ out, int N) {
  constexpr int U = 8;
  int wid = blockIdx.x * (BDIM / 64) + (threadIdx.x >> 6);
  int lane = threadIdx.x & 63;
  if (wid >= N) return;
  int head = lane >> 5;
  const __half2* hrow = (const __half2*)h;  // 64 half2 per node row
  int beg = row_ptr[wid], end = row_ptr[wid + 1];
  float accx = 0.0f, accy = 0.0f;
  for (int base = beg; base < end; base += 64) {
    int nch = min(64, end - base);
    int    s_l = (lane < nch) ? csr_src[base + lane] : 0;
    float2 a_l = (lane < nch) ? alpha2[base + lane] : make_float2(0.0f, 0.0f);
    int jmax = (nch + U - 1) & ~(U - 1);
    for (int j = 0; j < jmax; j += U) {
      int ss[U]; float aa[U]; __half2 vv[U];
#pragma unroll
      for (int u = 0; u < U; ++u) {
        ss[u] = __shfl(s_l, j + u, 64);
        float a0 = __shfl(a_l.x, j + u, 64);
        float a1 = __shfl(a_l.y, j + u, 64);
        aa[u] = head ? a1 : a0;
      }
#pragma unroll
      for (int u = 0; u < U; ++u) vv[u] = hrow[(size_t)ss[u] * 64 + lane];
#pragma unroll
      for (int u = 0; u < U; ++u) {
        float2 v = __half22float2(vv[u]);
        accx += aa[u] * v.x;
        accy += aa[u] * v.y;
      }
    }
  }
  float dn = den[(size_t)head * N + wid];
  const float2* b2v = (const float2*)b;
  float2 bb = b2v[lane];
  float2 o;
  o.x = fmaxf(accx / dn + bb.x, 0.0f);  // relu fused (layer 1 always relu)
  o.y = fmaxf(accy / dn + bb.y, 0.0f);
  ((float2*)out)[(size_t)wid * 64 + lane] = o;
}

// GAT layer-2 accumulate (1 head, 64 feats), 8-deep batched loads.
__launch_bounds__(BDIM) __global__
void gat_acc1(const __half* __restrict__ h, const int* __restrict__ row_ptr,
              const int* __restrict__ csr_src, const float* __restrict__ alpha,
              const float* __restrict__ den, const float* __restrict__ b,
              float* __restrict__ out, int N) {
  constexpr int U = 8;
  int wid = blockIdx.x * (BDIM / 64) + (threadIdx.x >> 6);
  int lane = threadIdx.x & 63;
  if (wid >= N) return;
  int beg = row_ptr[wid], end = row_ptr[wid + 1];
  float acc = 0.0f;
  for (int base = beg; base < end; base += 64) {
    int nch = min(64, end - base);
    int   s_l = (lane < nch) ? csr_src[base + lane] : 0;
    float a_l = (lane < nch) ? alpha[base + lane] : 0.0f;
    int jmax = (nch + U - 1) & ~(U - 1);
    for (int j = 0; j < jmax; j += U) {
      int ss[U]; float aa[U]; __half vv[U];
#pragma unroll
      for (int u = 0; u < U; ++u) {
        ss[u] = __shfl(s_l, j + u, 64);
        aa[u] = __shfl(a_l, j + u, 64);
      }
#pragma unroll
      for (int u = 0; u < U; ++u) vv[u] = h[(size_t)ss[u] * 64 + lane];
#pragma unroll
      for (int u = 0; u < U; ++u) acc += aa[u] * __half2float(vv[u]);
    }
  }
  out[(size_t)wid * 64 + lane] = acc / den[wid] + b[lane];  // no relu on layer 2
}

// ---------------------------------------------------------------- pool + head
__device__ __forceinline__ int lower_bound(const int* __restrict__ a, int n, int v) {
  int lo = 0, hi = n;
  while (lo < hi) {
    int mid = (lo + hi) >> 1;
    if (a[mid] < v) lo = mid + 1; else hi = mid;
  }
  return lo;
}

// wave per graph: batch is sorted -> contiguous node range; no atomics
__launch_bounds__(BDIM) __global__
void pool_final(const float* __restrict__ x3, const int* __restrict__ batch,
                const float* __restrict__ Wfc, const float* __restrict__ bfc,
                float* __restrict__ out, int N, int G) {
  int wid = blockIdx.x * (BDIM / 64) + (threadIdx.x >> 6);
  int lane = threadIdx.x & 63;
  if (wid >= G) return;
  int beg = lower_bound(batch, N, wid);
  int end = lower_bound(batch, N, wid + 1);
  float acc = 0.0f;
  for (int n = beg; n < end; ++n) acc += x3[(size_t)n * 64 + lane];
  float p = (end > beg) ? acc / (float)(end - beg) : 0.0f;
  float l0 = wave_sum64(p * Wfc[lane * 2 + 0]);
  float l1 = wave_sum64(p * Wfc[lane * 2 + 1]);
  if (lane == 0) {
    l0 += bfc[0];
    l1 += bfc[1];
    float m = fmaxf(l0, l1);
    float ls = m + logf(expf(l0 - m) + expf(l1 - m));
    out[wid * 2 + 0] = l0 - ls;
    out[wid * 2 + 1] = l1 - ls;
  }
}

// ---------------------------------------------------------------- launch

static inline int cdiv(int a, int b) { return (a + b - 1) / b; }

extern "C" void kernel_launch(void* const* d_in, const int* in_sizes, int n_in,
                              void* d_out, int out_size, void* d_ws, size_t ws_size,
                              hipStream_t stream) {
  const float* x      = (const float*)d_in[0];
  const int*   ei     = (const int*)d_in[1];
  const int*   batch  = (const int*)d_in[2];
  const float* W1     = (const float*)d_in[3];
  const float* b1     = (const float*)d_in[4];
  const float* W2     = (const float*)d_in[5];
  const float* a_src2 = (const float*)d_in[6];
  const float* a_dst2 = (const float*)d_in[7];
  const float* b2     = (const float*)d_in[8];
  const float* W3     = (const float*)d_in[9];
  const float* a_src3 = (const float*)d_in[10];
  const float* a_dst3 = (const float*)d_in[11];
  const float* b3     = (const float*)d_in[12];
  const float* Wfc    = (const float*)d_in[13];
  const float* bfc    = (const float*)d_in[14];
  float* out = (float*)d_out;

  const int N = in_sizes[2];       // 50000
  const int E = in_sizes[1] / 2;   // 800000
  const int G = out_size / 2;      // 512
  const int TOT = E + N;           // edges incl. self-loops

  // workspace layout (~70 MB)
  float* ws = (float*)d_ws;
  float*  out2  = ws;                          // N*128 f32 (x2)
  float*  out1  = out2 + (size_t)N * 128;      // N*64  f32 (x1; reused as out3/x3)
  float*  alpha = out1 + (size_t)N * 64;       // TOT*2 f32 (GCN w / interleaved alpha)
  float*  dis   = alpha + (size_t)TOT * 2;     // N
  float*  al_s  = dis + N;                     // N*2 planar
  float*  al_d  = al_s + (size_t)N * 2;        // N*2 planar
  float*  den   = al_d + (size_t)N * 2;        // N*2 planar
  __half* h1    = (__half*)(den + (size_t)N * 2);  // N*64 fp16
  __half* h2    = h1 + (size_t)N * 64;             // N*128 fp16 (reused as h3)
  int* cnt      = (int*)(h2 + (size_t)N * 128);    // N
  int* row_ptr  = cnt + N;                         // N+1
  int* cursor   = row_ptr + N + 1;                 // N
  int* csr_src  = cursor + N;                      // TOT

  // ---- CSR build (reused by all three layers); wgcn fused into csr_fill
  fill_int_kernel<<<cdiv(N, BDIM), BDIM, 0, stream>>>(cnt, 0, N);
  count_kernel<<<cdiv(TOT, BDIM), BDIM, 0, stream>>>(ei, E, N, cnt);
  dis_kernel<<<cdiv(N, BDIM), BDIM, 0, stream>>>(cnt, dis, N);
  scan_kernel<<<1, 1024, 0, stream>>>(cnt, N, row_ptr, cursor);
  csr_fill<<<cdiv(TOT, BDIM), BDIM, 0, stream>>>(ei, E, N, dis, cursor, csr_src, alpha);

  // ---- GCN layer
  gemm_small<128, 64, __half><<<cdiv(N, 4), BDIM, 0, stream>>>(x, W1, h1, N);
  gcn_gather<<<cdiv(N, 4), BDIM, 0, stream>>>(h1, row_ptr, csr_src, alpha, b1, out1, N);

  // ---- GAT layer 1 (heads=2, concat; fused dual-head accumulate)
  gemm_small<64, 128, __half><<<cdiv(N, 2), BDIM, 0, stream>>>(out1, W2, h2, N);
  att_coef<2><<<cdiv(N * 2, 4), BDIM, 0, stream>>>(h2, a_src2, a_dst2, N, al_s, al_d);
  gat_alpha<2><<<cdiv(N * 2, 4), BDIM, 0, stream>>>(row_ptr, csr_src, al_s, al_d,
                                                    alpha, den, N);
  gat_acc2<<<cdiv(N, 4), BDIM, 0, stream>>>(h2, row_ptr, csr_src, (const float2*)alpha,
                                            den, b2, out2, N);

  // ---- GAT layer 2 (heads=1, mean == identity)
  __half* h3   = h2;     // h2 dead after gat_acc2
  float*  out3 = out1;   // x1 dead after gemm2
  gemm_small<128, 64, __half><<<cdiv(N, 4), BDIM, 0, stream>>>(out2, W3, h3, N);
  att_coef<1><<<cdiv(N, 4), BDIM, 0, stream>>>(h3, a_src3, a_dst3, N, al_s, al_d);
  gat_alpha<1><<<cdiv(N, 4), BDIM, 0, stream>>>(row_ptr, csr_src, al_s, al_d,
                                                alpha, den, N);
  gat_acc1<<<cdiv(N, 4), BDIM, 0, stream>>>(h3, row_ptr, csr_src, alpha, den,
                                            b3, out3, N);

  // ---- global mean pool + fc + log_softmax (atomic-free; batch is sorted)
  pool_final<<<cdiv(G, 4), BDIM, 0, stream>>>(out3, batch, Wfc, bfc, out, N, G);
}

// Round 6
// 454.364 us; speedup vs baseline: 3.0790x; 1.3038x over previous
//
#include <hip/hip_runtime.h>
#include <hip/hip_bf16.h>
#include <hip/hip_fp16.h>
#include <math.h>

#define BDIM 256

using v8h = __attribute__((ext_vector_type(8))) _Float16;
using v4f = __attribute__((ext_vector_type(4))) float;

// ---------------------------------------------------------------- utilities

__global__ void fill_int_kernel(int* __restrict__ p, int v, int n) {
  int i = blockIdx.x * blockDim.x + threadIdx.x;
  if (i < n) p[i] = v;
}

__device__ __forceinline__ float wave_max64(float v) {
#pragma unroll
  for (int o = 32; o > 0; o >>= 1) v = fmaxf(v, __shfl_xor(v, o, 64));
  return v;
}
__device__ __forceinline__ float wave_sum64(float v) {
#pragma unroll
  for (int o = 32; o > 0; o >>= 1) v += __shfl_xor(v, o, 64);
  return v;
}

__device__ __forceinline__ float leaky02(float v) {
  return v >= 0.0f ? v : 0.2f * v;
}

// ---------------------------------------------------------------- MFMA GEMM
// C[N,KOUT](fp16) = A[N,KIN] @ W[KIN,KOUT](fp32 in, fp16 compute, fp32 acc)
// Wave computes 16 rows x KOUT cols. A-frag: A[m=lane&15][k=quad*8+j] (16B/lane
// direct from global). W staged transposed to LDS as Wt[n][k] fp16, row padded
// +8 halves (272B stride) to break the 16-way bank conflict of a 256B stride.
// C/D frag: col=lane&15, row=quad*4+reg (HW-verified mapping).
template <int KIN, int KOUT, bool A_FP32>
__launch_bounds__(BDIM) __global__
void gemm_mfma(const void* __restrict__ Ap, const float* __restrict__ W,
               _Float16* __restrict__ C, int N) {
  constexpr int KP = KIN + 8;
  constexpr int NT = KOUT / 16;
  __shared__ _Float16 Wt[KOUT * KP];
  int tid = threadIdx.x;
  for (int i = tid; i < KIN * KOUT; i += BDIM) {
    int k = i / KOUT, n = i % KOUT;
    Wt[n * KP + k] = (_Float16)W[i];
  }
  __syncthreads();
  int lane = tid & 63;
  int quad = lane >> 4, l16 = lane & 15;
  int m0 = blockIdx.x * 64 + (tid >> 6) * 16;
  if (m0 >= N) return;  // N % 16 == 0: whole wave in or out
  v4f acc[NT];
#pragma unroll
  for (int nt = 0; nt < NT; ++nt) acc[nt] = (v4f){0.0f, 0.0f, 0.0f, 0.0f};
#pragma unroll
  for (int k0 = 0; k0 < KIN; k0 += 32) {
    v8h a;
    if constexpr (A_FP32) {
      const float* ap = (const float*)Ap + (size_t)(m0 + l16) * KIN + k0 + quad * 8;
#pragma unroll
      for (int j = 0; j < 8; ++j) a[j] = (_Float16)ap[j];
    } else {
      a = *(const v8h*)((const _Float16*)Ap + (size_t)(m0 + l16) * KIN + k0 + quad * 8);
    }
#pragma unroll
    for (int nt = 0; nt < NT; ++nt) {
      v8h b = *(const v8h*)&Wt[(nt * 16 + l16) * KP + k0 + quad * 8];
      acc[nt] = __builtin_amdgcn_mfma_f32_16x16x32_f16(a, b, acc[nt], 0, 0, 0);
    }
  }
#pragma unroll
  for (int nt = 0; nt < NT; ++nt)
#pragma unroll
    for (int r = 0; r < 4; ++r)
      C[(size_t)(m0 + quad * 4 + r) * KOUT + nt * 16 + l16] = (_Float16)acc[nt][r];
}

// ---------------------------------------------------------------- CSR build
__global__ void count_kernel(const int* __restrict__ ei, int E, int N,
                             int* __restrict__ cnt) {
  int t = blockIdx.x * blockDim.x + threadIdx.x;
  if (t >= E + N) return;
  int dst = (t < E) ? ei[E + t] : (t - E);
  atomicAdd(&cnt[dst], 1);
}

__global__ void dis_kernel(const int* __restrict__ cnt, float* __restrict__ dis, int N) {
  int i = blockIdx.x * blockDim.x + threadIdx.x;
  if (i < N) {
    float d = (float)cnt[i];
    dis[i] = (d > 0.0f) ? rsqrtf(fmaxf(d, 1e-12f)) : 0.0f;
  }
}

// single-workgroup hierarchical exclusive scan: cnt[N] -> row_ptr[N+1], cursor[N]
__launch_bounds__(1024) __global__
void scan_kernel(const int* __restrict__ cnt, int N,
                 int* __restrict__ row_ptr, int* __restrict__ cursor) {
  __shared__ int wsum[16], wpre[16];
  __shared__ int carry_s;
  int tid = threadIdx.x, lane = tid & 63, w = tid >> 6;
  if (tid == 0) carry_s = 0;
  __syncthreads();
  for (int base = 0; base < N; base += 1024) {
    int i = base + tid;
    int v = (i < N) ? cnt[i] : 0;
    int incl = v;
#pragma unroll
    for (int off = 1; off < 64; off <<= 1) {
      int t = __shfl_up(incl, off, 64);
      if (lane >= off) incl += t;
    }
    if (lane == 63) wsum[w] = incl;
    __syncthreads();
    if (w == 0 && lane < 16) {
      int s = wsum[lane];
#pragma unroll
      for (int off = 1; off < 16; off <<= 1) {
        int t = __shfl_up(s, off, 64);
        if (lane >= off) s += t;
      }
      wpre[lane] = s - wsum[lane];
    }
    __syncthreads();
    int c = carry_s;
    int excl = c + wpre[w] + incl - v;
    if (i < N) { row_ptr[i] = excl; cursor[i] = excl; }
    __syncthreads();
    if (tid == 1023) carry_s = c + wpre[15] + wsum[15];
    __syncthreads();
  }
  if (tid == 0) row_ptr[N] = carry_s;
}

// scatter sources into CSR slots; also precompute GCN edge weight dis[s]*dis[d]
__global__ void csr_fill(const int* __restrict__ ei, int E, int N,
                         const float* __restrict__ dis,
                         int* __restrict__ cursor, int* __restrict__ csr_src,
                         float* __restrict__ wgcn) {
  int t = blockIdx.x * blockDim.x + threadIdx.x;
  if (t >= E + N) return;
  int src, dst;
  if (t < E) { src = ei[t]; dst = ei[E + t]; }
  else       { src = dst = t - E; }
  int slot = atomicAdd(&cursor[dst], 1);
  csr_src[slot] = src;
  wgcn[slot] = dis[src] * dis[dst];
}

// ---------------------------------------------------------------- GCN gather
// wave per dst node, lane = feature; 8-deep batched gather loads; fp16 output.
__launch_bounds__(BDIM) __global__
void gcn_gather(const __half* __restrict__ h, const int* __restrict__ row_ptr,
                const int* __restrict__ csr_src, const float* __restrict__ w,
                const float* __restrict__ b, __half* __restrict__ out, int N) {
  constexpr int U = 8;
  int wid = blockIdx.x * (BDIM / 64) + (threadIdx.x >> 6);
  int lane = threadIdx.x & 63;
  if (wid >= N) return;
  int beg = row_ptr[wid], end = row_ptr[wid + 1];
  float acc = 0.0f;
  for (int base = beg; base < end; base += 64) {
    int nch = min(64, end - base);
    int   s_l = (lane < nch) ? csr_src[base + lane] : 0;  // pad: s=0,w=0 -> adds 0
    float w_l = (lane < nch) ? w[base + lane] : 0.0f;
    int jmax = (nch + U - 1) & ~(U - 1);
    for (int j = 0; j < jmax; j += U) {
      int ss[U]; float ww[U]; __half vv[U];
#pragma unroll
      for (int u = 0; u < U; ++u) {
        ss[u] = __shfl(s_l, j + u, 64);
        ww[u] = __shfl(w_l, j + u, 64);
      }
#pragma unroll
      for (int u = 0; u < U; ++u) vv[u] = h[(size_t)ss[u] * 64 + lane];
#pragma unroll
      for (int u = 0; u < U; ++u) acc += ww[u] * __half2float(vv[u]);
    }
  }
  out[(size_t)wid * 64 + lane] = __float2half(fmaxf(acc + b[lane], 0.0f));
}

// ---------------------------------------------------------------- GAT
// wave per (node, head): attention coefficients; planar outputs al[hd*N + n]
template <int HEADS>
__launch_bounds__(BDIM) __global__
void att_coef(const __half* __restrict__ h, const float* __restrict__ a_src,
              const float* __restrict__ a_dst, int N,
              float* __restrict__ al_s, float* __restrict__ al_d) {
  int wid = blockIdx.x * (BDIM / 64) + (threadIdx.x >> 6);
  int lane = threadIdx.x & 63;
  if (wid >= N * HEADS) return;
  int n = wid % N, hd = wid / N;
  float v = __half2float(h[(size_t)n * (HEADS * 64) + hd * 64 + lane]);
  float ps = wave_sum64(v * a_src[hd * 64 + lane]);
  float pd = wave_sum64(v * a_dst[hd * 64 + lane]);
  if (lane == 0) { al_s[hd * N + n] = ps; al_d[hd * N + n] = pd; }
}

// wave per (dst, head): segment softmax -> unnormalized alpha per edge + den per dst
// alpha written interleaved: alpha[e*HEADS + hd]
template <int HEADS>
__launch_bounds__(BDIM) __global__
void gat_alpha(const int* __restrict__ row_ptr, const int* __restrict__ csr_src,
               const float* __restrict__ al_s, const float* __restrict__ al_d,
               float* __restrict__ alpha, float* __restrict__ den, int N) {
  int wid = blockIdx.x * (BDIM / 64) + (threadIdx.x >> 6);
  int lane = threadIdx.x & 63;
  if (wid >= N * HEADS) return;
  int dn = wid % N, hd = wid / N;
  const float* als_p = al_s + (size_t)hd * N;
  float ad = al_d[(size_t)hd * N + dn];
  int beg = row_ptr[dn], end = row_ptr[dn + 1];
  int deg = end - beg;
  if (deg <= 64) {  // common case: whole segment in one wave pass
    int   s = (lane < deg) ? csr_src[beg + lane] : 0;
    float e = (lane < deg) ? leaky02(als_p[s] + ad) : -3.4e38f;
    float m = wave_max64(e);
    float ex = (lane < deg) ? expf(e - m) : 0.0f;
    float l = wave_sum64(ex);
    if (lane < deg) alpha[(size_t)(beg + lane) * HEADS + hd] = ex;
    if (lane == 0) den[(size_t)hd * N + dn] = l;
  } else {
    float m = -3.4e38f;
    for (int base = beg; base < end; base += 64) {
      int nch = min(64, end - base);
      int   s = (lane < nch) ? csr_src[base + lane] : 0;
      float e = (lane < nch) ? leaky02(als_p[s] + ad) : -3.4e38f;
      m = fmaxf(m, wave_max64(e));
    }
    float l = 0.0f;
    for (int base = beg; base < end; base += 64) {
      int nch = min(64, end - base);
      int   s = (lane < nch) ? csr_src[base + lane] : 0;
      float e = (lane < nch) ? leaky02(als_p[s] + ad) : -3.4e38f;
      float ex = (lane < nch) ? expf(e - m) : 0.0f;
      if (lane < nch) alpha[(size_t)(base + lane) * HEADS + hd] = ex;
      l += wave_sum64(ex);
    }
    if (lane == 0) den[(size_t)hd * N + dn] = l;
  }
}

// GAT layer-1 accumulate, BOTH heads per wave. Row = 256B (__half2 per lane).
// lane covers combined features (2*lane, 2*lane+1); head = lane>>5. fp16 output.
__launch_bounds__(BDIM) __global__
void gat_acc2(const __half* __restrict__ h, const int* __restrict__ row_ptr,
              const int* __restrict__ csr_src, const float2* __restrict__ alpha2,
              const float* __restrict__ den, const float* __restrict__ b,
              __half* __restrict__ out, int N) {
  constexpr int U = 8;
  int wid = blockIdx.x * (BDIM / 64) + (threadIdx.x >> 6);
  int lane = threadIdx.x & 63;
  if (wid >= N) return;
  int head = lane >> 5;
  const __half2* hrow = (const __half2*)h;  // 64 half2 per node row
  int beg = row_ptr[wid], end = row_ptr[wid + 1];
  float accx = 0.0f, accy = 0.0f;
  for (int base = beg; base < end; base += 64) {
    int nch = min(64, end - base);
    int    s_l = (lane < nch) ? csr_src[base + lane] : 0;
    float2 a_l = (lane < nch) ? alpha2[base + lane] : make_float2(0.0f, 0.0f);
    int jmax = (nch + U - 1) & ~(U - 1);
    for (int j = 0; j < jmax; j += U) {
      int ss[U]; float aa[U]; __half2 vv[U];
#pragma unroll
      for (int u = 0; u < U; ++u) {
        ss[u] = __shfl(s_l, j + u, 64);
        float a0 = __shfl(a_l.x, j + u, 64);
        float a1 = __shfl(a_l.y, j + u, 64);
        aa[u] = head ? a1 : a0;
      }
#pragma unroll
      for (int u = 0; u < U; ++u) vv[u] = hrow[(size_t)ss[u] * 64 + lane];
#pragma unroll
      for (int u = 0; u < U; ++u) {
        float2 v = __half22float2(vv[u]);
        accx += aa[u] * v.x;
        accy += aa[u] * v.y;
      }
    }
  }
  float dn = den[(size_t)head * N + wid];
  const float2* b2v = (const float2*)b;
  float2 bb = b2v[lane];
  float ox = fmaxf(accx / dn + bb.x, 0.0f);  // relu fused (layer 1 always relu)
  float oy = fmaxf(accy / dn + bb.y, 0.0f);
  ((__half2*)out)[(size_t)wid * 64 + lane] = __floats2half2_rn(ox, oy);
}

// GAT layer-2 accumulate (1 head, 64 feats), 8-deep batched loads; fp32 out.
__launch_bounds__(BDIM) __global__
void gat_acc1(const __half* __restrict__ h, const int* __restrict__ row_ptr,
              const int* __restrict__ csr_src, const float* __restrict__ alpha,
              const float* __restrict__ den, const float* __restrict__ b,
              float* __restrict__ out, int N) {
  constexpr int U = 8;
  int wid = blockIdx.x * (BDIM / 64) + (threadIdx.x >> 6);
  int lane = threadIdx.x & 63;
  if (wid >= N) return;
  int beg = row_ptr[wid], end = row_ptr[wid + 1];
  float acc = 0.0f;
  for (int base = beg; base < end; base += 64) {
    int nch = min(64, end - base);
    int   s_l = (lane < nch) ? csr_src[base + lane] : 0;
    float a_l = (lane < nch) ? alpha[base + lane] : 0.0f;
    int jmax = (nch + U - 1) & ~(U - 1);
    for (int j = 0; j < jmax; j += U) {
      int ss[U]; float aa[U]; __half vv[U];
#pragma unroll
      for (int u = 0; u < U; ++u) {
        ss[u] = __shfl(s_l, j + u, 64);
        aa[u] = __shfl(a_l, j + u, 64);
      }
#pragma unroll
      for (int u = 0; u < U; ++u) vv[u] = h[(size_t)ss[u] * 64 + lane];
#pragma unroll
      for (int u = 0; u < U; ++u) acc += aa[u] * __half2float(vv[u]);
    }
  }
  out[(size_t)wid * 64 + lane] = acc / den[wid] + b[lane];  // no relu on layer 2
}

// ---------------------------------------------------------------- pool + head
__device__ __forceinline__ int lower_bound(const int* __restrict__ a, int n, int v) {
  int lo = 0, hi = n;
  while (lo < hi) {
    int mid = (lo + hi) >> 1;
    if (a[mid] < v) lo = mid + 1; else hi = mid;
  }
  return lo;
}

// wave per graph: batch is sorted -> contiguous node range; no atomics
__launch_bounds__(BDIM) __global__
void pool_final(const float* __restrict__ x3, const int* __restrict__ batch,
                const float* __restrict__ Wfc, const float* __restrict__ bfc,
                float* __restrict__ out, int N, int G) {
  int wid = blockIdx.x * (BDIM / 64) + (threadIdx.x >> 6);
  int lane = threadIdx.x & 63;
  if (wid >= G) return;
  int beg = lower_bound(batch, N, wid);
  int end = lower_bound(batch, N, wid + 1);
  float acc = 0.0f;
  for (int n = beg; n < end; ++n) acc += x3[(size_t)n * 64 + lane];
  float p = (end > beg) ? acc / (float)(end - beg) : 0.0f;
  float l0 = wave_sum64(p * Wfc[lane * 2 + 0]);
  float l1 = wave_sum64(p * Wfc[lane * 2 + 1]);
  if (lane == 0) {
    l0 += bfc[0];
    l1 += bfc[1];
    float m = fmaxf(l0, l1);
    float ls = m + logf(expf(l0 - m) + expf(l1 - m));
    out[wid * 2 + 0] = l0 - ls;
    out[wid * 2 + 1] = l1 - ls;
  }
}

// ---------------------------------------------------------------- launch

static inline int cdiv(int a, int b) { return (a + b - 1) / b; }

extern "C" void kernel_launch(void* const* d_in, const int* in_sizes, int n_in,
                              void* d_out, int out_size, void* d_ws, size_t ws_size,
                              hipStream_t stream) {
  const float* x      = (const float*)d_in[0];
  const int*   ei     = (const int*)d_in[1];
  const int*   batch  = (const int*)d_in[2];
  const float* W1     = (const float*)d_in[3];
  const float* b1     = (const float*)d_in[4];
  const float* W2     = (const float*)d_in[5];
  const float* a_src2 = (const float*)d_in[6];
  const float* a_dst2 = (const float*)d_in[7];
  const float* b2     = (const float*)d_in[8];
  const float* W3     = (const float*)d_in[9];
  const float* a_src3 = (const float*)d_in[10];
  const float* a_dst3 = (const float*)d_in[11];
  const float* b3     = (const float*)d_in[12];
  const float* Wfc    = (const float*)d_in[13];
  const float* bfc    = (const float*)d_in[14];
  float* out = (float*)d_out;

  const int N = in_sizes[2];       // 50000
  const int E = in_sizes[1] / 2;   // 800000
  const int G = out_size / 2;      // 512
  const int TOT = E + N;           // edges incl. self-loops

  // workspace layout (~64 MB), fp16 buffers first (16B-aligned offsets)
  char* wsb = (char*)d_ws;
  __half* h1    = (__half*)wsb;                       // N*64 fp16
  __half* h2    = h1 + (size_t)N * 64;                // N*128 fp16 (reused as h3)
  __half* out1h = h2 + (size_t)N * 128;               // N*64 fp16 (x1)
  __half* out2h = out1h + (size_t)N * 64;             // N*128 fp16 (x2)
  float*  out3  = (float*)(out2h + (size_t)N * 128);  // N*64 f32 (x3)
  float*  alpha = out3 + (size_t)N * 64;              // TOT*2 f32 (wgcn / alpha)
  float*  dis   = alpha + (size_t)TOT * 2;            // N
  float*  al_s  = dis + N;                            // N*2 planar
  float*  al_d  = al_s + (size_t)N * 2;               // N*2 planar
  float*  den   = al_d + (size_t)N * 2;               // N*2 planar
  int* cnt      = (int*)(den + (size_t)N * 2);        // N
  int* cursor   = cnt + N;                            // N
  int* csr_src  = cursor + N;                         // TOT
  int* row_ptr  = csr_src + TOT;                      // N+1

  // ---- CSR build (reused by all three layers); wgcn fused into csr_fill
  fill_int_kernel<<<cdiv(N, BDIM), BDIM, 0, stream>>>(cnt, 0, N);
  count_kernel<<<cdiv(TOT, BDIM), BDIM, 0, stream>>>(ei, E, N, cnt);
  dis_kernel<<<cdiv(N, BDIM), BDIM, 0, stream>>>(cnt, dis, N);
  scan_kernel<<<1, 1024, 0, stream>>>(cnt, N, row_ptr, cursor);
  csr_fill<<<cdiv(TOT, BDIM), BDIM, 0, stream>>>(ei, E, N, dis, cursor, csr_src, alpha);

  // ---- GCN layer
  gemm_mfma<128, 64, true><<<cdiv(N, 64), BDIM, 0, stream>>>(x, W1, (_Float16*)h1, N);
  gcn_gather<<<cdiv(N, 4), BDIM, 0, stream>>>(h1, row_ptr, csr_src, alpha, b1, out1h, N);

  // ---- GAT layer 1 (heads=2, concat; fused dual-head accumulate)
  gemm_mfma<64, 128, false><<<cdiv(N, 64), BDIM, 0, stream>>>(out1h, W2, (_Float16*)h2, N);
  att_coef<2><<<cdiv(N * 2, 4), BDIM, 0, stream>>>(h2, a_src2, a_dst2, N, al_s, al_d);
  gat_alpha<2><<<cdiv(N * 2, 4), BDIM, 0, stream>>>(row_ptr, csr_src, al_s, al_d,
                                                    alpha, den, N);
  gat_acc2<<<cdiv(N, 4), BDIM, 0, stream>>>(h2, row_ptr, csr_src, (const float2*)alpha,
                                            den, b2, out2h, N);

  // ---- GAT layer 2 (heads=1, mean == identity)
  __half* h3 = h2;  // h2 dead after gat_acc2
  gemm_mfma<128, 64, false><<<cdiv(N, 64), BDIM, 0, stream>>>(out2h, W3, (_Float16*)h3, N);
  att_coef<1><<<cdiv(N, 4), BDIM, 0, stream>>>(h3, a_src3, a_dst3, N, al_s, al_d);
  gat_alpha<1><<<cdiv(N, 4), BDIM, 0, stream>>>(row_ptr, csr_src, al_s, al_d,
                                                alpha, den, N);
  gat_acc1<<<cdiv(N, 4), BDIM, 0, stream>>>(h3, row_ptr, csr_src, alpha, den,
                                            b3, out3, N);

  // ---- global mean pool + fc + log_softmax (atomic-free; batch is sorted)
  pool_final<<<cdiv(G, 4), BDIM, 0, stream>>>(out3, batch, Wfc, bfc, out, N, G);
}

// Round 7
// 435.764 us; speedup vs baseline: 3.2104x; 1.0427x over previous
//
#include <hip/hip_runtime.h>
#include <hip/hip_bf16.h>
#include <hip/hip_fp16.h>
#include <math.h>

#define BDIM 256

using v8h = __attribute__((ext_vector_type(8))) _Float16;
using v4f = __attribute__((ext_vector_type(4))) float;

// ---------------------------------------------------------------- utilities

__global__ void fill_int_kernel(int* __restrict__ p, int v, int n) {
  int i = blockIdx.x * blockDim.x + threadIdx.x;
  if (i < n) p[i] = v;
}

__device__ __forceinline__ float wave_max64(float v) {
#pragma unroll
  for (int o = 32; o > 0; o >>= 1) v = fmaxf(v, __shfl_xor(v, o, 64));
  return v;
}
__device__ __forceinline__ float wave_sum64(float v) {
#pragma unroll
  for (int o = 32; o > 0; o >>= 1) v += __shfl_xor(v, o, 64);
  return v;
}

__device__ __forceinline__ float leaky02(float v) {
  return v >= 0.0f ? v : 0.2f * v;
}

// ---------------------------------------------------------------- MFMA GEMM
// C[N,KOUT](fp16) = A[N,KIN] @ W[KIN,KOUT] (fp16 compute, fp32 acc).
// Wave computes 16 rows x KOUT cols. A-frag: A[m=lane&15][k=quad*8+j].
// W transposed to LDS fp16, row padded +8 halves to break bank conflicts.
// C/D frag: col = nt*16 + (lane&15), row = quad*4 + r (HW-verified).
// HEADS>0: fused attention coefficients al_s/al_d (dot along features per head)
// computed from fp32 accumulators via shfl_xor reduction over the l16 group.
template <int KIN, int KOUT, bool A_FP32, int HEADS>
__launch_bounds__(BDIM) __global__
void gemm_mfma(const void* __restrict__ Ap, const float* __restrict__ W,
               _Float16* __restrict__ C,
               const float* __restrict__ a_src, const float* __restrict__ a_dst,
               float* __restrict__ al_s, float* __restrict__ al_d, int N) {
  constexpr int KP = KIN + 8;
  constexpr int NT = KOUT / 16;
  __shared__ _Float16 Wt[KOUT * KP];
  int tid = threadIdx.x;
  for (int i = tid; i < KIN * KOUT; i += BDIM) {
    int k = i / KOUT, n = i % KOUT;
    Wt[n * KP + k] = (_Float16)W[i];
  }
  __syncthreads();
  int lane = tid & 63;
  int quad = lane >> 4, l16 = lane & 15;
  int m0 = blockIdx.x * 64 + (tid >> 6) * 16;
  if (m0 >= N) return;  // N % 16 == 0: whole wave in or out
  v4f acc[NT];
#pragma unroll
  for (int nt = 0; nt < NT; ++nt) acc[nt] = (v4f){0.0f, 0.0f, 0.0f, 0.0f};
#pragma unroll
  for (int k0 = 0; k0 < KIN; k0 += 32) {
    v8h a;
    if constexpr (A_FP32) {
      const float* ap = (const float*)Ap + (size_t)(m0 + l16) * KIN + k0 + quad * 8;
#pragma unroll
      for (int j = 0; j < 8; ++j) a[j] = (_Float16)ap[j];
    } else {
      a = *(const v8h*)((const _Float16*)Ap + (size_t)(m0 + l16) * KIN + k0 + quad * 8);
    }
#pragma unroll
    for (int nt = 0; nt < NT; ++nt) {
      v8h b = *(const v8h*)&Wt[(nt * 16 + l16) * KP + k0 + quad * 8];
      acc[nt] = __builtin_amdgcn_mfma_f32_16x16x32_f16(a, b, acc[nt], 0, 0, 0);
    }
  }
#pragma unroll
  for (int nt = 0; nt < NT; ++nt)
#pragma unroll
    for (int r = 0; r < 4; ++r)
      C[(size_t)(m0 + quad * 4 + r) * KOUT + nt * 16 + l16] = (_Float16)acc[nt][r];

  if constexpr (HEADS > 0) {
    constexpr int TPH = NT / HEADS;     // MFMA tiles per head (4 here)
    constexpr int FPH = KOUT / HEADS;   // features per head (64)
    float av_s[NT], av_d[NT];
#pragma unroll
    for (int nt = 0; nt < NT; ++nt) {
      int head = nt / TPH, c = (nt % TPH) * 16 + l16;
      av_s[nt] = a_src[head * FPH + c];
      av_d[nt] = a_dst[head * FPH + c];
    }
#pragma unroll
    for (int r = 0; r < 4; ++r) {
#pragma unroll
      for (int head = 0; head < HEADS; ++head) {
        float ps = 0.0f, pd = 0.0f;
#pragma unroll
        for (int t = 0; t < TPH; ++t) {
          int nt = head * TPH + t;
          ps += acc[nt][r] * av_s[nt];
          pd += acc[nt][r] * av_d[nt];
        }
#pragma unroll
        for (int o = 1; o < 16; o <<= 1) {
          ps += __shfl_xor(ps, o, 64);
          pd += __shfl_xor(pd, o, 64);
        }
        if (l16 == 0) {
          int row = m0 + quad * 4 + r;
          al_s[(size_t)head * N + row] = ps;
          al_d[(size_t)head * N + row] = pd;
        }
      }
    }
  }
}

// ---------------------------------------------------------------- CSR build
__global__ void count_kernel(const int* __restrict__ ei, int E, int N,
                             int* __restrict__ cnt) {
  int t = blockIdx.x * blockDim.x + threadIdx.x;
  if (t >= E + N) return;
  int dst = (t < E) ? ei[E + t] : (t - E);
  atomicAdd(&cnt[dst], 1);
}

__global__ void dis_kernel(const int* __restrict__ cnt, float* __restrict__ dis, int N) {
  int i = blockIdx.x * blockDim.x + threadIdx.x;
  if (i < N) {
    float d = (float)cnt[i];
    dis[i] = (d > 0.0f) ? rsqrtf(fmaxf(d, 1e-12f)) : 0.0f;
  }
}

// single-workgroup hierarchical exclusive scan: cnt[N] -> row_ptr[N+1], cursor[N]
__launch_bounds__(1024) __global__
void scan_kernel(const int* __restrict__ cnt, int N,
                 int* __restrict__ row_ptr, int* __restrict__ cursor) {
  __shared__ int wsum[16], wpre[16];
  __shared__ int carry_s;
  int tid = threadIdx.x, lane = tid & 63, w = tid >> 6;
  if (tid == 0) carry_s = 0;
  __syncthreads();
  for (int base = 0; base < N; base += 1024) {
    int i = base + tid;
    int v = (i < N) ? cnt[i] : 0;
    int incl = v;
#pragma unroll
    for (int off = 1; off < 64; off <<= 1) {
      int t = __shfl_up(incl, off, 64);
      if (lane >= off) incl += t;
    }
    if (lane == 63) wsum[w] = incl;
    __syncthreads();
    if (w == 0 && lane < 16) {
      int s = wsum[lane];
#pragma unroll
      for (int off = 1; off < 16; off <<= 1) {
        int t = __shfl_up(s, off, 64);
        if (lane >= off) s += t;
      }
      wpre[lane] = s - wsum[lane];
    }
    __syncthreads();
    int c = carry_s;
    int excl = c + wpre[w] + incl - v;
    if (i < N) { row_ptr[i] = excl; cursor[i] = excl; }
    __syncthreads();
    if (tid == 1023) carry_s = c + wpre[15] + wsum[15];
    __syncthreads();
  }
  if (tid == 0) row_ptr[N] = carry_s;
}

// scatter sources into CSR slots (int atomics on cursors; csr_src only)
__global__ void csr_fill(const int* __restrict__ ei, int E, int N,
                         int* __restrict__ cursor, int* __restrict__ csr_src) {
  int t = blockIdx.x * blockDim.x + threadIdx.x;
  if (t >= E + N) return;
  int src, dst;
  if (t < E) { src = ei[t]; dst = ei[E + t]; }
  else       { src = dst = t - E; }
  int slot = atomicAdd(&cursor[dst], 1);
  csr_src[slot] = src;
}

// ---------------------------------------------------------------- GCN gather
// wave per dst node, lane = feature; 8-deep batched gather loads; fp16 output.
// norm factorized: out = relu(dis[dst] * sum(dis[src]*h[src]) + b)
__launch_bounds__(BDIM) __global__
void gcn_gather(const __half* __restrict__ h, const int* __restrict__ row_ptr,
                const int* __restrict__ csr_src, const float* __restrict__ dis,
                const float* __restrict__ b, __half* __restrict__ out, int N) {
  constexpr int U = 8;
  int wid = blockIdx.x * (BDIM / 64) + (threadIdx.x >> 6);
  int lane = threadIdx.x & 63;
  if (wid >= N) return;
  int beg = row_ptr[wid], end = row_ptr[wid + 1];
  float acc = 0.0f;
  for (int base = beg; base < end; base += 64) {
    int nch = min(64, end - base);
    int   s_l = (lane < nch) ? csr_src[base + lane] : 0;
    float d_l = (lane < nch) ? dis[s_l] : 0.0f;  // pad lanes contribute 0
    int jmax = (nch + U - 1) & ~(U - 1);
    for (int j = 0; j < jmax; j += U) {
      int ss[U]; float ww[U]; __half vv[U];
#pragma unroll
      for (int u = 0; u < U; ++u) {
        ss[u] = __shfl(s_l, j + u, 64);
        ww[u] = __shfl(d_l, j + u, 64);
      }
#pragma unroll
      for (int u = 0; u < U; ++u) vv[u] = h[(size_t)ss[u] * 64 + lane];
#pragma unroll
      for (int u = 0; u < U; ++u) acc += ww[u] * __half2float(vv[u]);
    }
  }
  out[(size_t)wid * 64 + lane] = __float2half(fmaxf(acc * dis[wid] + b[lane], 0.0f));
}

// ---------------------------------------------------------------- GAT
// wave per (dst, head): segment softmax -> unnormalized alpha per edge + den per dst
// alpha written interleaved: alpha[e*HEADS + hd]
template <int HEADS>
__launch_bounds__(BDIM) __global__
void gat_alpha(const int* __restrict__ row_ptr, const int* __restrict__ csr_src,
               const float* __restrict__ al_s, const float* __restrict__ al_d,
               float* __restrict__ alpha, float* __restrict__ den, int N) {
  int wid = blockIdx.x * (BDIM / 64) + (threadIdx.x >> 6);
  int lane = threadIdx.x & 63;
  if (wid >= N * HEADS) return;
  int dn = wid % N, hd = wid / N;
  const float* als_p = al_s + (size_t)hd * N;
  float ad = al_d[(size_t)hd * N + dn];
  int beg = row_ptr[dn], end = row_ptr[dn + 1];
  int deg = end - beg;
  if (deg <= 64) {  // common case: whole segment in one wave pass
    int   s = (lane < deg) ? csr_src[beg + lane] : 0;
    float e = (lane < deg) ? leaky02(als_p[s] + ad) : -3.4e38f;
    float m = wave_max64(e);
    float ex = (lane < deg) ? expf(e - m) : 0.0f;
    float l = wave_sum64(ex);
    if (lane < deg) alpha[(size_t)(beg + lane) * HEADS + hd] = ex;
    if (lane == 0) den[(size_t)hd * N + dn] = l;
  } else {
    float m = -3.4e38f;
    for (int base = beg; base < end; base += 64) {
      int nch = min(64, end - base);
      int   s = (lane < nch) ? csr_src[base + lane] : 0;
      float e = (lane < nch) ? leaky02(als_p[s] + ad) : -3.4e38f;
      m = fmaxf(m, wave_max64(e));
    }
    float l = 0.0f;
    for (int base = beg; base < end; base += 64) {
      int nch = min(64, end - base);
      int   s = (lane < nch) ? csr_src[base + lane] : 0;
      float e = (lane < nch) ? leaky02(als_p[s] + ad) : -3.4e38f;
      float ex = (lane < nch) ? expf(e - m) : 0.0f;
      if (lane < nch) alpha[(size_t)(base + lane) * HEADS + hd] = ex;
      l += wave_sum64(ex);
    }
    if (lane == 0) den[(size_t)hd * N + dn] = l;
  }
}

// GAT layer-1 accumulate, BOTH heads per wave. Row = 256B (__half2 per lane).
// lane covers combined features (2*lane, 2*lane+1); head = lane>>5. fp16 output.
__launch_bounds__(BDIM) __global__
void gat_acc2(const __half* __restrict__ h, const int* __restrict__ row_ptr,
              const int* __restrict__ csr_src, const float2* __restrict__ alpha2,
              const float* __restrict__ den, const float* __restrict__ b,
              __half* __restrict__ out, int N) {
  constexpr int U = 8;
  int wid = blockIdx.x * (BDIM / 64) + (threadIdx.x >> 6);
  int lane = threadIdx.x & 63;
  if (wid >= N) return;
  int head = lane >> 5;
  const __half2* hrow = (const __half2*)h;  // 64 half2 per node row
  int beg = row_ptr[wid], end = row_ptr[wid + 1];
  float accx = 0.0f, accy = 0.0f;
  for (int base = beg; base < end; base += 64) {
    int nch = min(64, end - base);
    int    s_l = (lane < nch) ? csr_src[base + lane] : 0;
    float2 a_l = (lane < nch) ? alpha2[base + lane] : make_float2(0.0f, 0.0f);
    int jmax = (nch + U - 1) & ~(U - 1);
    for (int j = 0; j < jmax; j += U) {
      int ss[U]; float aa[U]; __half2 vv[U];
#pragma unroll
      for (int u = 0; u < U; ++u) {
        ss[u] = __shfl(s_l, j + u, 64);
        float a0 = __shfl(a_l.x, j + u, 64);
        float a1 = __shfl(a_l.y, j + u, 64);
        aa[u] = head ? a1 : a0;
      }
#pragma unroll
      for (int u = 0; u < U; ++u) vv[u] = hrow[(size_t)ss[u] * 64 + lane];
#pragma unroll
      for (int u = 0; u < U; ++u) {
        float2 v = __half22float2(vv[u]);
        accx += aa[u] * v.x;
        accy += aa[u] * v.y;
      }
    }
  }
  float dn = den[(size_t)head * N + wid];
  const float2* b2v = (const float2*)b;
  float2 bb = b2v[lane];
  float ox = fmaxf(accx / dn + bb.x, 0.0f);  // relu fused (layer 1 always relu)
  float oy = fmaxf(accy / dn + bb.y, 0.0f);
  ((__half2*)out)[(size_t)wid * 64 + lane] = __floats2half2_rn(ox, oy);
}

// GAT layer-2 accumulate (1 head, 64 feats), 8-deep batched loads; fp32 out.
__launch_bounds__(BDIM) __global__
void gat_acc1(const __half* __restrict__ h, const int* __restrict__ row_ptr,
              const int* __restrict__ csr_src, const float* __restrict__ alpha,
              const float* __restrict__ den, const float* __restrict__ b,
              float* __restrict__ out, int N) {
  constexpr int U = 8;
  int wid = blockIdx.x * (BDIM / 64) + (threadIdx.x >> 6);
  int lane = threadIdx.x & 63;
  if (wid >= N) return;
  int beg = row_ptr[wid], end = row_ptr[wid + 1];
  float acc = 0.0f;
  for (int base = beg; base < end; base += 64) {
    int nch = min(64, end - base);
    int   s_l = (lane < nch) ? csr_src[base + lane] : 0;
    float a_l = (lane < nch) ? alpha[base + lane] : 0.0f;
    int jmax = (nch + U - 1) & ~(U - 1);
    for (int j = 0; j < jmax; j += U) {
      int ss[U]; float aa[U]; __half vv[U];
#pragma unroll
      for (int u = 0; u < U; ++u) {
        ss[u] = __shfl(s_l, j + u, 64);
        aa[u] = __shfl(a_l, j + u, 64);
      }
#pragma unroll
      for (int u = 0; u < U; ++u) vv[u] = h[(size_t)ss[u] * 64 + lane];
#pragma unroll
      for (int u = 0; u < U; ++u) acc += aa[u] * __half2float(vv[u]);
    }
  }
  out[(size_t)wid * 64 + lane] = acc / den[wid] + b[lane];  // no relu on layer 2
}

// ---------------------------------------------------------------- pool + head
__device__ __forceinline__ int lower_bound(const int* __restrict__ a, int n, int v) {
  int lo = 0, hi = n;
  while (lo < hi) {
    int mid = (lo + hi) >> 1;
    if (a[mid] < v) lo = mid + 1; else hi = mid;
  }
  return lo;
}

// wave per graph: batch is sorted -> contiguous node range; no atomics
__launch_bounds__(BDIM) __global__
void pool_final(const float* __restrict__ x3, const int* __restrict__ batch,
                const float* __restrict__ Wfc, const float* __restrict__ bfc,
                float* __restrict__ out, int N, int G) {
  int wid = blockIdx.x * (BDIM / 64) + (threadIdx.x >> 6);
  int lane = threadIdx.x & 63;
  if (wid >= G) return;
  int beg = lower_bound(batch, N, wid);
  int end = lower_bound(batch, N, wid + 1);
  float acc = 0.0f;
  for (int n = beg; n < end; ++n) acc += x3[(size_t)n * 64 + lane];
  float p = (end > beg) ? acc / (float)(end - beg) : 0.0f;
  float l0 = wave_sum64(p * Wfc[lane * 2 + 0]);
  float l1 = wave_sum64(p * Wfc[lane * 2 + 1]);
  if (lane == 0) {
    l0 += bfc[0];
    l1 += bfc[1];
    float m = fmaxf(l0, l1);
    float ls = m + logf(expf(l0 - m) + expf(l1 - m));
    out[wid * 2 + 0] = l0 - ls;
    out[wid * 2 + 1] = l1 - ls;
  }
}

// ---------------------------------------------------------------- launch

static inline int cdiv(int a, int b) { return (a + b - 1) / b; }

extern "C" void kernel_launch(void* const* d_in, const int* in_sizes, int n_in,
                              void* d_out, int out_size, void* d_ws, size_t ws_size,
                              hipStream_t stream) {
  const float* x      = (const float*)d_in[0];
  const int*   ei     = (const int*)d_in[1];
  const int*   batch  = (const int*)d_in[2];
  const float* W1     = (const float*)d_in[3];
  const float* b1     = (const float*)d_in[4];
  const float* W2     = (const float*)d_in[5];
  const float* a_src2 = (const float*)d_in[6];
  const float* a_dst2 = (const float*)d_in[7];
  const float* b2     = (const float*)d_in[8];
  const float* W3     = (const float*)d_in[9];
  const float* a_src3 = (const float*)d_in[10];
  const float* a_dst3 = (const float*)d_in[11];
  const float* b3     = (const float*)d_in[12];
  const float* Wfc    = (const float*)d_in[13];
  const float* bfc    = (const float*)d_in[14];
  float* out = (float*)d_out;

  const int N = in_sizes[2];       // 50000
  const int E = in_sizes[1] / 2;   // 800000
  const int G = out_size / 2;      // 512
  const int TOT = E + N;           // edges incl. self-loops

  // workspace layout (~60 MB), fp16 buffers first (16B-aligned offsets)
  char* wsb = (char*)d_ws;
  __half* h1    = (__half*)wsb;                       // N*64 fp16
  __half* h2    = h1 + (size_t)N * 64;                // N*128 fp16 (reused as h3)
  __half* out1h = h2 + (size_t)N * 128;               // N*64 fp16 (x1)
  __half* out2h = out1h + (size_t)N * 64;             // N*128 fp16 (x2)
  float*  out3  = (float*)(out2h + (size_t)N * 128);  // N*64 f32 (x3)
  float*  alpha = out3 + (size_t)N * 64;              // TOT*2 f32
  float*  dis   = alpha + (size_t)TOT * 2;            // N
  float*  al_s  = dis + N;                            // N*2 planar
  float*  al_d  = al_s + (size_t)N * 2;               // N*2 planar
  float*  den   = al_d + (size_t)N * 2;               // N*2 planar
  int* cnt      = (int*)(den + (size_t)N * 2);        // N
  int* cursor   = cnt + N;                            // N
  int* csr_src  = cursor + N;                         // TOT
  int* row_ptr  = csr_src + TOT;                      // N+1

  // ---- CSR build (reused by all three layers)
  fill_int_kernel<<<cdiv(N, BDIM), BDIM, 0, stream>>>(cnt, 0, N);
  count_kernel<<<cdiv(TOT, BDIM), BDIM, 0, stream>>>(ei, E, N, cnt);
  dis_kernel<<<cdiv(N, BDIM), BDIM, 0, stream>>>(cnt, dis, N);
  scan_kernel<<<1, 1024, 0, stream>>>(cnt, N, row_ptr, cursor);
  csr_fill<<<cdiv(TOT, BDIM), BDIM, 0, stream>>>(ei, E, N, cursor, csr_src);

  // ---- GCN layer
  gemm_mfma<128, 64, true, 0><<<cdiv(N, 64), BDIM, 0, stream>>>(
      x, W1, (_Float16*)h1, nullptr, nullptr, nullptr, nullptr, N);
  gcn_gather<<<cdiv(N, 4), BDIM, 0, stream>>>(h1, row_ptr, csr_src, dis, b1, out1h, N);

  // ---- GAT layer 1 (heads=2, concat; att_coef fused into GEMM epilogue)
  gemm_mfma<64, 128, false, 2><<<cdiv(N, 64), BDIM, 0, stream>>>(
      out1h, W2, (_Float16*)h2, a_src2, a_dst2, al_s, al_d, N);
  gat_alpha<2><<<cdiv(N * 2, 4), BDIM, 0, stream>>>(row_ptr, csr_src, al_s, al_d,
                                                    alpha, den, N);
  gat_acc2<<<cdiv(N, 4), BDIM, 0, stream>>>(h2, row_ptr, csr_src, (const float2*)alpha,
                                            den, b2, out2h, N);

  // ---- GAT layer 2 (heads=1, mean == identity)
  __half* h3 = h2;  // h2 dead after gat_acc2
  gemm_mfma<128, 64, false, 1><<<cdiv(N, 64), BDIM, 0, stream>>>(
      out2h, W3, (_Float16*)h3, a_src3, a_dst3, al_s, al_d, N);
  gat_alpha<1><<<cdiv(N, 4), BDIM, 0, stream>>>(row_ptr, csr_src, al_s, al_d,
                                                alpha, den, N);
  gat_acc1<<<cdiv(N, 4), BDIM, 0, stream>>>(h3, row_ptr, csr_src, alpha, den,
                                            b3, out3, N);

  // ---- global mean pool + fc + log_softmax (atomic-free; batch is sorted)
  pool_final<<<cdiv(G, 4), BDIM, 0, stream>>>(out3, batch, Wfc, bfc, out, N, G);
}

// Round 8
// 379.143 us; speedup vs baseline: 3.6899x; 1.1493x over previous
//
#include <hip/hip_runtime.h>
#include <hip/hip_bf16.h>
#include <hip/hip_fp16.h>
#include <math.h>

#define BDIM 256

using v8h = __attribute__((ext_vector_type(8))) _Float16;
using v4f = __attribute__((ext_vector_type(4))) float;

// CSR-build tuning: 512 dst-range buckets, 8192-edge chunks, 4096-edge bucket cap
#define NB  512
#define CH  8192
#define CAP 4096

// ---------------------------------------------------------------- utilities

__device__ __forceinline__ float wave_max64(float v) {
#pragma unroll
  for (int o = 32; o > 0; o >>= 1) v = fmaxf(v, __shfl_xor(v, o, 64));
  return v;
}
__device__ __forceinline__ float wave_sum64(float v) {
#pragma unroll
  for (int o = 32; o > 0; o >>= 1) v += __shfl_xor(v, o, 64);
  return v;
}

__device__ __forceinline__ float leaky02(float v) {
  return v >= 0.0f ? v : 0.2f * v;
}

// ---------------------------------------------------------------- MFMA GEMM
// C[N,KOUT](fp16) = A[N,KIN] @ W[KIN,KOUT] (fp16 compute, fp32 acc).
// Wave computes 16 rows x KOUT cols. A-frag: A[m=lane&15][k=quad*8+j].
// W transposed to LDS fp16, row padded +8 halves to break bank conflicts.
// C/D frag: col = nt*16 + (lane&15), row = quad*4 + r (HW-verified).
// HEADS>0: fused attention coefficients al_s/al_d from fp32 accumulators.
template <int KIN, int KOUT, bool A_FP32, int HEADS>
__launch_bounds__(BDIM) __global__
void gemm_mfma(const void* __restrict__ Ap, const float* __restrict__ W,
               _Float16* __restrict__ C,
               const float* __restrict__ a_src, const float* __restrict__ a_dst,
               float* __restrict__ al_s, float* __restrict__ al_d, int N) {
  constexpr int KP = KIN + 8;
  constexpr int NT = KOUT / 16;
  __shared__ _Float16 Wt[KOUT * KP];
  int tid = threadIdx.x;
  for (int i = tid; i < KIN * KOUT; i += BDIM) {
    int k = i / KOUT, n = i % KOUT;
    Wt[n * KP + k] = (_Float16)W[i];
  }
  __syncthreads();
  int lane = tid & 63;
  int quad = lane >> 4, l16 = lane & 15;
  int m0 = blockIdx.x * 64 + (tid >> 6) * 16;
  if (m0 >= N) return;  // N % 16 == 0: whole wave in or out
  v4f acc[NT];
#pragma unroll
  for (int nt = 0; nt < NT; ++nt) acc[nt] = (v4f){0.0f, 0.0f, 0.0f, 0.0f};
#pragma unroll
  for (int k0 = 0; k0 < KIN; k0 += 32) {
    v8h a;
    if constexpr (A_FP32) {
      const float* ap = (const float*)Ap + (size_t)(m0 + l16) * KIN + k0 + quad * 8;
#pragma unroll
      for (int j = 0; j < 8; ++j) a[j] = (_Float16)ap[j];
    } else {
      a = *(const v8h*)((const _Float16*)Ap + (size_t)(m0 + l16) * KIN + k0 + quad * 8);
    }
#pragma unroll
    for (int nt = 0; nt < NT; ++nt) {
      v8h b = *(const v8h*)&Wt[(nt * 16 + l16) * KP + k0 + quad * 8];
      acc[nt] = __builtin_amdgcn_mfma_f32_16x16x32_f16(a, b, acc[nt], 0, 0, 0);
    }
  }
#pragma unroll
  for (int nt = 0; nt < NT; ++nt)
#pragma unroll
    for (int r = 0; r < 4; ++r)
      C[(size_t)(m0 + quad * 4 + r) * KOUT + nt * 16 + l16] = (_Float16)acc[nt][r];

  if constexpr (HEADS > 0) {
    constexpr int TPH = NT / HEADS;     // MFMA tiles per head
    constexpr int FPH = KOUT / HEADS;   // features per head
    float av_s[NT], av_d[NT];
#pragma unroll
    for (int nt = 0; nt < NT; ++nt) {
      int head = nt / TPH, c = (nt % TPH) * 16 + l16;
      av_s[nt] = a_src[head * FPH + c];
      av_d[nt] = a_dst[head * FPH + c];
    }
#pragma unroll
    for (int r = 0; r < 4; ++r) {
#pragma unroll
      for (int head = 0; head < HEADS; ++head) {
        float ps = 0.0f, pd = 0.0f;
#pragma unroll
        for (int t = 0; t < TPH; ++t) {
          int nt = head * TPH + t;
          ps += acc[nt][r] * av_s[nt];
          pd += acc[nt][r] * av_d[nt];
        }
#pragma unroll
        for (int o = 1; o < 16; o <<= 1) {
          ps += __shfl_xor(ps, o, 64);
          pd += __shfl_xor(pd, o, 64);
        }
        if (l16 == 0) {
          int row = m0 + quad * 4 + r;
          al_s[(size_t)head * N + row] = ps;
          al_d[(size_t)head * N + row] = pd;
        }
      }
    }
  }
}

// ---------------------------------------------------------------- CSR build
// Atomic-free (LDS atomics only): hist -> scan -> bucket scatter -> per-bucket CSR.

// Pass A: per-chunk LDS histogram over NB dst-range buckets; coalesced count dump.
__launch_bounds__(BDIM) __global__
void hist_a(const int* __restrict__ ei, int E, int TOT, int bw,
            int* __restrict__ counts, int nWG) {
  __shared__ int hist[NB];
  int tid = threadIdx.x, wg = blockIdx.x;
  for (int i = tid; i < NB; i += BDIM) hist[i] = 0;
  __syncthreads();
  int base = wg * CH, lim = min(CH, TOT - base);
  for (int i = tid; i < lim; i += BDIM) {
    int e = base + i;
    int dst = (e < E) ? ei[E + e] : (e - E);
    atomicAdd(&hist[dst / bw], 1);
  }
  __syncthreads();
  for (int b = tid; b < NB; b += BDIM) counts[(size_t)b * nWG + wg] = hist[b];
}

// single-WG exclusive scan of counts[M] -> off[M]; also row_ptr[N] = TOT
__launch_bounds__(1024) __global__
void scan_all(const int* __restrict__ counts, int M,
              int* __restrict__ off, int* __restrict__ row_ptr, int N, int TOT) {
  __shared__ int wsum[16], wpre[16];
  __shared__ int carry_s;
  int tid = threadIdx.x, lane = tid & 63, w = tid >> 6;
  if (tid == 0) carry_s = 0;
  __syncthreads();
  for (int base = 0; base < M; base += 1024) {
    int i = base + tid;
    int v = (i < M) ? counts[i] : 0;
    int incl = v;
#pragma unroll
    for (int o = 1; o < 64; o <<= 1) {
      int t = __shfl_up(incl, o, 64);
      if (lane >= o) incl += t;
    }
    if (lane == 63) wsum[w] = incl;
    __syncthreads();
    if (w == 0 && lane < 16) {
      int s = wsum[lane];
#pragma unroll
      for (int o = 1; o < 16; o <<= 1) {
        int t = __shfl_up(s, o, 64);
        if (lane >= o) s += t;
      }
      wpre[lane] = s - wsum[lane];
    }
    __syncthreads();
    int c = carry_s;
    if (i < M) off[i] = c + wpre[w] + incl - v;
    __syncthreads();
    if (tid == 1023) carry_s = c + wpre[15] + wsum[15];
    __syncthreads();
  }
  if (tid == 0) row_ptr[N] = TOT;
}

// Pass B: scatter edges into bucket-major ebuf, packed (dst_local<<17 | src).
__launch_bounds__(BDIM) __global__
void bucket_b(const int* __restrict__ ei, int E, int TOT, int bw,
              const int* __restrict__ off, int nWG, unsigned int* __restrict__ ebuf) {
  __shared__ int cur[NB];
  int tid = threadIdx.x, wg = blockIdx.x;
  for (int b = tid; b < NB; b += BDIM) cur[b] = off[(size_t)b * nWG + wg];
  __syncthreads();
  int base = wg * CH, lim = min(CH, TOT - base);
  for (int i = tid; i < lim; i += BDIM) {
    int e = base + i;
    int src, dst;
    if (e < E) { src = ei[e]; dst = ei[E + e]; }
    else       { src = dst = e - E; }
    int b = dst / bw;
    int pos = atomicAdd(&cur[b], 1);
    ebuf[pos] = ((unsigned int)(dst - b * bw) << 17) | (unsigned int)src;
  }
}

// Pass C: one WG per bucket. Build CSR segment fully in LDS; all global IO coalesced.
__launch_bounds__(BDIM) __global__
void csr_c(const unsigned int* __restrict__ ebuf, const int* __restrict__ off,
           int nWG, int N, int TOT, int bw,
           int* __restrict__ row_ptr, float* __restrict__ dis,
           int* __restrict__ csr_src) {
  __shared__ unsigned int eb[CAP];
  __shared__ unsigned int ob[CAP];
  __shared__ int cnt[128], loff[128], cur[128];
  int tid = threadIdx.x, b = blockIdx.x;
  int d0 = b * bw;
  if (d0 >= N) return;
  int width = min(bw, N - d0);
  int sbase = off[(size_t)b * nWG];
  int send = (b == NB - 1) ? TOT : off[(size_t)(b + 1) * nWG];
  int nb = send - sbase;
  if (tid < 128) cnt[tid] = 0;
  __syncthreads();
  for (int i = tid; i < nb; i += BDIM) {
    unsigned int v = ebuf[sbase + i];
    eb[i] = v;
    atomicAdd(&cnt[v >> 17], 1);
  }
  __syncthreads();
  if (tid < 64) {  // wave 0: exclusive scan of 128 counters (2 per lane)
    int c0 = cnt[tid * 2], c1 = cnt[tid * 2 + 1];
    int s = c0 + c1;
    int incl = s;
#pragma unroll
    for (int o = 1; o < 64; o <<= 1) {
      int t = __shfl_up(incl, o, 64);
      if (tid >= o) incl += t;
    }
    int excl = incl - s;
    loff[tid * 2] = excl;
    loff[tid * 2 + 1] = excl + c0;
  }
  __syncthreads();
  if (tid < width) {
    row_ptr[d0 + tid] = sbase + loff[tid];
    dis[d0 + tid] = rsqrtf((float)cnt[tid]);  // deg >= 1 (self-loops)
    cur[tid] = loff[tid];
  }
  __syncthreads();
  for (int i = tid; i < nb; i += BDIM) {
    unsigned int v = eb[i];
    int p = atomicAdd(&cur[v >> 17], 1);
    ob[p] = v & 0x1FFFFu;
  }
  __syncthreads();
  for (int i = tid; i < nb; i += BDIM) csr_src[sbase + i] = (int)ob[i];
}

// ---------------------------------------------------------------- GCN gather
// wave per dst node, lane = feature; 8-deep batched gather loads; fp16 output.
// norm factorized: out = relu(dis[dst] * sum(dis[src]*h[src]) + b)
__launch_bounds__(BDIM) __global__
void gcn_gather(const __half* __restrict__ h, const int* __restrict__ row_ptr,
                const int* __restrict__ csr_src, const float* __restrict__ dis,
                const float* __restrict__ b, __half* __restrict__ out, int N) {
  constexpr int U = 8;
  int wid = blockIdx.x * (BDIM / 64) + (threadIdx.x >> 6);
  int lane = threadIdx.x & 63;
  if (wid >= N) return;
  int beg = row_ptr[wid], end = row_ptr[wid + 1];
  float acc = 0.0f;
  for (int base = beg; base < end; base += 64) {
    int nch = min(64, end - base);
    int   s_l = (lane < nch) ? csr_src[base + lane] : 0;
    float d_l = (lane < nch) ? dis[s_l] : 0.0f;  // pad lanes contribute 0
    int jmax = (nch + U - 1) & ~(U - 1);
    for (int j = 0; j < jmax; j += U) {
      int ss[U]; float ww[U]; __half vv[U];
#pragma unroll
      for (int u = 0; u < U; ++u) {
        ss[u] = __shfl(s_l, j + u, 64);
        ww[u] = __shfl(d_l, j + u, 64);
      }
#pragma unroll
      for (int u = 0; u < U; ++u) vv[u] = h[(size_t)ss[u] * 64 + lane];
#pragma unroll
      for (int u = 0; u < U; ++u) acc += ww[u] * __half2float(vv[u]);
    }
  }
  out[(size_t)wid * 64 + lane] = __float2half(fmaxf(acc * dis[wid] + b[lane], 0.0f));
}

// ---------------------------------------------------------------- GAT
// wave per (dst, head): segment softmax -> unnormalized alpha per edge + den per dst
// alpha written interleaved: alpha[e*HEADS + hd]
template <int HEADS>
__launch_bounds__(BDIM) __global__
void gat_alpha(const int* __restrict__ row_ptr, const int* __restrict__ csr_src,
               const float* __restrict__ al_s, const float* __restrict__ al_d,
               float* __restrict__ alpha, float* __restrict__ den, int N) {
  int wid = blockIdx.x * (BDIM / 64) + (threadIdx.x >> 6);
  int lane = threadIdx.x & 63;
  if (wid >= N * HEADS) return;
  int dn = wid % N, hd = wid / N;
  const float* als_p = al_s + (size_t)hd * N;
  float ad = al_d[(size_t)hd * N + dn];
  int beg = row_ptr[dn], end = row_ptr[dn + 1];
  int deg = end - beg;
  if (deg <= 64) {  // common case: whole segment in one wave pass
    int   s = (lane < deg) ? csr_src[beg + lane] : 0;
    float e = (lane < deg) ? leaky02(als_p[s] + ad) : -3.4e38f;
    float m = wave_max64(e);
    float ex = (lane < deg) ? expf(e - m) : 0.0f;
    float l = wave_sum64(ex);
    if (lane < deg) alpha[(size_t)(beg + lane) * HEADS + hd] = ex;
    if (lane == 0) den[(size_t)hd * N + dn] = l;
  } else {
    float m = -3.4e38f;
    for (int base = beg; base < end; base += 64) {
      int nch = min(64, end - base);
      int   s = (lane < nch) ? csr_src[base + lane] : 0;
      float e = (lane < nch) ? leaky02(als_p[s] + ad) : -3.4e38f;
      m = fmaxf(m, wave_max64(e));
    }
    float l = 0.0f;
    for (int base = beg; base < end; base += 64) {
      int nch = min(64, end - base);
      int   s = (lane < nch) ? csr_src[base + lane] : 0;
      float e = (lane < nch) ? leaky02(als_p[s] + ad) : -3.4e38f;
      float ex = (lane < nch) ? expf(e - m) : 0.0f;
      if (lane < nch) alpha[(size_t)(base + lane) * HEADS + hd] = ex;
      l += wave_sum64(ex);
    }
    if (lane == 0) den[(size_t)hd * N + dn] = l;
  }
}

// GAT layer-1 accumulate, BOTH heads per wave. Row = 256B (__half2 per lane).
__launch_bounds__(BDIM) __global__
void gat_acc2(const __half* __restrict__ h, const int* __restrict__ row_ptr,
              const int* __restrict__ csr_src, const float2* __restrict__ alpha2,
              const float* __restrict__ den, const float* __restrict__ b,
              __half* __restrict__ out, int N) {
  constexpr int U = 8;
  int wid = blockIdx.x * (BDIM / 64) + (threadIdx.x >> 6);
  int lane = threadIdx.x & 63;
  if (wid >= N) return;
  int head = lane >> 5;
  const __half2* hrow = (const __half2*)h;  // 64 half2 per node row
  int beg = row_ptr[wid], end = row_ptr[wid + 1];
  float accx = 0.0f, accy = 0.0f;
  for (int base = beg; base < end; base += 64) {
    int nch = min(64, end - base);
    int    s_l = (lane < nch) ? csr_src[base + lane] : 0;
    float2 a_l = (lane < nch) ? alpha2[base + lane] : make_float2(0.0f, 0.0f);
    int jmax = (nch + U - 1) & ~(U - 1);
    for (int j = 0; j < jmax; j += U) {
      int ss[U]; float aa[U]; __half2 vv[U];
#pragma unroll
      for (int u = 0; u < U; ++u) {
        ss[u] = __shfl(s_l, j + u, 64);
        float a0 = __shfl(a_l.x, j + u, 64);
        float a1 = __shfl(a_l.y, j + u, 64);
        aa[u] = head ? a1 : a0;
      }
#pragma unroll
      for (int u = 0; u < U; ++u) vv[u] = hrow[(size_t)ss[u] * 64 + lane];
#pragma unroll
      for (int u = 0; u < U; ++u) {
        float2 v = __half22float2(vv[u]);
        accx += aa[u] * v.x;
        accy += aa[u] * v.y;
      }
    }
  }
  float dn = den[(size_t)head * N + wid];
  const float2* b2v = (const float2*)b;
  float2 bb = b2v[lane];
  float ox = fmaxf(accx / dn + bb.x, 0.0f);  // relu fused
  float oy = fmaxf(accy / dn + bb.y, 0.0f);
  ((__half2*)out)[(size_t)wid * 64 + lane] = __floats2half2_rn(ox, oy);
}

// GAT layer-2 accumulate (1 head, 64 feats), 8-deep batched loads; fp32 out.
__launch_bounds__(BDIM) __global__
void gat_acc1(const __half* __restrict__ h, const int* __restrict__ row_ptr,
              const int* __restrict__ csr_src, const float* __restrict__ alpha,
              const float* __restrict__ den, const float* __restrict__ b,
              float* __restrict__ out, int N) {
  constexpr int U = 8;
  int wid = blockIdx.x * (BDIM / 64) + (threadIdx.x >> 6);
  int lane = threadIdx.x & 63;
  if (wid >= N) return;
  int beg = row_ptr[wid], end = row_ptr[wid + 1];
  float acc = 0.0f;
  for (int base = beg; base < end; base += 64) {
    int nch = min(64, end - base);
    int   s_l = (lane < nch) ? csr_src[base + lane] : 0;
    float a_l = (lane < nch) ? alpha[base + lane] : 0.0f;
    int jmax = (nch + U - 1) & ~(U - 1);
    for (int j = 0; j < jmax; j += U) {
      int ss[U]; float aa[U]; __half vv[U];
#pragma unroll
      for (int u = 0; u < U; ++u) {
        ss[u] = __shfl(s_l, j + u, 64);
        aa[u] = __shfl(a_l, j + u, 64);
      }
#pragma unroll
      for (int u = 0; u < U; ++u) vv[u] = h[(size_t)ss[u] * 64 + lane];
#pragma unroll
      for (int u = 0; u < U; ++u) acc += aa[u] * __half2float(vv[u]);
    }
  }
  out[(size_t)wid * 64 + lane] = acc / den[wid] + b[lane];  // no relu on layer 2
}

// ---------------------------------------------------------------- pool + head
__device__ __forceinline__ int lower_bound(const int* __restrict__ a, int n, int v) {
  int lo = 0, hi = n;
  while (lo < hi) {
    int mid = (lo + hi) >> 1;
    if (a[mid] < v) lo = mid + 1; else hi = mid;
  }
  return lo;
}

// wave per graph: batch is sorted -> contiguous node range; no atomics
__launch_bounds__(BDIM) __global__
void pool_final(const float* __restrict__ x3, const int* __restrict__ batch,
                const float* __restrict__ Wfc, const float* __restrict__ bfc,
                float* __restrict__ out, int N, int G) {
  int wid = blockIdx.x * (BDIM / 64) + (threadIdx.x >> 6);
  int lane = threadIdx.x & 63;
  if (wid >= G) return;
  int beg = lower_bound(batch, N, wid);
  int end = lower_bound(batch, N, wid + 1);
  float acc = 0.0f;
  for (int n = beg; n < end; ++n) acc += x3[(size_t)n * 64 + lane];
  float p = (end > beg) ? acc / (float)(end - beg) : 0.0f;
  float l0 = wave_sum64(p * Wfc[lane * 2 + 0]);
  float l1 = wave_sum64(p * Wfc[lane * 2 + 1]);
  if (lane == 0) {
    l0 += bfc[0];
    l1 += bfc[1];
    float m = fmaxf(l0, l1);
    float ls = m + logf(expf(l0 - m) + expf(l1 - m));
    out[wid * 2 + 0] = l0 - ls;
    out[wid * 2 + 1] = l1 - ls;
  }
}

// ---------------------------------------------------------------- launch

static inline int cdiv(int a, int b) { return (a + b - 1) / b; }

extern "C" void kernel_launch(void* const* d_in, const int* in_sizes, int n_in,
                              void* d_out, int out_size, void* d_ws, size_t ws_size,
                              hipStream_t stream) {
  const float* x      = (const float*)d_in[0];
  const int*   ei     = (const int*)d_in[1];
  const int*   batch  = (const int*)d_in[2];
  const float* W1     = (const float*)d_in[3];
  const float* b1     = (const float*)d_in[4];
  const float* W2     = (const float*)d_in[5];
  const float* a_src2 = (const float*)d_in[6];
  const float* a_dst2 = (const float*)d_in[7];
  const float* b2     = (const float*)d_in[8];
  const float* W3     = (const float*)d_in[9];
  const float* a_src3 = (const float*)d_in[10];
  const float* a_dst3 = (const float*)d_in[11];
  const float* b3     = (const float*)d_in[12];
  const float* Wfc    = (const float*)d_in[13];
  const float* bfc    = (const float*)d_in[14];
  float* out = (float*)d_out;

  const int N = in_sizes[2];       // 50000
  const int E = in_sizes[1] / 2;   // 800000
  const int G = out_size / 2;      // 512
  const int TOT = E + N;           // edges incl. self-loops
  const int bw  = cdiv(N, NB);     // dst-range per bucket (98)
  const int nWG = cdiv(TOT, CH);   // chunks (104)
  const int M   = NB * nWG;        // count-matrix size

  // workspace layout (~70 MB), fp16 buffers first (16B-aligned offsets)
  char* wsb = (char*)d_ws;
  __half* h1    = (__half*)wsb;                       // N*64 fp16
  __half* h2    = h1 + (size_t)N * 64;                // N*128 fp16 (reused as h3)
  __half* out1h = h2 + (size_t)N * 128;               // N*64 fp16 (x1)
  __half* out2h = out1h + (size_t)N * 64;             // N*128 fp16 (x2)
  float*  out3  = (float*)(out2h + (size_t)N * 128);  // N*64 f32 (x3)
  float*  alpha = out3 + (size_t)N * 64;              // TOT*2 f32
  float*  dis   = alpha + (size_t)TOT * 2;            // N
  float*  al_s  = dis + N;                            // N*2 planar
  float*  al_d  = al_s + (size_t)N * 2;               // N*2 planar
  float*  den   = al_d + (size_t)N * 2;               // N*2 planar
  int* counts   = (int*)(den + (size_t)N * 2);        // M
  int* off      = counts + M;                         // M
  unsigned int* ebuf = (unsigned int*)(off + M);      // TOT
  int* csr_src  = (int*)(ebuf + TOT);                 // TOT
  int* row_ptr  = csr_src + TOT;                      // N+1

  // ---- CSR build: atomic-free radix bucketing (LDS atomics only)
  hist_a<<<nWG, BDIM, 0, stream>>>(ei, E, TOT, bw, counts, nWG);
  scan_all<<<1, 1024, 0, stream>>>(counts, M, off, row_ptr, N, TOT);
  bucket_b<<<nWG, BDIM, 0, stream>>>(ei, E, TOT, bw, off, nWG, ebuf);
  csr_c<<<NB, BDIM, 0, stream>>>(ebuf, off, nWG, N, TOT, bw, row_ptr, dis, csr_src);

  // ---- GCN layer
  gemm_mfma<128, 64, true, 0><<<cdiv(N, 64), BDIM, 0, stream>>>(
      x, W1, (_Float16*)h1, nullptr, nullptr, nullptr, nullptr, N);
  gcn_gather<<<cdiv(N, 4), BDIM, 0, stream>>>(h1, row_ptr, csr_src, dis, b1, out1h, N);

  // ---- GAT layer 1 (heads=2, concat; att_coef fused into GEMM epilogue)
  gemm_mfma<64, 128, false, 2><<<cdiv(N, 64), BDIM, 0, stream>>>(
      out1h, W2, (_Float16*)h2, a_src2, a_dst2, al_s, al_d, N);
  gat_alpha<2><<<cdiv(N * 2, 4), BDIM, 0, stream>>>(row_ptr, csr_src, al_s, al_d,
                                                    alpha, den, N);
  gat_acc2<<<cdiv(N, 4), BDIM, 0, stream>>>(h2, row_ptr, csr_src, (const float2*)alpha,
                                            den, b2, out2h, N);

  // ---- GAT layer 2 (heads=1, mean == identity)
  __half* h3 = h2;  // h2 dead after gat_acc2
  gemm_mfma<128, 64, false, 1><<<cdiv(N, 64), BDIM, 0, stream>>>(
      out2h, W3, (_Float16*)h3, a_src3, a_dst3, al_s, al_d, N);
  gat_alpha<1><<<cdiv(N, 4), BDIM, 0, stream>>>(row_ptr, csr_src, al_s, al_d,
                                                alpha, den, N);
  gat_acc1<<<cdiv(N, 4), BDIM, 0, stream>>>(h3, row_ptr, csr_src, alpha, den,
                                            b3, out3, N);

  // ---- global mean pool + fc + log_softmax (atomic-free; batch is sorted)
  pool_final<<<cdiv(G, 4), BDIM, 0, stream>>>(out3, batch, Wfc, bfc, out, N, G);
}

// Round 9
// 330.065 us; speedup vs baseline: 4.2385x; 1.1487x over previous
//
#include <hip/hip_runtime.h>
#include <hip/hip_bf16.h>
#include <hip/hip_fp16.h>
#include <math.h>

#define BDIM 256

using v8h = __attribute__((ext_vector_type(8))) _Float16;
using v4f = __attribute__((ext_vector_type(4))) float;

// CSR-build tuning: 512 dst-range buckets, 8192-edge chunks, 4096-edge bucket cap
#define NB  512
#define CH  8192
#define CAP 4096

// ---------------------------------------------------------------- utilities

__device__ __forceinline__ float wave_max64(float v) {
#pragma unroll
  for (int o = 32; o > 0; o >>= 1) v = fmaxf(v, __shfl_xor(v, o, 64));
  return v;
}
__device__ __forceinline__ float wave_sum64(float v) {
#pragma unroll
  for (int o = 32; o > 0; o >>= 1) v += __shfl_xor(v, o, 64);
  return v;
}

__device__ __forceinline__ float leaky02(float v) {
  return v >= 0.0f ? v : 0.2f * v;
}

// ---------------------------------------------------------------- MFMA GEMM
// C[N,KOUT](fp16) = A[N,KIN] @ W[KIN,KOUT] (fp16 compute, fp32 acc).
// Wave computes 16 rows x KOUT cols. A-frag: A[m=lane&15][k=quad*8+j].
// W transposed to LDS fp16, row padded +8 halves to break bank conflicts.
// C/D frag: col = nt*16 + (lane&15), row = quad*4 + r (HW-verified).
// HEADS>0: fused attention coefficients al_s/al_d from fp32 accumulators.
template <int KIN, int KOUT, bool A_FP32, int HEADS>
__launch_bounds__(BDIM) __global__
void gemm_mfma(const void* __restrict__ Ap, const float* __restrict__ W,
               _Float16* __restrict__ C,
               const float* __restrict__ a_src, const float* __restrict__ a_dst,
               float* __restrict__ al_s, float* __restrict__ al_d, int N) {
  constexpr int KP = KIN + 8;
  constexpr int NT = KOUT / 16;
  __shared__ _Float16 Wt[KOUT * KP];
  int tid = threadIdx.x;
  for (int i = tid; i < KIN * KOUT; i += BDIM) {
    int k = i / KOUT, n = i % KOUT;
    Wt[n * KP + k] = (_Float16)W[i];
  }
  __syncthreads();
  int lane = tid & 63;
  int quad = lane >> 4, l16 = lane & 15;
  int m0 = blockIdx.x * 64 + (tid >> 6) * 16;
  if (m0 >= N) return;  // N % 16 == 0: whole wave in or out
  v4f acc[NT];
#pragma unroll
  for (int nt = 0; nt < NT; ++nt) acc[nt] = (v4f){0.0f, 0.0f, 0.0f, 0.0f};
#pragma unroll
  for (int k0 = 0; k0 < KIN; k0 += 32) {
    v8h a;
    if constexpr (A_FP32) {
      const float* ap = (const float*)Ap + (size_t)(m0 + l16) * KIN + k0 + quad * 8;
#pragma unroll
      for (int j = 0; j < 8; ++j) a[j] = (_Float16)ap[j];
    } else {
      a = *(const v8h*)((const _Float16*)Ap + (size_t)(m0 + l16) * KIN + k0 + quad * 8);
    }
#pragma unroll
    for (int nt = 0; nt < NT; ++nt) {
      v8h b = *(const v8h*)&Wt[(nt * 16 + l16) * KP + k0 + quad * 8];
      acc[nt] = __builtin_amdgcn_mfma_f32_16x16x32_f16(a, b, acc[nt], 0, 0, 0);
    }
  }
#pragma unroll
  for (int nt = 0; nt < NT; ++nt)
#pragma unroll
    for (int r = 0; r < 4; ++r)
      C[(size_t)(m0 + quad * 4 + r) * KOUT + nt * 16 + l16] = (_Float16)acc[nt][r];

  if constexpr (HEADS > 0) {
    constexpr int TPH = NT / HEADS;     // MFMA tiles per head
    constexpr int FPH = KOUT / HEADS;   // features per head
    float av_s[NT], av_d[NT];
#pragma unroll
    for (int nt = 0; nt < NT; ++nt) {
      int head = nt / TPH, c = (nt % TPH) * 16 + l16;
      av_s[nt] = a_src[head * FPH + c];
      av_d[nt] = a_dst[head * FPH + c];
    }
#pragma unroll
    for (int r = 0; r < 4; ++r) {
#pragma unroll
      for (int head = 0; head < HEADS; ++head) {
        float ps = 0.0f, pd = 0.0f;
#pragma unroll
        for (int t = 0; t < TPH; ++t) {
          int nt = head * TPH + t;
          ps += acc[nt][r] * av_s[nt];
          pd += acc[nt][r] * av_d[nt];
        }
#pragma unroll
        for (int o = 1; o < 16; o <<= 1) {
          ps += __shfl_xor(ps, o, 64);
          pd += __shfl_xor(pd, o, 64);
        }
        if (l16 == 0) {
          int row = m0 + quad * 4 + r;
          al_s[(size_t)head * N + row] = ps;
          al_d[(size_t)head * N + row] = pd;
        }
      }
    }
  }
}

// ---------------------------------------------------------------- CSR build
// Atomic-free (LDS atomics only): hist -> factored parallel scan -> bucket
// scatter -> per-bucket CSR.

// Pass A: per-chunk LDS histogram over NB dst-range buckets; coalesced count dump.
__launch_bounds__(BDIM) __global__
void hist_a(const int* __restrict__ ei, int E, int TOT, int bw,
            int* __restrict__ counts, int nWG) {
  __shared__ int hist[NB];
  int tid = threadIdx.x, wg = blockIdx.x;
  for (int i = tid; i < NB; i += BDIM) hist[i] = 0;
  __syncthreads();
  int base = wg * CH, lim = min(CH, TOT - base);
  for (int i = tid; i < lim; i += BDIM) {
    int e = base + i;
    int dst = (e < E) ? ei[E + e] : (e - E);
    atomicAdd(&hist[dst / bw], 1);
  }
  __syncthreads();
  for (int b = tid; b < NB; b += BDIM) counts[(size_t)b * nWG + wg] = hist[b];
}

// one wave per bucket: exclusive scan of its nWG chunk-counts (within-bucket)
// off[b*nWG+wg] = prefix within bucket; btot[b] = bucket total. Fully parallel.
__launch_bounds__(BDIM) __global__
void scan_bucket(const int* __restrict__ counts, int nWG,
                 int* __restrict__ off, int* __restrict__ btot) {
  int b = blockIdx.x * (BDIM / 64) + (threadIdx.x >> 6);
  int lane = threadIdx.x & 63;
  if (b >= NB) return;
  const int* c = counts + (size_t)b * nWG;
  int* o = off + (size_t)b * nWG;
  int carry = 0;
  for (int base = 0; base < nWG; base += 64) {
    int i = base + lane;
    int v = (i < nWG) ? c[i] : 0;
    int incl = v;
#pragma unroll
    for (int s = 1; s < 64; s <<= 1) {
      int t = __shfl_up(incl, s, 64);
      if (lane >= s) incl += t;
    }
    if (i < nWG) o[i] = carry + incl - v;
    carry += __shfl(incl, 63, 64);
  }
  if (lane == 0) btot[b] = carry;
}

// single 512-thread WG: exclusive scan of the NB bucket totals -> bbase[NB+1]
__launch_bounds__(512) __global__
void scan_tot(const int* __restrict__ btot, int* __restrict__ bbase,
              int* __restrict__ row_ptr, int N, int TOT) {
  __shared__ int wsum[8], wpre[8];
  int tid = threadIdx.x, lane = tid & 63, w = tid >> 6;
  int v = btot[tid];  // NB == 512 == blockDim
  int incl = v;
#pragma unroll
  for (int o = 1; o < 64; o <<= 1) {
    int t = __shfl_up(incl, o, 64);
    if (lane >= o) incl += t;
  }
  if (lane == 63) wsum[w] = incl;
  __syncthreads();
  if (w == 0 && lane < 8) {
    int s = wsum[lane];
#pragma unroll
    for (int o = 1; o < 8; o <<= 1) {
      int t = __shfl_up(s, o, 64);
      if (lane >= o) s += t;
    }
    wpre[lane] = s - wsum[lane];
  }
  __syncthreads();
  bbase[tid] = wpre[w] + incl - v;
  if (tid == 0) { bbase[NB] = TOT; row_ptr[N] = TOT; }
}

// Pass B: scatter edges into bucket-major ebuf, packed (dst_local<<17 | src).
__launch_bounds__(BDIM) __global__
void bucket_b(const int* __restrict__ ei, int E, int TOT, int bw,
              const int* __restrict__ off, const int* __restrict__ bbase,
              int nWG, unsigned int* __restrict__ ebuf) {
  __shared__ int cur[NB];
  int tid = threadIdx.x, wg = blockIdx.x;
  for (int b = tid; b < NB; b += BDIM)
    cur[b] = bbase[b] + off[(size_t)b * nWG + wg];
  __syncthreads();
  int base = wg * CH, lim = min(CH, TOT - base);
  for (int i = tid; i < lim; i += BDIM) {
    int e = base + i;
    int src, dst;
    if (e < E) { src = ei[e]; dst = ei[E + e]; }
    else       { src = dst = e - E; }
    int b = dst / bw;
    int pos = atomicAdd(&cur[b], 1);
    ebuf[pos] = ((unsigned int)(dst - b * bw) << 17) | (unsigned int)src;
  }
}

// Pass C: one WG per bucket. Build CSR segment fully in LDS; all global IO coalesced.
__launch_bounds__(BDIM) __global__
void csr_c(const unsigned int* __restrict__ ebuf, const int* __restrict__ bbase,
           int N, int bw,
           int* __restrict__ row_ptr, float* __restrict__ dis,
           int* __restrict__ csr_src) {
  __shared__ unsigned int eb[CAP];
  __shared__ unsigned int ob[CAP];
  __shared__ int cnt[128], loff[128], cur[128];
  int tid = threadIdx.x, b = blockIdx.x;
  int d0 = b * bw;
  if (d0 >= N) return;
  int width = min(bw, N - d0);
  int sbase = bbase[b];
  int send = bbase[b + 1];
  int nb = send - sbase;
  if (tid < 128) cnt[tid] = 0;
  __syncthreads();
  for (int i = tid; i < nb; i += BDIM) {
    unsigned int v = ebuf[sbase + i];
    eb[i] = v;
    atomicAdd(&cnt[v >> 17], 1);
  }
  __syncthreads();
  if (tid < 64) {  // wave 0: exclusive scan of 128 counters (2 per lane)
    int c0 = cnt[tid * 2], c1 = cnt[tid * 2 + 1];
    int s = c0 + c1;
    int incl = s;
#pragma unroll
    for (int o = 1; o < 64; o <<= 1) {
      int t = __shfl_up(incl, o, 64);
      if (tid >= o) incl += t;
    }
    int excl = incl - s;
    loff[tid * 2] = excl;
    loff[tid * 2 + 1] = excl + c0;
  }
  __syncthreads();
  if (tid < width) {
    row_ptr[d0 + tid] = sbase + loff[tid];
    dis[d0 + tid] = rsqrtf((float)cnt[tid]);  // deg >= 1 (self-loops)
    cur[tid] = loff[tid];
  }
  __syncthreads();
  for (int i = tid; i < nb; i += BDIM) {
    unsigned int v = eb[i];
    int p = atomicAdd(&cur[v >> 17], 1);
    ob[p] = v & 0x1FFFFu;
  }
  __syncthreads();
  for (int i = tid; i < nb; i += BDIM) csr_src[sbase + i] = (int)ob[i];
}

// ---------------------------------------------------------------- GCN gather
// wave per dst node, lane = feature; 8-deep batched gather loads; fp16 output.
// norm factorized: out = relu(dis[dst] * sum(dis[src]*h[src]) + b)
__launch_bounds__(BDIM) __global__
void gcn_gather(const __half* __restrict__ h, const int* __restrict__ row_ptr,
                const int* __restrict__ csr_src, const float* __restrict__ dis,
                const float* __restrict__ b, __half* __restrict__ out, int N) {
  constexpr int U = 8;
  int wid = blockIdx.x * (BDIM / 64) + (threadIdx.x >> 6);
  int lane = threadIdx.x & 63;
  if (wid >= N) return;
  int beg = row_ptr[wid], end = row_ptr[wid + 1];
  float acc = 0.0f;
  for (int base = beg; base < end; base += 64) {
    int nch = min(64, end - base);
    int   s_l = (lane < nch) ? csr_src[base + lane] : 0;
    float d_l = (lane < nch) ? dis[s_l] : 0.0f;  // pad lanes contribute 0
    int jmax = (nch + U - 1) & ~(U - 1);
    for (int j = 0; j < jmax; j += U) {
      int ss[U]; float ww[U]; __half vv[U];
#pragma unroll
      for (int u = 0; u < U; ++u) {
        ss[u] = __shfl(s_l, j + u, 64);
        ww[u] = __shfl(d_l, j + u, 64);
      }
#pragma unroll
      for (int u = 0; u < U; ++u) vv[u] = h[(size_t)ss[u] * 64 + lane];
#pragma unroll
      for (int u = 0; u < U; ++u) acc += ww[u] * __half2float(vv[u]);
    }
  }
  out[(size_t)wid * 64 + lane] = __float2half(fmaxf(acc * dis[wid] + b[lane], 0.0f));
}

// ---------------------------------------------------------------- GAT
// wave per (dst, head): segment softmax -> unnormalized alpha per edge + den per dst
// alpha written interleaved: alpha[e*HEADS + hd]
template <int HEADS>
__launch_bounds__(BDIM) __global__
void gat_alpha(const int* __restrict__ row_ptr, const int* __restrict__ csr_src,
               const float* __restrict__ al_s, const float* __restrict__ al_d,
               float* __restrict__ alpha, float* __restrict__ den, int N) {
  int wid = blockIdx.x * (BDIM / 64) + (threadIdx.x >> 6);
  int lane = threadIdx.x & 63;
  if (wid >= N * HEADS) return;
  int dn = wid % N, hd = wid / N;
  const float* als_p = al_s + (size_t)hd * N;
  float ad = al_d[(size_t)hd * N + dn];
  int beg = row_ptr[dn], end = row_ptr[dn + 1];
  int deg = end - beg;
  if (deg <= 64) {  // common case: whole segment in one wave pass
    int   s = (lane < deg) ? csr_src[beg + lane] : 0;
    float e = (lane < deg) ? leaky02(als_p[s] + ad) : -3.4e38f;
    float m = wave_max64(e);
    float ex = (lane < deg) ? expf(e - m) : 0.0f;
    float l = wave_sum64(ex);
    if (lane < deg) alpha[(size_t)(beg + lane) * HEADS + hd] = ex;
    if (lane == 0) den[(size_t)hd * N + dn] = l;
  } else {
    float m = -3.4e38f;
    for (int base = beg; base < end; base += 64) {
      int nch = min(64, end - base);
      int   s = (lane < nch) ? csr_src[base + lane] : 0;
      float e = (lane < nch) ? leaky02(als_p[s] + ad) : -3.4e38f;
      m = fmaxf(m, wave_max64(e));
    }
    float l = 0.0f;
    for (int base = beg; base < end; base += 64) {
      int nch = min(64, end - base);
      int   s = (lane < nch) ? csr_src[base + lane] : 0;
      float e = (lane < nch) ? leaky02(als_p[s] + ad) : -3.4e38f;
      float ex = (lane < nch) ? expf(e - m) : 0.0f;
      if (lane < nch) alpha[(size_t)(base + lane) * HEADS + hd] = ex;
      l += wave_sum64(ex);
    }
    if (lane == 0) den[(size_t)hd * N + dn] = l;
  }
}

// GAT layer-1 accumulate, BOTH heads per wave. Row = 256B (__half2 per lane).
__launch_bounds__(BDIM) __global__
void gat_acc2(const __half* __restrict__ h, const int* __restrict__ row_ptr,
              const int* __restrict__ csr_src, const float2* __restrict__ alpha2,
              const float* __restrict__ den, const float* __restrict__ b,
              __half* __restrict__ out, int N) {
  constexpr int U = 8;
  int wid = blockIdx.x * (BDIM / 64) + (threadIdx.x >> 6);
  int lane = threadIdx.x & 63;
  if (wid >= N) return;
  int head = lane >> 5;
  const __half2* hrow = (const __half2*)h;  // 64 half2 per node row
  int beg = row_ptr[wid], end = row_ptr[wid + 1];
  float accx = 0.0f, accy = 0.0f;
  for (int base = beg; base < end; base += 64) {
    int nch = min(64, end - base);
    int    s_l = (lane < nch) ? csr_src[base + lane] : 0;
    float2 a_l = (lane < nch) ? alpha2[base + lane] : make_float2(0.0f, 0.0f);
    int jmax = (nch + U - 1) & ~(U - 1);
    for (int j = 0; j < jmax; j += U) {
      int ss[U]; float aa[U]; __half2 vv[U];
#pragma unroll
      for (int u = 0; u < U; ++u) {
        ss[u] = __shfl(s_l, j + u, 64);
        float a0 = __shfl(a_l.x, j + u, 64);
        float a1 = __shfl(a_l.y, j + u, 64);
        aa[u] = head ? a1 : a0;
      }
#pragma unroll
      for (int u = 0; u < U; ++u) vv[u] = hrow[(size_t)ss[u] * 64 + lane];
#pragma unroll
      for (int u = 0; u < U; ++u) {
        float2 v = __half22float2(vv[u]);
        accx += aa[u] * v.x;
        accy += aa[u] * v.y;
      }
    }
  }
  float dn = den[(size_t)head * N + wid];
  const float2* b2v = (const float2*)b;
  float2 bb = b2v[lane];
  float ox = fmaxf(accx / dn + bb.x, 0.0f);  // relu fused
  float oy = fmaxf(accy / dn + bb.y, 0.0f);
  ((__half2*)out)[(size_t)wid * 64 + lane] = __floats2half2_rn(ox, oy);
}

// GAT layer-2 accumulate (1 head, 64 feats), 8-deep batched loads; fp32 out.
__launch_bounds__(BDIM) __global__
void gat_acc1(const __half* __restrict__ h, const int* __restrict__ row_ptr,
              const int* __restrict__ csr_src, const float* __restrict__ alpha,
              const float* __restrict__ den, const float* __restrict__ b,
              float* __restrict__ out, int N) {
  constexpr int U = 8;
  int wid = blockIdx.x * (BDIM / 64) + (threadIdx.x >> 6);
  int lane = threadIdx.x & 63;
  if (wid >= N) return;
  int beg = row_ptr[wid], end = row_ptr[wid + 1];
  float acc = 0.0f;
  for (int base = beg; base < end; base += 64) {
    int nch = min(64, end - base);
    int   s_l = (lane < nch) ? csr_src[base + lane] : 0;
    float a_l = (lane < nch) ? alpha[base + lane] : 0.0f;
    int jmax = (nch + U - 1) & ~(U - 1);
    for (int j = 0; j < jmax; j += U) {
      int ss[U]; float aa[U]; __half vv[U];
#pragma unroll
      for (int u = 0; u < U; ++u) {
        ss[u] = __shfl(s_l, j + u, 64);
        aa[u] = __shfl(a_l, j + u, 64);
      }
#pragma unroll
      for (int u = 0; u < U; ++u) vv[u] = h[(size_t)ss[u] * 64 + lane];
#pragma unroll
      for (int u = 0; u < U; ++u) acc += aa[u] * __half2float(vv[u]);
    }
  }
  out[(size_t)wid * 64 + lane] = acc / den[wid] + b[lane];  // no relu on layer 2
}

// ---------------------------------------------------------------- pool + head
__device__ __forceinline__ int lower_bound(const int* __restrict__ a, int n, int v) {
  int lo = 0, hi = n;
  while (lo < hi) {
    int mid = (lo + hi) >> 1;
    if (a[mid] < v) lo = mid + 1; else hi = mid;
  }
  return lo;
}

// wave per graph: batch is sorted -> contiguous node range; no atomics
__launch_bounds__(BDIM) __global__
void pool_final(const float* __restrict__ x3, const int* __restrict__ batch,
                const float* __restrict__ Wfc, const float* __restrict__ bfc,
                float* __restrict__ out, int N, int G) {
  int wid = blockIdx.x * (BDIM / 64) + (threadIdx.x >> 6);
  int lane = threadIdx.x & 63;
  if (wid >= G) return;
  int beg = lower_bound(batch, N, wid);
  int end = lower_bound(batch, N, wid + 1);
  float acc = 0.0f;
  for (int n = beg; n < end; ++n) acc += x3[(size_t)n * 64 + lane];
  float p = (end > beg) ? acc / (float)(end - beg) : 0.0f;
  float l0 = wave_sum64(p * Wfc[lane * 2 + 0]);
  float l1 = wave_sum64(p * Wfc[lane * 2 + 1]);
  if (lane == 0) {
    l0 += bfc[0];
    l1 += bfc[1];
    float m = fmaxf(l0, l1);
    float ls = m + logf(expf(l0 - m) + expf(l1 - m));
    out[wid * 2 + 0] = l0 - ls;
    out[wid * 2 + 1] = l1 - ls;
  }
}

// ---------------------------------------------------------------- launch

static inline int cdiv(int a, int b) { return (a + b - 1) / b; }

extern "C" void kernel_launch(void* const* d_in, const int* in_sizes, int n_in,
                              void* d_out, int out_size, void* d_ws, size_t ws_size,
                              hipStream_t stream) {
  const float* x      = (const float*)d_in[0];
  const int*   ei     = (const int*)d_in[1];
  const int*   batch  = (const int*)d_in[2];
  const float* W1     = (const float*)d_in[3];
  const float* b1     = (const float*)d_in[4];
  const float* W2     = (const float*)d_in[5];
  const float* a_src2 = (const float*)d_in[6];
  const float* a_dst2 = (const float*)d_in[7];
  const float* b2     = (const float*)d_in[8];
  const float* W3     = (const float*)d_in[9];
  const float* a_src3 = (const float*)d_in[10];
  const float* a_dst3 = (const float*)d_in[11];
  const float* b3     = (const float*)d_in[12];
  const float* Wfc    = (const float*)d_in[13];
  const float* bfc    = (const float*)d_in[14];
  float* out = (float*)d_out;

  const int N = in_sizes[2];       // 50000
  const int E = in_sizes[1] / 2;   // 800000
  const int G = out_size / 2;      // 512
  const int TOT = E + N;           // edges incl. self-loops
  const int bw  = cdiv(N, NB);     // dst-range per bucket (98)
  const int nWG = cdiv(TOT, CH);   // chunks (104)
  const int M   = NB * nWG;        // count-matrix size

  // workspace layout (~70 MB), fp16 buffers first (16B-aligned offsets)
  char* wsb = (char*)d_ws;
  __half* h1    = (__half*)wsb;                       // N*64 fp16
  __half* h2    = h1 + (size_t)N * 64;                // N*128 fp16 (reused as h3)
  __half* out1h = h2 + (size_t)N * 128;               // N*64 fp16 (x1)
  __half* out2h = out1h + (size_t)N * 64;             // N*128 fp16 (x2)
  float*  out3  = (float*)(out2h + (size_t)N * 128);  // N*64 f32 (x3)
  float*  alpha = out3 + (size_t)N * 64;              // TOT*2 f32
  float*  dis   = alpha + (size_t)TOT * 2;            // N
  float*  al_s  = dis + N;                            // N*2 planar
  float*  al_d  = al_s + (size_t)N * 2;               // N*2 planar
  float*  den   = al_d + (size_t)N * 2;               // N*2 planar
  int* counts   = (int*)(den + (size_t)N * 2);        // M
  int* off      = counts + M;                         // M
  int* btot     = off + M;                            // NB
  int* bbase    = btot + NB;                          // NB+1
  unsigned int* ebuf = (unsigned int*)(bbase + NB + 1);  // TOT
  int* csr_src  = (int*)(ebuf + TOT);                 // TOT
  int* row_ptr  = csr_src + TOT;                      // N+1

  // ---- CSR build: atomic-free radix bucketing, factored parallel scan
  hist_a<<<nWG, BDIM, 0, stream>>>(ei, E, TOT, bw, counts, nWG);
  scan_bucket<<<cdiv(NB, 4), BDIM, 0, stream>>>(counts, nWG, off, btot);
  scan_tot<<<1, 512, 0, stream>>>(btot, bbase, row_ptr, N, TOT);
  bucket_b<<<nWG, BDIM, 0, stream>>>(ei, E, TOT, bw, off, bbase, nWG, ebuf);
  csr_c<<<NB, BDIM, 0, stream>>>(ebuf, bbase, N, bw, row_ptr, dis, csr_src);

  // ---- GCN layer
  gemm_mfma<128, 64, true, 0><<<cdiv(N, 64), BDIM, 0, stream>>>(
      x, W1, (_Float16*)h1, nullptr, nullptr, nullptr, nullptr, N);
  gcn_gather<<<cdiv(N, 4), BDIM, 0, stream>>>(h1, row_ptr, csr_src, dis, b1, out1h, N);

  // ---- GAT layer 1 (heads=2, concat; att_coef fused into GEMM epilogue)
  gemm_mfma<64, 128, false, 2><<<cdiv(N, 64), BDIM, 0, stream>>>(
      out1h, W2, (_Float16*)h2, a_src2, a_dst2, al_s, al_d, N);
  gat_alpha<2><<<cdiv(N * 2, 4), BDIM, 0, stream>>>(row_ptr, csr_src, al_s, al_d,
                                                    alpha, den, N);
  gat_acc2<<<cdiv(N, 4), BDIM, 0, stream>>>(h2, row_ptr, csr_src, (const float2*)alpha,
                                            den, b2, out2h, N);

  // ---- GAT layer 2 (heads=1, mean == identity)
  __half* h3 = h2;  // h2 dead after gat_acc2
  gemm_mfma<128, 64, false, 1><<<cdiv(N, 64), BDIM, 0, stream>>>(
      out2h, W3, (_Float16*)h3, a_src3, a_dst3, al_s, al_d, N);
  gat_alpha<1><<<cdiv(N, 4), BDIM, 0, stream>>>(row_ptr, csr_src, al_s, al_d,
                                                alpha, den, N);
  gat_acc1<<<cdiv(N, 4), BDIM, 0, stream>>>(h3, row_ptr, csr_src, alpha, den,
                                            b3, out3, N);

  // ---- global mean pool + fc + log_softmax (atomic-free; batch is sorted)
  pool_final<<<cdiv(G, 4), BDIM, 0, stream>>>(out3, batch, Wfc, bfc, out, N, G);
}

// Round 10
// 309.356 us; speedup vs baseline: 4.5222x; 1.0669x over previous
//
#include <hip/hip_runtime.h>
#include <hip/hip_bf16.h>
#include <hip/hip_fp16.h>
#include <math.h>

#define BDIM 256

using v8h = __attribute__((ext_vector_type(8))) _Float16;
using v4f = __attribute__((ext_vector_type(4))) float;

// CSR-build tuning: 512 dst-range buckets, 8192-edge chunks, 4096-edge bucket cap
#define NB  512
#define CH  8192
#define CAP 4096
// pool slices per graph
#define PS  8

// ---------------------------------------------------------------- utilities

__device__ __forceinline__ float wave_max64(float v) {
#pragma unroll
  for (int o = 32; o > 0; o >>= 1) v = fmaxf(v, __shfl_xor(v, o, 64));
  return v;
}
__device__ __forceinline__ float wave_sum64(float v) {
#pragma unroll
  for (int o = 32; o > 0; o >>= 1) v += __shfl_xor(v, o, 64);
  return v;
}

__device__ __forceinline__ float leaky02(float v) {
  return v >= 0.0f ? v : 0.2f * v;
}

// ---------------------------------------------------------------- MFMA GEMM
// C[N,KOUT](fp16) = A[N,KIN] @ W[KIN,KOUT] (fp16 compute, fp32 acc).
// Wave computes 16 rows x KOUT cols. A-frag: A[m=lane&15][k=quad*8+j].
// W transposed to LDS fp16, row padded +8 halves to break bank conflicts.
// C/D frag: col = nt*16 + (lane&15), row = quad*4 + r (HW-verified).
// HEADS>0: fused attention coefficients al_s/al_d from fp32 accumulators.
template <int KIN, int KOUT, bool A_FP32, int HEADS>
__launch_bounds__(BDIM) __global__
void gemm_mfma(const void* __restrict__ Ap, const float* __restrict__ W,
               _Float16* __restrict__ C,
               const float* __restrict__ a_src, const float* __restrict__ a_dst,
               float* __restrict__ al_s, float* __restrict__ al_d, int N) {
  constexpr int KP = KIN + 8;
  constexpr int NT = KOUT / 16;
  __shared__ _Float16 Wt[KOUT * KP];
  int tid = threadIdx.x;
  for (int i = tid; i < KIN * KOUT; i += BDIM) {
    int k = i / KOUT, n = i % KOUT;
    Wt[n * KP + k] = (_Float16)W[i];
  }
  __syncthreads();
  int lane = tid & 63;
  int quad = lane >> 4, l16 = lane & 15;
  int m0 = blockIdx.x * 64 + (tid >> 6) * 16;
  if (m0 >= N) return;  // N % 16 == 0: whole wave in or out
  v4f acc[NT];
#pragma unroll
  for (int nt = 0; nt < NT; ++nt) acc[nt] = (v4f){0.0f, 0.0f, 0.0f, 0.0f};
#pragma unroll
  for (int k0 = 0; k0 < KIN; k0 += 32) {
    v8h a;
    if constexpr (A_FP32) {
      const float* ap = (const float*)Ap + (size_t)(m0 + l16) * KIN + k0 + quad * 8;
#pragma unroll
      for (int j = 0; j < 8; ++j) a[j] = (_Float16)ap[j];
    } else {
      a = *(const v8h*)((const _Float16*)Ap + (size_t)(m0 + l16) * KIN + k0 + quad * 8);
    }
#pragma unroll
    for (int nt = 0; nt < NT; ++nt) {
      v8h b = *(const v8h*)&Wt[(nt * 16 + l16) * KP + k0 + quad * 8];
      acc[nt] = __builtin_amdgcn_mfma_f32_16x16x32_f16(a, b, acc[nt], 0, 0, 0);
    }
  }
#pragma unroll
  for (int nt = 0; nt < NT; ++nt)
#pragma unroll
    for (int r = 0; r < 4; ++r)
      C[(size_t)(m0 + quad * 4 + r) * KOUT + nt * 16 + l16] = (_Float16)acc[nt][r];

  if constexpr (HEADS > 0) {
    constexpr int TPH = NT / HEADS;     // MFMA tiles per head
    constexpr int FPH = KOUT / HEADS;   // features per head
    float av_s[NT], av_d[NT];
#pragma unroll
    for (int nt = 0; nt < NT; ++nt) {
      int head = nt / TPH, c = (nt % TPH) * 16 + l16;
      av_s[nt] = a_src[head * FPH + c];
      av_d[nt] = a_dst[head * FPH + c];
    }
#pragma unroll
    for (int r = 0; r < 4; ++r) {
#pragma unroll
      for (int head = 0; head < HEADS; ++head) {
        float ps = 0.0f, pd = 0.0f;
#pragma unroll
        for (int t = 0; t < TPH; ++t) {
          int nt = head * TPH + t;
          ps += acc[nt][r] * av_s[nt];
          pd += acc[nt][r] * av_d[nt];
        }
#pragma unroll
        for (int o = 1; o < 16; o <<= 1) {
          ps += __shfl_xor(ps, o, 64);
          pd += __shfl_xor(pd, o, 64);
        }
        if (l16 == 0) {
          int row = m0 + quad * 4 + r;
          al_s[(size_t)head * N + row] = ps;
          al_d[(size_t)head * N + row] = pd;
        }
      }
    }
  }
}

// ---------------------------------------------------------------- CSR build
// Atomic-free (LDS atomics only): hist -> factored parallel scan -> bucket
// scatter -> per-bucket CSR.

// Pass A: per-chunk LDS histogram over NB dst-range buckets; coalesced count dump.
__launch_bounds__(BDIM) __global__
void hist_a(const int* __restrict__ ei, int E, int TOT, int bw,
            int* __restrict__ counts, int nWG) {
  __shared__ int hist[NB];
  int tid = threadIdx.x, wg = blockIdx.x;
  for (int i = tid; i < NB; i += BDIM) hist[i] = 0;
  __syncthreads();
  int base = wg * CH, lim = min(CH, TOT - base);
  for (int i = tid; i < lim; i += BDIM) {
    int e = base + i;
    int dst = (e < E) ? ei[E + e] : (e - E);
    atomicAdd(&hist[dst / bw], 1);
  }
  __syncthreads();
  for (int b = tid; b < NB; b += BDIM) counts[(size_t)b * nWG + wg] = hist[b];
}

// one wave per bucket: exclusive scan of its nWG chunk-counts (within-bucket)
__launch_bounds__(BDIM) __global__
void scan_bucket(const int* __restrict__ counts, int nWG,
                 int* __restrict__ off, int* __restrict__ btot) {
  int b = blockIdx.x * (BDIM / 64) + (threadIdx.x >> 6);
  int lane = threadIdx.x & 63;
  if (b >= NB) return;
  const int* c = counts + (size_t)b * nWG;
  int* o = off + (size_t)b * nWG;
  int carry = 0;
  for (int base = 0; base < nWG; base += 64) {
    int i = base + lane;
    int v = (i < nWG) ? c[i] : 0;
    int incl = v;
#pragma unroll
    for (int s = 1; s < 64; s <<= 1) {
      int t = __shfl_up(incl, s, 64);
      if (lane >= s) incl += t;
    }
    if (i < nWG) o[i] = carry + incl - v;
    carry += __shfl(incl, 63, 64);
  }
  if (lane == 0) btot[b] = carry;
}

// single 512-thread WG: exclusive scan of the NB bucket totals -> bbase[NB+1]
__launch_bounds__(512) __global__
void scan_tot(const int* __restrict__ btot, int* __restrict__ bbase,
              int* __restrict__ row_ptr, int N, int TOT) {
  __shared__ int wsum[8], wpre[8];
  int tid = threadIdx.x, lane = tid & 63, w = tid >> 6;
  int v = btot[tid];  // NB == 512 == blockDim
  int incl = v;
#pragma unroll
  for (int o = 1; o < 64; o <<= 1) {
    int t = __shfl_up(incl, o, 64);
    if (lane >= o) incl += t;
  }
  if (lane == 63) wsum[w] = incl;
  __syncthreads();
  if (w == 0 && lane < 8) {
    int s = wsum[lane];
#pragma unroll
    for (int o = 1; o < 8; o <<= 1) {
      int t = __shfl_up(s, o, 64);
      if (lane >= o) s += t;
    }
    wpre[lane] = s - wsum[lane];
  }
  __syncthreads();
  bbase[tid] = wpre[w] + incl - v;
  if (tid == 0) { bbase[NB] = TOT; row_ptr[N] = TOT; }
}

// Pass B: scatter edges into bucket-major ebuf, packed (dst_local<<17 | src).
__launch_bounds__(BDIM) __global__
void bucket_b(const int* __restrict__ ei, int E, int TOT, int bw,
              const int* __restrict__ off, const int* __restrict__ bbase,
              int nWG, unsigned int* __restrict__ ebuf) {
  __shared__ int cur[NB];
  int tid = threadIdx.x, wg = blockIdx.x;
  for (int b = tid; b < NB; b += BDIM)
    cur[b] = bbase[b] + off[(size_t)b * nWG + wg];
  __syncthreads();
  int base = wg * CH, lim = min(CH, TOT - base);
  for (int i = tid; i < lim; i += BDIM) {
    int e = base + i;
    int src, dst;
    if (e < E) { src = ei[e]; dst = ei[E + e]; }
    else       { src = dst = e - E; }
    int b = dst / bw;
    int pos = atomicAdd(&cur[b], 1);
    ebuf[pos] = ((unsigned int)(dst - b * bw) << 17) | (unsigned int)src;
  }
}

// Pass C: one WG per bucket. Build CSR segment fully in LDS; all global IO coalesced.
__launch_bounds__(BDIM) __global__
void csr_c(const unsigned int* __restrict__ ebuf, const int* __restrict__ bbase,
           int N, int bw,
           int* __restrict__ row_ptr, float* __restrict__ dis,
           int* __restrict__ csr_src) {
  __shared__ unsigned int eb[CAP];
  __shared__ unsigned int ob[CAP];
  __shared__ int cnt[128], loff[128], cur[128];
  int tid = threadIdx.x, b = blockIdx.x;
  int d0 = b * bw;
  if (d0 >= N) return;
  int width = min(bw, N - d0);
  int sbase = bbase[b];
  int send = bbase[b + 1];
  int nb = send - sbase;
  if (tid < 128) cnt[tid] = 0;
  __syncthreads();
  for (int i = tid; i < nb; i += BDIM) {
    unsigned int v = ebuf[sbase + i];
    eb[i] = v;
    atomicAdd(&cnt[v >> 17], 1);
  }
  __syncthreads();
  if (tid < 64) {  // wave 0: exclusive scan of 128 counters (2 per lane)
    int c0 = cnt[tid * 2], c1 = cnt[tid * 2 + 1];
    int s = c0 + c1;
    int incl = s;
#pragma unroll
    for (int o = 1; o < 64; o <<= 1) {
      int t = __shfl_up(incl, o, 64);
      if (tid >= o) incl += t;
    }
    int excl = incl - s;
    loff[tid * 2] = excl;
    loff[tid * 2 + 1] = excl + c0;
  }
  __syncthreads();
  if (tid < width) {
    row_ptr[d0 + tid] = sbase + loff[tid];
    dis[d0 + tid] = rsqrtf((float)cnt[tid]);  // deg >= 1 (self-loops)
    cur[tid] = loff[tid];
  }
  __syncthreads();
  for (int i = tid; i < nb; i += BDIM) {
    unsigned int v = eb[i];
    int p = atomicAdd(&cur[v >> 17], 1);
    ob[p] = v & 0x1FFFFu;
  }
  __syncthreads();
  for (int i = tid; i < nb; i += BDIM) csr_src[sbase + i] = (int)ob[i];
}

// ---------------------------------------------------------------- GCN gather
// wave per dst node, lane = feature; 8-deep batched gather loads; fp16 output.
// norm factorized: out = relu(dis[dst] * sum(dis[src]*h[src]) + b)
__launch_bounds__(BDIM) __global__
void gcn_gather(const __half* __restrict__ h, const int* __restrict__ row_ptr,
                const int* __restrict__ csr_src, const float* __restrict__ dis,
                const float* __restrict__ b, __half* __restrict__ out, int N) {
  constexpr int U = 8;
  int wid = blockIdx.x * (BDIM / 64) + (threadIdx.x >> 6);
  int lane = threadIdx.x & 63;
  if (wid >= N) return;
  int beg = row_ptr[wid], end = row_ptr[wid + 1];
  float acc = 0.0f;
  for (int base = beg; base < end; base += 64) {
    int nch = min(64, end - base);
    int   s_l = (lane < nch) ? csr_src[base + lane] : 0;
    float d_l = (lane < nch) ? dis[s_l] : 0.0f;  // pad lanes contribute 0
    int jmax = (nch + U - 1) & ~(U - 1);
    for (int j = 0; j < jmax; j += U) {
      int ss[U]; float ww[U]; __half vv[U];
#pragma unroll
      for (int u = 0; u < U; ++u) {
        ss[u] = __shfl(s_l, j + u, 64);
        ww[u] = __shfl(d_l, j + u, 64);
      }
#pragma unroll
      for (int u = 0; u < U; ++u) vv[u] = h[(size_t)ss[u] * 64 + lane];
#pragma unroll
      for (int u = 0; u < U; ++u) acc += ww[u] * __half2float(vv[u]);
    }
  }
  out[(size_t)wid * 64 + lane] = __float2half(fmaxf(acc * dis[wid] + b[lane], 0.0f));
}

// ---------------------------------------------------------------- GAT
// wave per (dst, head): segment softmax -> unnormalized alpha per edge + den per dst
// alpha written interleaved: alpha[e*HEADS + hd]
template <int HEADS>
__launch_bounds__(BDIM) __global__
void gat_alpha(const int* __restrict__ row_ptr, const int* __restrict__ csr_src,
               const float* __restrict__ al_s, const float* __restrict__ al_d,
               float* __restrict__ alpha, float* __restrict__ den, int N) {
  int wid = blockIdx.x * (BDIM / 64) + (threadIdx.x >> 6);
  int lane = threadIdx.x & 63;
  if (wid >= N * HEADS) return;
  int dn = wid % N, hd = wid / N;
  const float* als_p = al_s + (size_t)hd * N;
  float ad = al_d[(size_t)hd * N + dn];
  int beg = row_ptr[dn], end = row_ptr[dn + 1];
  int deg = end - beg;
  if (deg <= 64) {  // common case: whole segment in one wave pass
    int   s = (lane < deg) ? csr_src[beg + lane] : 0;
    float e = (lane < deg) ? leaky02(als_p[s] + ad) : -3.4e38f;
    float m = wave_max64(e);
    float ex = (lane < deg) ? expf(e - m) : 0.0f;
    float l = wave_sum64(ex);
    if (lane < deg) alpha[(size_t)(beg + lane) * HEADS + hd] = ex;
    if (lane == 0) den[(size_t)hd * N + dn] = l;
  } else {
    float m = -3.4e38f;
    for (int base = beg; base < end; base += 64) {
      int nch = min(64, end - base);
      int   s = (lane < nch) ? csr_src[base + lane] : 0;
      float e = (lane < nch) ? leaky02(als_p[s] + ad) : -3.4e38f;
      m = fmaxf(m, wave_max64(e));
    }
    float l = 0.0f;
    for (int base = beg; base < end; base += 64) {
      int nch = min(64, end - base);
      int   s = (lane < nch) ? csr_src[base + lane] : 0;
      float e = (lane < nch) ? leaky02(als_p[s] + ad) : -3.4e38f;
      float ex = (lane < nch) ? expf(e - m) : 0.0f;
      if (lane < nch) alpha[(size_t)(base + lane) * HEADS + hd] = ex;
      l += wave_sum64(ex);
    }
    if (lane == 0) den[(size_t)hd * N + dn] = l;
  }
}

// GAT layer-1 accumulate, BOTH heads per wave. Row = 256B (__half2 per lane).
__launch_bounds__(BDIM) __global__
void gat_acc2(const __half* __restrict__ h, const int* __restrict__ row_ptr,
              const int* __restrict__ csr_src, const float2* __restrict__ alpha2,
              const float* __restrict__ den, const float* __restrict__ b,
              __half* __restrict__ out, int N) {
  constexpr int U = 8;
  int wid = blockIdx.x * (BDIM / 64) + (threadIdx.x >> 6);
  int lane = threadIdx.x & 63;
  if (wid >= N) return;
  int head = lane >> 5;
  const __half2* hrow = (const __half2*)h;  // 64 half2 per node row
  int beg = row_ptr[wid], end = row_ptr[wid + 1];
  float accx = 0.0f, accy = 0.0f;
  for (int base = beg; base < end; base += 64) {
    int nch = min(64, end - base);
    int    s_l = (lane < nch) ? csr_src[base + lane] : 0;
    float2 a_l = (lane < nch) ? alpha2[base + lane] : make_float2(0.0f, 0.0f);
    int jmax = (nch + U - 1) & ~(U - 1);
    for (int j = 0; j < jmax; j += U) {
      int ss[U]; float aa[U]; __half2 vv[U];
#pragma unroll
      for (int u = 0; u < U; ++u) {
        ss[u] = __shfl(s_l, j + u, 64);
        float a0 = __shfl(a_l.x, j + u, 64);
        float a1 = __shfl(a_l.y, j + u, 64);
        aa[u] = head ? a1 : a0;
      }
#pragma unroll
      for (int u = 0; u < U; ++u) vv[u] = hrow[(size_t)ss[u] * 64 + lane];
#pragma unroll
      for (int u = 0; u < U; ++u) {
        float2 v = __half22float2(vv[u]);
        accx += aa[u] * v.x;
        accy += aa[u] * v.y;
      }
    }
  }
  float dn = den[(size_t)head * N + wid];
  const float2* b2v = (const float2*)b;
  float2 bb = b2v[lane];
  float ox = fmaxf(accx / dn + bb.x, 0.0f);  // relu fused
  float oy = fmaxf(accy / dn + bb.y, 0.0f);
  ((__half2*)out)[(size_t)wid * 64 + lane] = __floats2half2_rn(ox, oy);
}

// GAT layer-2 accumulate (1 head, 64 feats), 8-deep batched loads; fp32 out.
__launch_bounds__(BDIM) __global__
void gat_acc1(const __half* __restrict__ h, const int* __restrict__ row_ptr,
              const int* __restrict__ csr_src, const float* __restrict__ alpha,
              const float* __restrict__ den, const float* __restrict__ b,
              float* __restrict__ out, int N) {
  constexpr int U = 8;
  int wid = blockIdx.x * (BDIM / 64) + (threadIdx.x >> 6);
  int lane = threadIdx.x & 63;
  if (wid >= N) return;
  int beg = row_ptr[wid], end = row_ptr[wid + 1];
  float acc = 0.0f;
  for (int base = beg; base < end; base += 64) {
    int nch = min(64, end - base);
    int   s_l = (lane < nch) ? csr_src[base + lane] : 0;
    float a_l = (lane < nch) ? alpha[base + lane] : 0.0f;
    int jmax = (nch + U - 1) & ~(U - 1);
    for (int j = 0; j < jmax; j += U) {
      int ss[U]; float aa[U]; __half vv[U];
#pragma unroll
      for (int u = 0; u < U; ++u) {
        ss[u] = __shfl(s_l, j + u, 64);
        aa[u] = __shfl(a_l, j + u, 64);
      }
#pragma unroll
      for (int u = 0; u < U; ++u) vv[u] = h[(size_t)ss[u] * 64 + lane];
#pragma unroll
      for (int u = 0; u < U; ++u) acc += aa[u] * __half2float(vv[u]);
    }
  }
  out[(size_t)wid * 64 + lane] = acc / den[wid] + b[lane];  // no relu on layer 2
}

// ---------------------------------------------------------------- pool + head
__device__ __forceinline__ int lower_bound(const int* __restrict__ a, int n, int v) {
  int lo = 0, hi = n;
  while (lo < hi) {
    int mid = (lo + hi) >> 1;
    if (a[mid] < v) lo = mid + 1; else hi = mid;
  }
  return lo;
}

// stage A: wave per (graph, slice): sum a contiguous slice of the graph's rows.
__launch_bounds__(BDIM) __global__
void pool_partial(const float* __restrict__ x3, const int* __restrict__ batch,
                  float* __restrict__ part, int N, int G) {
  int wid = blockIdx.x * (BDIM / 64) + (threadIdx.x >> 6);
  int lane = threadIdx.x & 63;
  if (wid >= G * PS) return;
  int g = wid / PS, s = wid % PS;
  int beg = lower_bound(batch, N, g);
  int end = lower_bound(batch, N, g + 1);
  int len = end - beg;
  int lo = beg + (int)((long long)len * s / PS);
  int hi = beg + (int)((long long)len * (s + 1) / PS);
  float acc = 0.0f;
  int n = lo;
  for (; n + 4 <= hi; n += 4) {  // 4 independent line-loads in flight
    float a0 = x3[(size_t)(n + 0) * 64 + lane];
    float a1 = x3[(size_t)(n + 1) * 64 + lane];
    float a2 = x3[(size_t)(n + 2) * 64 + lane];
    float a3 = x3[(size_t)(n + 3) * 64 + lane];
    acc += (a0 + a1) + (a2 + a3);
  }
  for (; n < hi; ++n) acc += x3[(size_t)n * 64 + lane];
  part[(size_t)wid * 64 + lane] = acc;
}

// stage B: wave per graph: reduce PS partials, mean, FC, log_softmax.
__launch_bounds__(BDIM) __global__
void pool_head(const float* __restrict__ part, const int* __restrict__ batch,
               const float* __restrict__ Wfc, const float* __restrict__ bfc,
               float* __restrict__ out, int N, int G) {
  int wid = blockIdx.x * (BDIM / 64) + (threadIdx.x >> 6);
  int lane = threadIdx.x & 63;
  if (wid >= G) return;
  float acc = 0.0f;
#pragma unroll
  for (int s = 0; s < PS; ++s) acc += part[((size_t)wid * PS + s) * 64 + lane];
  int beg = lower_bound(batch, N, wid);
  int end = lower_bound(batch, N, wid + 1);
  float p = (end > beg) ? acc / (float)(end - beg) : 0.0f;
  float l0 = wave_sum64(p * Wfc[lane * 2 + 0]);
  float l1 = wave_sum64(p * Wfc[lane * 2 + 1]);
  if (lane == 0) {
    l0 += bfc[0];
    l1 += bfc[1];
    float m = fmaxf(l0, l1);
    float ls = m + logf(expf(l0 - m) + expf(l1 - m));
    out[wid * 2 + 0] = l0 - ls;
    out[wid * 2 + 1] = l1 - ls;
  }
}

// ---------------------------------------------------------------- launch

static inline int cdiv(int a, int b) { return (a + b - 1) / b; }

extern "C" void kernel_launch(void* const* d_in, const int* in_sizes, int n_in,
                              void* d_out, int out_size, void* d_ws, size_t ws_size,
                              hipStream_t stream) {
  const float* x      = (const float*)d_in[0];
  const int*   ei     = (const int*)d_in[1];
  const int*   batch  = (const int*)d_in[2];
  const float* W1     = (const float*)d_in[3];
  const float* b1     = (const float*)d_in[4];
  const float* W2     = (const float*)d_in[5];
  const float* a_src2 = (const float*)d_in[6];
  const float* a_dst2 = (const float*)d_in[7];
  const float* b2     = (const float*)d_in[8];
  const float* W3     = (const float*)d_in[9];
  const float* a_src3 = (const float*)d_in[10];
  const float* a_dst3 = (const float*)d_in[11];
  const float* b3     = (const float*)d_in[12];
  const float* Wfc    = (const float*)d_in[13];
  const float* bfc    = (const float*)d_in[14];
  float* out = (float*)d_out;

  const int N = in_sizes[2];       // 50000
  const int E = in_sizes[1] / 2;   // 800000
  const int G = out_size / 2;      // 512
  const int TOT = E + N;           // edges incl. self-loops
  const int bw  = cdiv(N, NB);     // dst-range per bucket (98)
  const int nWG = cdiv(TOT, CH);   // chunks (104)
  const int M   = NB * nWG;        // count-matrix size

  // workspace layout (~70 MB), fp16 buffers first (16B-aligned offsets)
  char* wsb = (char*)d_ws;
  __half* h1    = (__half*)wsb;                       // N*64 fp16
  __half* h2    = h1 + (size_t)N * 64;                // N*128 fp16 (reused as h3)
  __half* out1h = h2 + (size_t)N * 128;               // N*64 fp16 (x1)
  __half* out2h = out1h + (size_t)N * 64;             // N*128 fp16 (x2)
  float*  out3  = (float*)(out2h + (size_t)N * 128);  // N*64 f32 (x3)
  float*  alpha = out3 + (size_t)N * 64;              // TOT*2 f32
  float*  dis   = alpha + (size_t)TOT * 2;            // N
  float*  al_s  = dis + N;                            // N*2 planar
  float*  al_d  = al_s + (size_t)N * 2;               // N*2 planar
  float*  den   = al_d + (size_t)N * 2;               // N*2 planar
  float*  part  = den + (size_t)N * 2;                // G*PS*64
  int* counts   = (int*)(part + (size_t)G * PS * 64); // M
  int* off      = counts + M;                         // M
  int* btot     = off + M;                            // NB
  int* bbase    = btot + NB;                          // NB+1
  unsigned int* ebuf = (unsigned int*)(bbase + NB + 1);  // TOT
  int* csr_src  = (int*)(ebuf + TOT);                 // TOT
  int* row_ptr  = csr_src + TOT;                      // N+1

  // ---- CSR build: atomic-free radix bucketing, factored parallel scan
  hist_a<<<nWG, BDIM, 0, stream>>>(ei, E, TOT, bw, counts, nWG);
  scan_bucket<<<cdiv(NB, 4), BDIM, 0, stream>>>(counts, nWG, off, btot);
  scan_tot<<<1, 512, 0, stream>>>(btot, bbase, row_ptr, N, TOT);
  bucket_b<<<nWG, BDIM, 0, stream>>>(ei, E, TOT, bw, off, bbase, nWG, ebuf);
  csr_c<<<NB, BDIM, 0, stream>>>(ebuf, bbase, N, bw, row_ptr, dis, csr_src);

  // ---- GCN layer
  gemm_mfma<128, 64, true, 0><<<cdiv(N, 64), BDIM, 0, stream>>>(
      x, W1, (_Float16*)h1, nullptr, nullptr, nullptr, nullptr, N);
  gcn_gather<<<cdiv(N, 4), BDIM, 0, stream>>>(h1, row_ptr, csr_src, dis, b1, out1h, N);

  // ---- GAT layer 1 (heads=2, concat; att_coef fused into GEMM epilogue)
  gemm_mfma<64, 128, false, 2><<<cdiv(N, 64), BDIM, 0, stream>>>(
      out1h, W2, (_Float16*)h2, a_src2, a_dst2, al_s, al_d, N);
  gat_alpha<2><<<cdiv(N * 2, 4), BDIM, 0, stream>>>(row_ptr, csr_src, al_s, al_d,
                                                    alpha, den, N);
  gat_acc2<<<cdiv(N, 4), BDIM, 0, stream>>>(h2, row_ptr, csr_src, (const float2*)alpha,
                                            den, b2, out2h, N);

  // ---- GAT layer 2 (heads=1, mean == identity)
  __half* h3 = h2;  // h2 dead after gat_acc2
  gemm_mfma<128, 64, false, 1><<<cdiv(N, 64), BDIM, 0, stream>>>(
      out2h, W3, (_Float16*)h3, a_src3, a_dst3, al_s, al_d, N);
  gat_alpha<1><<<cdiv(N, 4), BDIM, 0, stream>>>(row_ptr, csr_src, al_s, al_d,
                                                alpha, den, N);
  gat_acc1<<<cdiv(N, 4), BDIM, 0, stream>>>(h3, row_ptr, csr_src, alpha, den,
                                            b3, out3, N);

  // ---- global mean pool + fc + log_softmax (atomic-free; batch is sorted)
  pool_partial<<<cdiv(G * PS, 4), BDIM, 0, stream>>>(out3, batch, part, N, G);
  pool_head<<<cdiv(G, 4), BDIM, 0, stream>>>(part, batch, Wfc, bfc, out, N, G);
}

// Round 11
// 288.163 us; speedup vs baseline: 4.8548x; 1.0735x over previous
//
#include <hip/hip_runtime.h>
#include <hip/hip_bf16.h>
#include <hip/hip_fp16.h>
#include <math.h>

#define BDIM 256

using v8h = __attribute__((ext_vector_type(8))) _Float16;
using v4f = __attribute__((ext_vector_type(4))) float;

// CSR-build tuning: 512 dst-range buckets, 8192-edge chunks, 4096-edge bucket cap
#define NB  512
#define CH  8192
#define CAP 4096
// pool slices per graph
#define PS  8

// ---------------------------------------------------------------- utilities

__device__ __forceinline__ float wave_max64(float v) {
#pragma unroll
  for (int o = 32; o > 0; o >>= 1) v = fmaxf(v, __shfl_xor(v, o, 64));
  return v;
}
__device__ __forceinline__ float wave_sum64(float v) {
#pragma unroll
  for (int o = 32; o > 0; o >>= 1) v += __shfl_xor(v, o, 64);
  return v;
}

__device__ __forceinline__ float leaky02(float v) {
  return v >= 0.0f ? v : 0.2f * v;
}

// ---------------------------------------------------------------- MFMA GEMM
// C[N,KOUT](fp16) = A[N,KIN] @ W[KIN,KOUT] (fp16 compute, fp32 acc).
// Wave computes 16 rows x KOUT cols. A-frag: A[m=lane&15][k=quad*8+j].
// W transposed to LDS fp16, row padded +8 halves to break bank conflicts.
// C/D frag: col = nt*16 + (lane&15), row = quad*4 + r (HW-verified).
// HEADS>0: fused attention coefficients al_s/al_d from fp32 accumulators.
// SCALE: multiply each output row by rs[row] (GCN dis pre-scaling).
template <int KIN, int KOUT, bool A_FP32, int HEADS, bool SCALE>
__launch_bounds__(BDIM) __global__
void gemm_mfma(const void* __restrict__ Ap, const float* __restrict__ W,
               _Float16* __restrict__ C, const float* __restrict__ rs,
               const float* __restrict__ a_src, const float* __restrict__ a_dst,
               float* __restrict__ al_s, float* __restrict__ al_d, int N) {
  constexpr int KP = KIN + 8;
  constexpr int NT = KOUT / 16;
  __shared__ _Float16 Wt[KOUT * KP];
  int tid = threadIdx.x;
  for (int i = tid; i < KIN * KOUT; i += BDIM) {
    int k = i / KOUT, n = i % KOUT;
    Wt[n * KP + k] = (_Float16)W[i];
  }
  __syncthreads();
  int lane = tid & 63;
  int quad = lane >> 4, l16 = lane & 15;
  int m0 = blockIdx.x * 64 + (tid >> 6) * 16;
  if (m0 >= N) return;  // N % 16 == 0: whole wave in or out
  v4f acc[NT];
#pragma unroll
  for (int nt = 0; nt < NT; ++nt) acc[nt] = (v4f){0.0f, 0.0f, 0.0f, 0.0f};
#pragma unroll
  for (int k0 = 0; k0 < KIN; k0 += 32) {
    v8h a;
    if constexpr (A_FP32) {
      const float* ap = (const float*)Ap + (size_t)(m0 + l16) * KIN + k0 + quad * 8;
#pragma unroll
      for (int j = 0; j < 8; ++j) a[j] = (_Float16)ap[j];
    } else {
      a = *(const v8h*)((const _Float16*)Ap + (size_t)(m0 + l16) * KIN + k0 + quad * 8);
    }
#pragma unroll
    for (int nt = 0; nt < NT; ++nt) {
      v8h b = *(const v8h*)&Wt[(nt * 16 + l16) * KP + k0 + quad * 8];
      acc[nt] = __builtin_amdgcn_mfma_f32_16x16x32_f16(a, b, acc[nt], 0, 0, 0);
    }
  }
  float sc[4];
#pragma unroll
  for (int r = 0; r < 4; ++r) sc[r] = SCALE ? rs[m0 + quad * 4 + r] : 1.0f;
#pragma unroll
  for (int nt = 0; nt < NT; ++nt)
#pragma unroll
    for (int r = 0; r < 4; ++r)
      C[(size_t)(m0 + quad * 4 + r) * KOUT + nt * 16 + l16] =
          (_Float16)(acc[nt][r] * sc[r]);

  if constexpr (HEADS > 0) {
    constexpr int TPH = NT / HEADS;     // MFMA tiles per head
    constexpr int FPH = KOUT / HEADS;   // features per head
    float av_s[NT], av_d[NT];
#pragma unroll
    for (int nt = 0; nt < NT; ++nt) {
      int head = nt / TPH, c = (nt % TPH) * 16 + l16;
      av_s[nt] = a_src[head * FPH + c];
      av_d[nt] = a_dst[head * FPH + c];
    }
#pragma unroll
    for (int r = 0; r < 4; ++r) {
#pragma unroll
      for (int head = 0; head < HEADS; ++head) {
        float ps = 0.0f, pd = 0.0f;
#pragma unroll
        for (int t = 0; t < TPH; ++t) {
          int nt = head * TPH + t;
          ps += acc[nt][r] * av_s[nt];
          pd += acc[nt][r] * av_d[nt];
        }
#pragma unroll
        for (int o = 1; o < 16; o <<= 1) {
          ps += __shfl_xor(ps, o, 64);
          pd += __shfl_xor(pd, o, 64);
        }
        if (l16 == 0) {
          int row = m0 + quad * 4 + r;
          al_s[(size_t)head * N + row] = ps;
          al_d[(size_t)head * N + row] = pd;
        }
      }
    }
  }
}

// ---------------------------------------------------------------- CSR build
// Atomic-free (LDS atomics only): hist -> factored parallel scan -> bucket
// scatter -> per-bucket CSR.

// Pass A: per-chunk LDS histogram over NB dst-range buckets; coalesced count dump.
__launch_bounds__(BDIM) __global__
void hist_a(const int* __restrict__ ei, int E, int TOT, int bw,
            int* __restrict__ counts, int nWG) {
  __shared__ int hist[NB];
  int tid = threadIdx.x, wg = blockIdx.x;
  for (int i = tid; i < NB; i += BDIM) hist[i] = 0;
  __syncthreads();
  int base = wg * CH, lim = min(CH, TOT - base);
  for (int i = tid; i < lim; i += BDIM) {
    int e = base + i;
    int dst = (e < E) ? ei[E + e] : (e - E);
    atomicAdd(&hist[dst / bw], 1);
  }
  __syncthreads();
  for (int b = tid; b < NB; b += BDIM) counts[(size_t)b * nWG + wg] = hist[b];
}

// one wave per bucket: exclusive scan of its nWG chunk-counts (within-bucket)
__launch_bounds__(BDIM) __global__
void scan_bucket(const int* __restrict__ counts, int nWG,
                 int* __restrict__ off, int* __restrict__ btot) {
  int b = blockIdx.x * (BDIM / 64) + (threadIdx.x >> 6);
  int lane = threadIdx.x & 63;
  if (b >= NB) return;
  const int* c = counts + (size_t)b * nWG;
  int* o = off + (size_t)b * nWG;
  int carry = 0;
  for (int base = 0; base < nWG; base += 64) {
    int i = base + lane;
    int v = (i < nWG) ? c[i] : 0;
    int incl = v;
#pragma unroll
    for (int s = 1; s < 64; s <<= 1) {
      int t = __shfl_up(incl, s, 64);
      if (lane >= s) incl += t;
    }
    if (i < nWG) o[i] = carry + incl - v;
    carry += __shfl(incl, 63, 64);
  }
  if (lane == 0) btot[b] = carry;
}

// single 512-thread WG: exclusive scan of the NB bucket totals -> bbase[NB+1]
__launch_bounds__(512) __global__
void scan_tot(const int* __restrict__ btot, int* __restrict__ bbase,
              int* __restrict__ row_ptr, int N, int TOT) {
  __shared__ int wsum[8], wpre[8];
  int tid = threadIdx.x, lane = tid & 63, w = tid >> 6;
  int v = btot[tid];  // NB == 512 == blockDim
  int incl = v;
#pragma unroll
  for (int o = 1; o < 64; o <<= 1) {
    int t = __shfl_up(incl, o, 64);
    if (lane >= o) incl += t;
  }
  if (lane == 63) wsum[w] = incl;
  __syncthreads();
  if (w == 0 && lane < 8) {
    int s = wsum[lane];
#pragma unroll
    for (int o = 1; o < 8; o <<= 1) {
      int t = __shfl_up(s, o, 64);
      if (lane >= o) s += t;
    }
    wpre[lane] = s - wsum[lane];
  }
  __syncthreads();
  bbase[tid] = wpre[w] + incl - v;
  if (tid == 0) { bbase[NB] = TOT; row_ptr[N] = TOT; }
}

// Pass B: scatter edges into bucket-major ebuf, packed (dst_local<<17 | src).
__launch_bounds__(BDIM) __global__
void bucket_b(const int* __restrict__ ei, int E, int TOT, int bw,
              const int* __restrict__ off, const int* __restrict__ bbase,
              int nWG, unsigned int* __restrict__ ebuf) {
  __shared__ int cur[NB];
  int tid = threadIdx.x, wg = blockIdx.x;
  for (int b = tid; b < NB; b += BDIM)
    cur[b] = bbase[b] + off[(size_t)b * nWG + wg];
  __syncthreads();
  int base = wg * CH, lim = min(CH, TOT - base);
  for (int i = tid; i < lim; i += BDIM) {
    int e = base + i;
    int src, dst;
    if (e < E) { src = ei[e]; dst = ei[E + e]; }
    else       { src = dst = e - E; }
    int b = dst / bw;
    int pos = atomicAdd(&cur[b], 1);
    ebuf[pos] = ((unsigned int)(dst - b * bw) << 17) | (unsigned int)src;
  }
}

// Pass C: one WG per bucket. Build CSR segment fully in LDS; all global IO coalesced.
__launch_bounds__(BDIM) __global__
void csr_c(const unsigned int* __restrict__ ebuf, const int* __restrict__ bbase,
           int N, int bw,
           int* __restrict__ row_ptr, float* __restrict__ dis,
           int* __restrict__ csr_src) {
  __shared__ unsigned int eb[CAP];
  __shared__ unsigned int ob[CAP];
  __shared__ int cnt[128], loff[128], cur[128];
  int tid = threadIdx.x, b = blockIdx.x;
  int d0 = b * bw;
  if (d0 >= N) return;
  int width = min(bw, N - d0);
  int sbase = bbase[b];
  int send = bbase[b + 1];
  int nb = send - sbase;
  if (tid < 128) cnt[tid] = 0;
  __syncthreads();
  for (int i = tid; i < nb; i += BDIM) {
    unsigned int v = ebuf[sbase + i];
    eb[i] = v;
    atomicAdd(&cnt[v >> 17], 1);
  }
  __syncthreads();
  if (tid < 64) {  // wave 0: exclusive scan of 128 counters (2 per lane)
    int c0 = cnt[tid * 2], c1 = cnt[tid * 2 + 1];
    int s = c0 + c1;
    int incl = s;
#pragma unroll
    for (int o = 1; o < 64; o <<= 1) {
      int t = __shfl_up(incl, o, 64);
      if (tid >= o) incl += t;
    }
    int excl = incl - s;
    loff[tid * 2] = excl;
    loff[tid * 2 + 1] = excl + c0;
  }
  __syncthreads();
  if (tid < width) {
    row_ptr[d0 + tid] = sbase + loff[tid];
    dis[d0 + tid] = rsqrtf((float)cnt[tid]);  // deg >= 1 (self-loops)
    cur[tid] = loff[tid];
  }
  __syncthreads();
  for (int i = tid; i < nb; i += BDIM) {
    unsigned int v = eb[i];
    int p = atomicAdd(&cur[v >> 17], 1);
    ob[p] = v & 0x1FFFFu;
  }
  __syncthreads();
  for (int i = tid; i < nb; i += BDIM) csr_src[sbase + i] = (int)ob[i];
}

// ---------------------------------------------------------------- GCN gather
// wave per dst node, lane = feature; h is pre-scaled by dis[src] (GEMM epilogue)
// out = relu(dis[dst] * sum(h'[src]) + b); 8-deep batched loads, scalar tail.
__launch_bounds__(BDIM) __global__
void gcn_gather(const __half* __restrict__ h, const int* __restrict__ row_ptr,
                const int* __restrict__ csr_src, const float* __restrict__ dis,
                const float* __restrict__ b, __half* __restrict__ out, int N) {
  constexpr int U = 8;
  int wid = blockIdx.x * (BDIM / 64) + (threadIdx.x >> 6);
  int lane = threadIdx.x & 63;
  if (wid >= N) return;
  int beg = row_ptr[wid], end = row_ptr[wid + 1];
  float acc = 0.0f;
  for (int base = beg; base < end; base += 64) {
    int nch = min(64, end - base);
    int s_l = (lane < nch) ? csr_src[base + lane] : 0;
    int jfull = nch & ~(U - 1);
    for (int j = 0; j < jfull; j += U) {
      int ss[U]; __half vv[U];
#pragma unroll
      for (int u = 0; u < U; ++u) ss[u] = __shfl(s_l, j + u, 64);
#pragma unroll
      for (int u = 0; u < U; ++u) vv[u] = h[(size_t)ss[u] * 64 + lane];
#pragma unroll
      for (int u = 0; u < U; ++u) acc += __half2float(vv[u]);
    }
    for (int j = jfull; j < nch; ++j) {
      int s = __shfl(s_l, j, 64);
      acc += __half2float(h[(size_t)s * 64 + lane]);
    }
  }
  out[(size_t)wid * 64 + lane] = __float2half(fmaxf(acc * dis[wid] + b[lane], 0.0f));
}

// ---------------------------------------------------------------- GAT (fused)
// Layer 1: wave per dst, BOTH heads. Phase 1: lane-per-edge softmax (al_s
// gathers, wave max/sum). Phase 2: U=8 batched h-row gathers, alpha via shfl
// from registers. deg>64 fallback recomputes ex chunk-wise.
__launch_bounds__(BDIM) __global__
void gat_fused2(const __half* __restrict__ h, const int* __restrict__ row_ptr,
                const int* __restrict__ csr_src, const float* __restrict__ al_s,
                const float* __restrict__ al_d, const float* __restrict__ b,
                __half* __restrict__ out, int N) {
  constexpr int U = 8;
  int wid = blockIdx.x * (BDIM / 64) + (threadIdx.x >> 6);
  int lane = threadIdx.x & 63;
  if (wid >= N) return;
  int head = lane >> 5;
  const __half2* hrow = (const __half2*)h;  // 64 half2 per node row
  int beg = row_ptr[wid], end = row_ptr[wid + 1];
  int deg = end - beg;
  float ad0 = al_d[wid], ad1 = al_d[(size_t)N + wid];
  float accx = 0.0f, accy = 0.0f, l0, l1;
  if (deg <= 64) {
    int s_l = (lane < deg) ? csr_src[beg + lane] : 0;
    float e0 = (lane < deg) ? leaky02(al_s[s_l] + ad0) : -3.4e38f;
    float e1 = (lane < deg) ? leaky02(al_s[(size_t)N + s_l] + ad1) : -3.4e38f;
    float m0 = wave_max64(e0), m1 = wave_max64(e1);
    float ex0 = (lane < deg) ? expf(e0 - m0) : 0.0f;
    float ex1 = (lane < deg) ? expf(e1 - m1) : 0.0f;
    l0 = wave_sum64(ex0);
    l1 = wave_sum64(ex1);
    int jmax = (deg + U - 1) & ~(U - 1);
    for (int j = 0; j < jmax; j += U) {
      int ss[U]; float aa[U]; __half2 vv[U];
#pragma unroll
      for (int u = 0; u < U; ++u) {
        ss[u] = __shfl(s_l, j + u, 64);
        float a0 = __shfl(ex0, j + u, 64);
        float a1 = __shfl(ex1, j + u, 64);
        aa[u] = head ? a1 : a0;  // pad lanes: ex==0 -> no contribution
      }
#pragma unroll
      for (int u = 0; u < U; ++u) vv[u] = hrow[(size_t)ss[u] * 64 + lane];
#pragma unroll
      for (int u = 0; u < U; ++u) {
        float2 v = __half22float2(vv[u]);
        accx += aa[u] * v.x;
        accy += aa[u] * v.y;
      }
    }
  } else {  // rare: two-pass recompute
    float m0 = -3.4e38f, m1 = -3.4e38f;
    for (int base = beg; base < end; base += 64) {
      int nch = min(64, end - base);
      int s = (lane < nch) ? csr_src[base + lane] : 0;
      float e0 = (lane < nch) ? leaky02(al_s[s] + ad0) : -3.4e38f;
      float e1 = (lane < nch) ? leaky02(al_s[(size_t)N + s] + ad1) : -3.4e38f;
      m0 = fmaxf(m0, wave_max64(e0));
      m1 = fmaxf(m1, wave_max64(e1));
    }
    l0 = l1 = 0.0f;
    for (int base = beg; base < end; base += 64) {
      int nch = min(64, end - base);
      int s_l = (lane < nch) ? csr_src[base + lane] : 0;
      float ex0 = 0.0f, ex1 = 0.0f;
      if (lane < nch) {
        ex0 = expf(leaky02(al_s[s_l] + ad0) - m0);
        ex1 = expf(leaky02(al_s[(size_t)N + s_l] + ad1) - m1);
      }
      l0 += wave_sum64(ex0);
      l1 += wave_sum64(ex1);
      int jmax = (nch + U - 1) & ~(U - 1);
      for (int j = 0; j < jmax; j += U) {
        int ss[U]; float aa[U]; __half2 vv[U];
#pragma unroll
        for (int u = 0; u < U; ++u) {
          ss[u] = __shfl(s_l, j + u, 64);
          float a0 = __shfl(ex0, j + u, 64);
          float a1 = __shfl(ex1, j + u, 64);
          aa[u] = head ? a1 : a0;
        }
#pragma unroll
        for (int u = 0; u < U; ++u) vv[u] = hrow[(size_t)ss[u] * 64 + lane];
#pragma unroll
        for (int u = 0; u < U; ++u) {
          float2 v = __half22float2(vv[u]);
          accx += aa[u] * v.x;
          accy += aa[u] * v.y;
        }
      }
    }
  }
  float dn = head ? l1 : l0;
  const float2* b2v = (const float2*)b;
  float2 bb = b2v[lane];
  float ox = fmaxf(accx / dn + bb.x, 0.0f);  // relu fused
  float oy = fmaxf(accy / dn + bb.y, 0.0f);
  ((__half2*)out)[(size_t)wid * 64 + lane] = __floats2half2_rn(ox, oy);
}

// Layer 2 fused (1 head, 64 feats); fp16 out, no relu.
__launch_bounds__(BDIM) __global__
void gat_fused1(const __half* __restrict__ h, const int* __restrict__ row_ptr,
                const int* __restrict__ csr_src, const float* __restrict__ al_s,
                const float* __restrict__ al_d, const float* __restrict__ b,
                __half* __restrict__ out, int N) {
  constexpr int U = 8;
  int wid = blockIdx.x * (BDIM / 64) + (threadIdx.x >> 6);
  int lane = threadIdx.x & 63;
  if (wid >= N) return;
  int beg = row_ptr[wid], end = row_ptr[wid + 1];
  int deg = end - beg;
  float ad = al_d[wid];
  float acc = 0.0f, l;
  if (deg <= 64) {
    int s_l = (lane < deg) ? csr_src[beg + lane] : 0;
    float e = (lane < deg) ? leaky02(al_s[s_l] + ad) : -3.4e38f;
    float m = wave_max64(e);
    float ex = (lane < deg) ? expf(e - m) : 0.0f;
    l = wave_sum64(ex);
    int jmax = (deg + U - 1) & ~(U - 1);
    for (int j = 0; j < jmax; j += U) {
      int ss[U]; float aa[U]; __half vv[U];
#pragma unroll
      for (int u = 0; u < U; ++u) {
        ss[u] = __shfl(s_l, j + u, 64);
        aa[u] = __shfl(ex, j + u, 64);
      }
#pragma unroll
      for (int u = 0; u < U; ++u) vv[u] = h[(size_t)ss[u] * 64 + lane];
#pragma unroll
      for (int u = 0; u < U; ++u) acc += aa[u] * __half2float(vv[u]);
    }
  } else {
    float m = -3.4e38f;
    for (int base = beg; base < end; base += 64) {
      int nch = min(64, end - base);
      int s = (lane < nch) ? csr_src[base + lane] : 0;
      float e = (lane < nch) ? leaky02(al_s[s] + ad) : -3.4e38f;
      m = fmaxf(m, wave_max64(e));
    }
    l = 0.0f;
    for (int base = beg; base < end; base += 64) {
      int nch = min(64, end - base);
      int s_l = (lane < nch) ? csr_src[base + lane] : 0;
      float ex = (lane < nch) ? expf(leaky02(al_s[s_l] + ad) - m) : 0.0f;
      l += wave_sum64(ex);
      int jmax = (nch + U - 1) & ~(U - 1);
      for (int j = 0; j < jmax; j += U) {
        int ss[U]; float aa[U]; __half vv[U];
#pragma unroll
        for (int u = 0; u < U; ++u) {
          ss[u] = __shfl(s_l, j + u, 64);
          aa[u] = __shfl(ex, j + u, 64);
        }
#pragma unroll
        for (int u = 0; u < U; ++u) vv[u] = h[(size_t)ss[u] * 64 + lane];
#pragma unroll
        for (int u = 0; u < U; ++u) acc += aa[u] * __half2float(vv[u]);
      }
    }
  }
  out[(size_t)wid * 64 + lane] = __float2half(acc / l + b[lane]);
}

// ---------------------------------------------------------------- pool + head
__device__ __forceinline__ int lower_bound(const int* __restrict__ a, int n, int v) {
  int lo = 0, hi = n;
  while (lo < hi) {
    int mid = (lo + hi) >> 1;
    if (a[mid] < v) lo = mid + 1; else hi = mid;
  }
  return lo;
}

// stage A: wave per (graph, slice): sum a contiguous slice of the graph's rows.
__launch_bounds__(BDIM) __global__
void pool_partial(const __half* __restrict__ x3, const int* __restrict__ batch,
                  float* __restrict__ part, int N, int G) {
  int wid = blockIdx.x * (BDIM / 64) + (threadIdx.x >> 6);
  int lane = threadIdx.x & 63;
  if (wid >= G * PS) return;
  int g = wid / PS, s = wid % PS;
  int beg = lower_bound(batch, N, g);
  int end = lower_bound(batch, N, g + 1);
  int len = end - beg;
  int lo = beg + (int)((long long)len * s / PS);
  int hi = beg + (int)((long long)len * (s + 1) / PS);
  float acc = 0.0f;
  int n = lo;
  for (; n + 4 <= hi; n += 4) {  // 4 independent line-loads in flight
    float a0 = __half2float(x3[(size_t)(n + 0) * 64 + lane]);
    float a1 = __half2float(x3[(size_t)(n + 1) * 64 + lane]);
    float a2 = __half2float(x3[(size_t)(n + 2) * 64 + lane]);
    float a3 = __half2float(x3[(size_t)(n + 3) * 64 + lane]);
    acc += (a0 + a1) + (a2 + a3);
  }
  for (; n < hi; ++n) acc += __half2float(x3[(size_t)n * 64 + lane]);
  part[(size_t)wid * 64 + lane] = acc;
}

// stage B: wave per graph: reduce PS partials, mean, FC, log_softmax.
__launch_bounds__(BDIM) __global__
void pool_head(const float* __restrict__ part, const int* __restrict__ batch,
               const float* __restrict__ Wfc, const float* __restrict__ bfc,
               float* __restrict__ out, int N, int G) {
  int wid = blockIdx.x * (BDIM / 64) + (threadIdx.x >> 6);
  int lane = threadIdx.x & 63;
  if (wid >= G) return;
  float acc = 0.0f;
#pragma unroll
  for (int s = 0; s < PS; ++s) acc += part[((size_t)wid * PS + s) * 64 + lane];
  int beg = lower_bound(batch, N, wid);
  int end = lower_bound(batch, N, wid + 1);
  float p = (end > beg) ? acc / (float)(end - beg) : 0.0f;
  float l0 = wave_sum64(p * Wfc[lane * 2 + 0]);
  float l1 = wave_sum64(p * Wfc[lane * 2 + 1]);
  if (lane == 0) {
    l0 += bfc[0];
    l1 += bfc[1];
    float m = fmaxf(l0, l1);
    float ls = m + logf(expf(l0 - m) + expf(l1 - m));
    out[wid * 2 + 0] = l0 - ls;
    out[wid * 2 + 1] = l1 - ls;
  }
}

// ---------------------------------------------------------------- launch

static inline int cdiv(int a, int b) { return (a + b - 1) / b; }

extern "C" void kernel_launch(void* const* d_in, const int* in_sizes, int n_in,
                              void* d_out, int out_size, void* d_ws, size_t ws_size,
                              hipStream_t stream) {
  const float* x      = (const float*)d_in[0];
  const int*   ei     = (const int*)d_in[1];
  const int*   batch  = (const int*)d_in[2];
  const float* W1     = (const float*)d_in[3];
  const float* b1     = (const float*)d_in[4];
  const float* W2     = (const float*)d_in[5];
  const float* a_src2 = (const float*)d_in[6];
  const float* a_dst2 = (const float*)d_in[7];
  const float* b2     = (const float*)d_in[8];
  const float* W3     = (const float*)d_in[9];
  const float* a_src3 = (const float*)d_in[10];
  const float* a_dst3 = (const float*)d_in[11];
  const float* b3     = (const float*)d_in[12];
  const float* Wfc    = (const float*)d_in[13];
  const float* bfc    = (const float*)d_in[14];
  float* out = (float*)d_out;

  const int N = in_sizes[2];       // 50000
  const int E = in_sizes[1] / 2;   // 800000
  const int G = out_size / 2;      // 512
  const int TOT = E + N;           // edges incl. self-loops
  const int bw  = cdiv(N, NB);     // dst-range per bucket (98)
  const int nWG = cdiv(TOT, CH);   // chunks (104)
  const int M   = NB * nWG;        // count-matrix size

  // workspace layout, fp16 buffers first (16B-aligned offsets)
  char* wsb = (char*)d_ws;
  __half* h1    = (__half*)wsb;                       // N*64 fp16
  __half* h2    = h1 + (size_t)N * 64;                // N*128 fp16 (reused as h3)
  __half* out1h = h2 + (size_t)N * 128;               // N*64 fp16 (x1)
  __half* out2h = out1h + (size_t)N * 64;             // N*128 fp16 (x2)
  __half* out3h = out2h + (size_t)N * 128;            // N*64 fp16 (x3)
  float*  dis   = (float*)(out3h + (size_t)N * 64);   // N
  float*  al_s  = dis + N;                            // N*2 planar
  float*  al_d  = al_s + (size_t)N * 2;               // N*2 planar
  float*  part  = al_d + (size_t)N * 2;               // G*PS*64
  int* counts   = (int*)(part + (size_t)G * PS * 64); // M
  int* off      = counts + M;                         // M
  int* btot     = off + M;                            // NB
  int* bbase    = btot + NB;                          // NB+1
  unsigned int* ebuf = (unsigned int*)(bbase + NB + 1);  // TOT
  int* csr_src  = (int*)(ebuf + TOT);                 // TOT
  int* row_ptr  = csr_src + TOT;                      // N+1

  // ---- CSR build: atomic-free radix bucketing, factored parallel scan
  hist_a<<<nWG, BDIM, 0, stream>>>(ei, E, TOT, bw, counts, nWG);
  scan_bucket<<<cdiv(NB, 4), BDIM, 0, stream>>>(counts, nWG, off, btot);
  scan_tot<<<1, 512, 0, stream>>>(btot, bbase, row_ptr, N, TOT);
  bucket_b<<<nWG, BDIM, 0, stream>>>(ei, E, TOT, bw, off, bbase, nWG, ebuf);
  csr_c<<<NB, BDIM, 0, stream>>>(ebuf, bbase, N, bw, row_ptr, dis, csr_src);

  // ---- GCN layer (h1 pre-scaled by dis[row] in GEMM epilogue)
  gemm_mfma<128, 64, true, 0, true><<<cdiv(N, 64), BDIM, 0, stream>>>(
      x, W1, (_Float16*)h1, dis, nullptr, nullptr, nullptr, nullptr, N);
  gcn_gather<<<cdiv(N, 4), BDIM, 0, stream>>>(h1, row_ptr, csr_src, dis, b1, out1h, N);

  // ---- GAT layer 1 (heads=2, concat; att_coef fused into GEMM epilogue,
  //      softmax fused into accumulate)
  gemm_mfma<64, 128, false, 2, false><<<cdiv(N, 64), BDIM, 0, stream>>>(
      out1h, W2, (_Float16*)h2, nullptr, a_src2, a_dst2, al_s, al_d, N);
  gat_fused2<<<cdiv(N, 4), BDIM, 0, stream>>>(h2, row_ptr, csr_src, al_s, al_d,
                                              b2, out2h, N);

  // ---- GAT layer 2 (heads=1, mean == identity)
  __half* h3 = h2;  // h2 dead after gat_fused2
  gemm_mfma<128, 64, false, 1, false><<<cdiv(N, 64), BDIM, 0, stream>>>(
      out2h, W3, (_Float16*)h3, nullptr, a_src3, a_dst3, al_s, al_d, N);
  gat_fused1<<<cdiv(N, 4), BDIM, 0, stream>>>(h3, row_ptr, csr_src, al_s, al_d,
                                              b3, out3h, N);

  // ---- global mean pool + fc + log_softmax (atomic-free; batch is sorted)
  pool_partial<<<cdiv(G * PS, 4), BDIM, 0, stream>>>(out3h, batch, part, N, G);
  pool_head<<<cdiv(G, 4), BDIM, 0, stream>>>(part, batch, Wfc, bfc, out, N, G);
}

// Round 12
// 277.558 us; speedup vs baseline: 5.0403x; 1.0382x over previous
//
#include <hip/hip_runtime.h>
#include <hip/hip_bf16.h>
#include <hip/hip_fp16.h>
#include <math.h>

#define BDIM 256

using v8h = __attribute__((ext_vector_type(8))) _Float16;
using v4f = __attribute__((ext_vector_type(4))) float;

// CSR-build tuning: 512 dst-range buckets, 8192-edge chunks, 4096-edge bucket cap
#define NB  512
#define CH  8192
#define CAP 4096
// pool slices per graph
#define PS  8

// ---------------------------------------------------------------- utilities

__device__ __forceinline__ float wave_max64(float v) {
#pragma unroll
  for (int o = 32; o > 0; o >>= 1) v = fmaxf(v, __shfl_xor(v, o, 64));
  return v;
}
__device__ __forceinline__ float wave_sum64(float v) {
#pragma unroll
  for (int o = 32; o > 0; o >>= 1) v += __shfl_xor(v, o, 64);
  return v;
}

__device__ __forceinline__ float leaky02(float v) {
  return v >= 0.0f ? v : 0.2f * v;
}

// ---------------------------------------------------------------- MFMA GEMM
// C[N,KOUT](fp16) = A[N,KIN] @ W[KIN,KOUT] (fp16 compute, fp32 acc).
// Wave computes 16 rows x KOUT cols. A-frag: A[m=lane&15][k=quad*8+j].
// W transposed to LDS fp16, row padded +8 halves to break bank conflicts.
// C/D frag: col = nt*16 + (lane&15), row = quad*4 + r (HW-verified).
// HEADS>0: fused attention coefficients al_s/al_d from fp32 accumulators.
// SCALE: multiply each output row by rs[row] (GCN dis pre-scaling).
template <int KIN, int KOUT, bool A_FP32, int HEADS, bool SCALE>
__launch_bounds__(BDIM) __global__
void gemm_mfma(const void* __restrict__ Ap, const float* __restrict__ W,
               _Float16* __restrict__ C, const float* __restrict__ rs,
               const float* __restrict__ a_src, const float* __restrict__ a_dst,
               float* __restrict__ al_s, float* __restrict__ al_d, int N) {
  constexpr int KP = KIN + 8;
  constexpr int NT = KOUT / 16;
  __shared__ _Float16 Wt[KOUT * KP];
  int tid = threadIdx.x;
  for (int i = tid; i < KIN * KOUT; i += BDIM) {
    int k = i / KOUT, n = i % KOUT;
    Wt[n * KP + k] = (_Float16)W[i];
  }
  __syncthreads();
  int lane = tid & 63;
  int quad = lane >> 4, l16 = lane & 15;
  int m0 = blockIdx.x * 64 + (tid >> 6) * 16;
  if (m0 >= N) return;  // N % 16 == 0: whole wave in or out
  v4f acc[NT];
#pragma unroll
  for (int nt = 0; nt < NT; ++nt) acc[nt] = (v4f){0.0f, 0.0f, 0.0f, 0.0f};
#pragma unroll
  for (int k0 = 0; k0 < KIN; k0 += 32) {
    v8h a;
    if constexpr (A_FP32) {
      const float* ap = (const float*)Ap + (size_t)(m0 + l16) * KIN + k0 + quad * 8;
#pragma unroll
      for (int j = 0; j < 8; ++j) a[j] = (_Float16)ap[j];
    } else {
      a = *(const v8h*)((const _Float16*)Ap + (size_t)(m0 + l16) * KIN + k0 + quad * 8);
    }
#pragma unroll
    for (int nt = 0; nt < NT; ++nt) {
      v8h b = *(const v8h*)&Wt[(nt * 16 + l16) * KP + k0 + quad * 8];
      acc[nt] = __builtin_amdgcn_mfma_f32_16x16x32_f16(a, b, acc[nt], 0, 0, 0);
    }
  }
  float sc[4];
#pragma unroll
  for (int r = 0; r < 4; ++r) sc[r] = SCALE ? rs[m0 + quad * 4 + r] : 1.0f;
#pragma unroll
  for (int nt = 0; nt < NT; ++nt)
#pragma unroll
    for (int r = 0; r < 4; ++r)
      C[(size_t)(m0 + quad * 4 + r) * KOUT + nt * 16 + l16] =
          (_Float16)(acc[nt][r] * sc[r]);

  if constexpr (HEADS > 0) {
    constexpr int TPH = NT / HEADS;     // MFMA tiles per head
    constexpr int FPH = KOUT / HEADS;   // features per head
    float av_s[NT], av_d[NT];
#pragma unroll
    for (int nt = 0; nt < NT; ++nt) {
      int head = nt / TPH, c = (nt % TPH) * 16 + l16;
      av_s[nt] = a_src[head * FPH + c];
      av_d[nt] = a_dst[head * FPH + c];
    }
#pragma unroll
    for (int r = 0; r < 4; ++r) {
#pragma unroll
      for (int head = 0; head < HEADS; ++head) {
        float ps = 0.0f, pd = 0.0f;
#pragma unroll
        for (int t = 0; t < TPH; ++t) {
          int nt = head * TPH + t;
          ps += acc[nt][r] * av_s[nt];
          pd += acc[nt][r] * av_d[nt];
        }
#pragma unroll
        for (int o = 1; o < 16; o <<= 1) {
          ps += __shfl_xor(ps, o, 64);
          pd += __shfl_xor(pd, o, 64);
        }
        if (l16 == 0) {
          int row = m0 + quad * 4 + r;
          al_s[(size_t)head * N + row] = ps;
          al_d[(size_t)head * N + row] = pd;
        }
      }
    }
  }
}

// ---------------------------------------------------------------- CSR build
// Atomic-free (LDS atomics only): hist -> factored parallel scan -> bucket
// scatter -> per-bucket CSR.

// Pass A: per-chunk LDS histogram over NB dst-range buckets; coalesced count dump.
__launch_bounds__(BDIM) __global__
void hist_a(const int* __restrict__ ei, int E, int TOT, int bw,
            int* __restrict__ counts, int nWG) {
  __shared__ int hist[NB];
  int tid = threadIdx.x, wg = blockIdx.x;
  for (int i = tid; i < NB; i += BDIM) hist[i] = 0;
  __syncthreads();
  int base = wg * CH, lim = min(CH, TOT - base);
  for (int i = tid; i < lim; i += BDIM) {
    int e = base + i;
    int dst = (e < E) ? ei[E + e] : (e - E);
    atomicAdd(&hist[dst / bw], 1);
  }
  __syncthreads();
  for (int b = tid; b < NB; b += BDIM) counts[(size_t)b * nWG + wg] = hist[b];
}

// one wave per bucket: exclusive scan of its nWG chunk-counts (within-bucket)
__launch_bounds__(BDIM) __global__
void scan_bucket(const int* __restrict__ counts, int nWG,
                 int* __restrict__ off, int* __restrict__ btot) {
  int b = blockIdx.x * (BDIM / 64) + (threadIdx.x >> 6);
  int lane = threadIdx.x & 63;
  if (b >= NB) return;
  const int* c = counts + (size_t)b * nWG;
  int* o = off + (size_t)b * nWG;
  int carry = 0;
  for (int base = 0; base < nWG; base += 64) {
    int i = base + lane;
    int v = (i < nWG) ? c[i] : 0;
    int incl = v;
#pragma unroll
    for (int s = 1; s < 64; s <<= 1) {
      int t = __shfl_up(incl, s, 64);
      if (lane >= s) incl += t;
    }
    if (i < nWG) o[i] = carry + incl - v;
    carry += __shfl(incl, 63, 64);
  }
  if (lane == 0) btot[b] = carry;
}

// single 512-thread WG: exclusive scan of the NB bucket totals -> bbase[NB+1]
__launch_bounds__(512) __global__
void scan_tot(const int* __restrict__ btot, int* __restrict__ bbase,
              int* __restrict__ row_ptr, int N, int TOT) {
  __shared__ int wsum[8], wpre[8];
  int tid = threadIdx.x, lane = tid & 63, w = tid >> 6;
  int v = btot[tid];  // NB == 512 == blockDim
  int incl = v;
#pragma unroll
  for (int o = 1; o < 64; o <<= 1) {
    int t = __shfl_up(incl, o, 64);
    if (lane >= o) incl += t;
  }
  if (lane == 63) wsum[w] = incl;
  __syncthreads();
  if (w == 0 && lane < 8) {
    int s = wsum[lane];
#pragma unroll
    for (int o = 1; o < 8; o <<= 1) {
      int t = __shfl_up(s, o, 64);
      if (lane >= o) s += t;
    }
    wpre[lane] = s - wsum[lane];
  }
  __syncthreads();
  bbase[tid] = wpre[w] + incl - v;
  if (tid == 0) { bbase[NB] = TOT; row_ptr[N] = TOT; }
}

// Pass B: scatter edges into bucket-major ebuf, packed (dst_local<<17 | src).
__launch_bounds__(BDIM) __global__
void bucket_b(const int* __restrict__ ei, int E, int TOT, int bw,
              const int* __restrict__ off, const int* __restrict__ bbase,
              int nWG, unsigned int* __restrict__ ebuf) {
  __shared__ int cur[NB];
  int tid = threadIdx.x, wg = blockIdx.x;
  for (int b = tid; b < NB; b += BDIM)
    cur[b] = bbase[b] + off[(size_t)b * nWG + wg];
  __syncthreads();
  int base = wg * CH, lim = min(CH, TOT - base);
  for (int i = tid; i < lim; i += BDIM) {
    int e = base + i;
    int src, dst;
    if (e < E) { src = ei[e]; dst = ei[E + e]; }
    else       { src = dst = e - E; }
    int b = dst / bw;
    int pos = atomicAdd(&cur[b], 1);
    ebuf[pos] = ((unsigned int)(dst - b * bw) << 17) | (unsigned int)src;
  }
}

// Pass C: one WG per bucket. Build CSR segment fully in LDS; all global IO coalesced.
__launch_bounds__(BDIM) __global__
void csr_c(const unsigned int* __restrict__ ebuf, const int* __restrict__ bbase,
           int N, int bw,
           int* __restrict__ row_ptr, float* __restrict__ dis,
           int* __restrict__ csr_src) {
  __shared__ unsigned int eb[CAP];
  __shared__ unsigned int ob[CAP];
  __shared__ int cnt[128], loff[128], cur[128];
  int tid = threadIdx.x, b = blockIdx.x;
  int d0 = b * bw;
  if (d0 >= N) return;
  int width = min(bw, N - d0);
  int sbase = bbase[b];
  int send = bbase[b + 1];
  int nb = send - sbase;
  if (tid < 128) cnt[tid] = 0;
  __syncthreads();
  for (int i = tid; i < nb; i += BDIM) {
    unsigned int v = ebuf[sbase + i];
    eb[i] = v;
    atomicAdd(&cnt[v >> 17], 1);
  }
  __syncthreads();
  if (tid < 64) {  // wave 0: exclusive scan of 128 counters (2 per lane)
    int c0 = cnt[tid * 2], c1 = cnt[tid * 2 + 1];
    int s = c0 + c1;
    int incl = s;
#pragma unroll
    for (int o = 1; o < 64; o <<= 1) {
      int t = __shfl_up(incl, o, 64);
      if (tid >= o) incl += t;
    }
    int excl = incl - s;
    loff[tid * 2] = excl;
    loff[tid * 2 + 1] = excl + c0;
  }
  __syncthreads();
  if (tid < width) {
    row_ptr[d0 + tid] = sbase + loff[tid];
    dis[d0 + tid] = rsqrtf((float)cnt[tid]);  // deg >= 1 (self-loops)
    cur[tid] = loff[tid];
  }
  __syncthreads();
  for (int i = tid; i < nb; i += BDIM) {
    unsigned int v = eb[i];
    int p = atomicAdd(&cur[v >> 17], 1);
    ob[p] = v & 0x1FFFFu;
  }
  __syncthreads();
  for (int i = tid; i < nb; i += BDIM) csr_src[sbase + i] = (int)ob[i];
}

// ---------------------------------------------------------------- GCN gather
// Wide-load: 8 lanes per 128B row -> 8 edges per global_load_dwordx4 (1KB/inst).
// lane = (edge-slot grp = lane>>3, feature octet fb = (lane&7)*8).
// h pre-scaled by dis[src]; out = relu(dis[dst]*sum + b), fp16.
__launch_bounds__(BDIM) __global__
void gcn_gather(const __half* __restrict__ h, const int* __restrict__ row_ptr,
                const int* __restrict__ csr_src, const float* __restrict__ dis,
                const float* __restrict__ b, __half* __restrict__ out, int N) {
  int wid = blockIdx.x * (BDIM / 64) + (threadIdx.x >> 6);
  int lane = threadIdx.x & 63;
  if (wid >= N) return;
  int grp = lane >> 3;
  int fb = (lane & 7) * 8;
  int beg = row_ptr[wid], end = row_ptr[wid + 1];
  float acc[8];
#pragma unroll
  for (int k = 0; k < 8; ++k) acc[k] = 0.0f;
  for (int base = beg; base < end; base += 64) {
    int nch = min(64, end - base);
    int s_l = (lane < nch) ? csr_src[base + lane] : 0;
    for (int j = 0; j < nch; j += 8) {
      int idx = j + grp;  // j <= 56, idx <= 63
      int s = __shfl(s_l, idx, 64);
      float w = (idx < nch) ? 1.0f : 0.0f;
      v8h v = *(const v8h*)((const _Float16*)h + (size_t)s * 64 + fb);
#pragma unroll
      for (int k = 0; k < 8; ++k) acc[k] += w * (float)v[k];
    }
  }
#pragma unroll
  for (int o = 8; o < 64; o <<= 1)
#pragma unroll
    for (int k = 0; k < 8; ++k) acc[k] += __shfl_xor(acc[k], o, 64);
  if (lane < 8) {
    float dd = dis[wid];
    v8h ov;
#pragma unroll
    for (int k = 0; k < 8; ++k)
      ov[k] = (_Float16)fmaxf(acc[k] * dd + b[fb + k], 0.0f);
    *(v8h*)((_Float16*)out + (size_t)wid * 64 + fb) = ov;
  }
}

// ---------------------------------------------------------------- GAT (fused)
// Layer 1 (2 heads, 256B rows): 16 lanes/row -> 4 edges per load.
// grp = lane>>4 (edge slot), fb = (lane&15)*8 (combined-feature octet),
// hb = (lane&15)>>3 (head). Softmax phase unchanged; alphas shfl'd from regs.
__launch_bounds__(BDIM) __global__
void gat_fused2(const __half* __restrict__ h, const int* __restrict__ row_ptr,
                const int* __restrict__ csr_src, const float* __restrict__ al_s,
                const float* __restrict__ al_d, const float* __restrict__ b,
                __half* __restrict__ out, int N) {
  int wid = blockIdx.x * (BDIM / 64) + (threadIdx.x >> 6);
  int lane = threadIdx.x & 63;
  if (wid >= N) return;
  int grp = lane >> 4;
  int fb = (lane & 15) * 8;
  int hb = (lane & 15) >> 3;
  int beg = row_ptr[wid], end = row_ptr[wid + 1];
  int deg = end - beg;
  float ad0 = al_d[wid], ad1 = al_d[(size_t)N + wid];
  float acc[8];
#pragma unroll
  for (int k = 0; k < 8; ++k) acc[k] = 0.0f;
  float l0, l1;
  if (deg <= 64) {
    int s_l = (lane < deg) ? csr_src[beg + lane] : 0;
    float e0 = (lane < deg) ? leaky02(al_s[s_l] + ad0) : -3.4e38f;
    float e1 = (lane < deg) ? leaky02(al_s[(size_t)N + s_l] + ad1) : -3.4e38f;
    float m0 = wave_max64(e0), m1 = wave_max64(e1);
    float ex0 = (lane < deg) ? expf(e0 - m0) : 0.0f;
    float ex1 = (lane < deg) ? expf(e1 - m1) : 0.0f;
    l0 = wave_sum64(ex0);
    l1 = wave_sum64(ex1);
    for (int j = 0; j < deg; j += 4) {
      int idx = j + grp;  // j <= 60, idx <= 63; pad lanes carry ex=0, s=0
      int s = __shfl(s_l, idx, 64);
      float a0 = __shfl(ex0, idx, 64);
      float a1 = __shfl(ex1, idx, 64);
      float a = hb ? a1 : a0;
      v8h v = *(const v8h*)((const _Float16*)h + (size_t)s * 128 + fb);
#pragma unroll
      for (int k = 0; k < 8; ++k) acc[k] += a * (float)v[k];
    }
  } else {  // rare: two-pass recompute, chunked
    float m0 = -3.4e38f, m1 = -3.4e38f;
    for (int base = beg; base < end; base += 64) {
      int nch = min(64, end - base);
      int s = (lane < nch) ? csr_src[base + lane] : 0;
      float e0 = (lane < nch) ? leaky02(al_s[s] + ad0) : -3.4e38f;
      float e1 = (lane < nch) ? leaky02(al_s[(size_t)N + s] + ad1) : -3.4e38f;
      m0 = fmaxf(m0, wave_max64(e0));
      m1 = fmaxf(m1, wave_max64(e1));
    }
    l0 = l1 = 0.0f;
    for (int base = beg; base < end; base += 64) {
      int nch = min(64, end - base);
      int s_l = (lane < nch) ? csr_src[base + lane] : 0;
      float ex0 = 0.0f, ex1 = 0.0f;
      if (lane < nch) {
        ex0 = expf(leaky02(al_s[s_l] + ad0) - m0);
        ex1 = expf(leaky02(al_s[(size_t)N + s_l] + ad1) - m1);
      }
      l0 += wave_sum64(ex0);
      l1 += wave_sum64(ex1);
      for (int j = 0; j < nch; j += 4) {
        int idx = j + grp;
        int s = __shfl(s_l, idx, 64);
        float a0 = __shfl(ex0, idx, 64);
        float a1 = __shfl(ex1, idx, 64);
        float a = hb ? a1 : a0;
        v8h v = *(const v8h*)((const _Float16*)h + (size_t)s * 128 + fb);
#pragma unroll
        for (int k = 0; k < 8; ++k) acc[k] += a * (float)v[k];
      }
    }
  }
#pragma unroll
  for (int o = 16; o < 64; o <<= 1)
#pragma unroll
    for (int k = 0; k < 8; ++k) acc[k] += __shfl_xor(acc[k], o, 64);
  if (lane < 16) {
    float dn = hb ? l1 : l0;
    v8h ov;
#pragma unroll
    for (int k = 0; k < 8; ++k)
      ov[k] = (_Float16)fmaxf(acc[k] / dn + b[fb + k], 0.0f);  // relu fused
    *(v8h*)((_Float16*)out + (size_t)wid * 128 + fb) = ov;
  }
}

// Layer 2 fused (1 head, 128B rows): 8 lanes/row -> 8 edges per load; fp16 out.
__launch_bounds__(BDIM) __global__
void gat_fused1(const __half* __restrict__ h, const int* __restrict__ row_ptr,
                const int* __restrict__ csr_src, const float* __restrict__ al_s,
                const float* __restrict__ al_d, const float* __restrict__ b,
                __half* __restrict__ out, int N) {
  int wid = blockIdx.x * (BDIM / 64) + (threadIdx.x >> 6);
  int lane = threadIdx.x & 63;
  if (wid >= N) return;
  int grp = lane >> 3;
  int fb = (lane & 7) * 8;
  int beg = row_ptr[wid], end = row_ptr[wid + 1];
  int deg = end - beg;
  float ad = al_d[wid];
  float acc[8];
#pragma unroll
  for (int k = 0; k < 8; ++k) acc[k] = 0.0f;
  float l;
  if (deg <= 64) {
    int s_l = (lane < deg) ? csr_src[beg + lane] : 0;
    float e = (lane < deg) ? leaky02(al_s[s_l] + ad) : -3.4e38f;
    float m = wave_max64(e);
    float ex = (lane < deg) ? expf(e - m) : 0.0f;
    l = wave_sum64(ex);
    for (int j = 0; j < deg; j += 8) {
      int idx = j + grp;  // <= 63; pads: ex=0, s=0
      int s = __shfl(s_l, idx, 64);
      float a = __shfl(ex, idx, 64);
      v8h v = *(const v8h*)((const _Float16*)h + (size_t)s * 64 + fb);
#pragma unroll
      for (int k = 0; k < 8; ++k) acc[k] += a * (float)v[k];
    }
  } else {
    float m = -3.4e38f;
    for (int base = beg; base < end; base += 64) {
      int nch = min(64, end - base);
      int s = (lane < nch) ? csr_src[base + lane] : 0;
      float e = (lane < nch) ? leaky02(al_s[s] + ad) : -3.4e38f;
      m = fmaxf(m, wave_max64(e));
    }
    l = 0.0f;
    for (int base = beg; base < end; base += 64) {
      int nch = min(64, end - base);
      int s_l = (lane < nch) ? csr_src[base + lane] : 0;
      float ex = (lane < nch) ? expf(leaky02(al_s[s_l] + ad) - m) : 0.0f;
      l += wave_sum64(ex);
      for (int j = 0; j < nch; j += 8) {
        int idx = j + grp;
        int s = __shfl(s_l, idx, 64);
        float a = __shfl(ex, idx, 64);
        v8h v = *(const v8h*)((const _Float16*)h + (size_t)s * 64 + fb);
#pragma unroll
        for (int k = 0; k < 8; ++k) acc[k] += a * (float)v[k];
      }
    }
  }
#pragma unroll
  for (int o = 8; o < 64; o <<= 1)
#pragma unroll
    for (int k = 0; k < 8; ++k) acc[k] += __shfl_xor(acc[k], o, 64);
  if (lane < 8) {
    v8h ov;
#pragma unroll
    for (int k = 0; k < 8; ++k)
      ov[k] = (_Float16)(acc[k] / l + b[fb + k]);  // no relu on layer 2
    *(v8h*)((_Float16*)out + (size_t)wid * 64 + fb) = ov;
  }
}

// ---------------------------------------------------------------- pool + head
__device__ __forceinline__ int lower_bound(const int* __restrict__ a, int n, int v) {
  int lo = 0, hi = n;
  while (lo < hi) {
    int mid = (lo + hi) >> 1;
    if (a[mid] < v) lo = mid + 1; else hi = mid;
  }
  return lo;
}

// stage A: wave per (graph, slice): sum a contiguous slice of the graph's rows.
__launch_bounds__(BDIM) __global__
void pool_partial(const __half* __restrict__ x3, const int* __restrict__ batch,
                  float* __restrict__ part, int N, int G) {
  int wid = blockIdx.x * (BDIM / 64) + (threadIdx.x >> 6);
  int lane = threadIdx.x & 63;
  if (wid >= G * PS) return;
  int g = wid / PS, s = wid % PS;
  int beg = lower_bound(batch, N, g);
  int end = lower_bound(batch, N, g + 1);
  int len = end - beg;
  int lo = beg + (int)((long long)len * s / PS);
  int hi = beg + (int)((long long)len * (s + 1) / PS);
  float acc = 0.0f;
  int n = lo;
  for (; n + 4 <= hi; n += 4) {  // 4 independent line-loads in flight
    float a0 = __half2float(x3[(size_t)(n + 0) * 64 + lane]);
    float a1 = __half2float(x3[(size_t)(n + 1) * 64 + lane]);
    float a2 = __half2float(x3[(size_t)(n + 2) * 64 + lane]);
    float a3 = __half2float(x3[(size_t)(n + 3) * 64 + lane]);
    acc += (a0 + a1) + (a2 + a3);
  }
  for (; n < hi; ++n) acc += __half2float(x3[(size_t)n * 64 + lane]);
  part[(size_t)wid * 64 + lane] = acc;
}

// stage B: wave per graph: reduce PS partials, mean, FC, log_softmax.
__launch_bounds__(BDIM) __global__
void pool_head(const float* __restrict__ part, const int* __restrict__ batch,
               const float* __restrict__ Wfc, const float* __restrict__ bfc,
               float* __restrict__ out, int N, int G) {
  int wid = blockIdx.x * (BDIM / 64) + (threadIdx.x >> 6);
  int lane = threadIdx.x & 63;
  if (wid >= G) return;
  float acc = 0.0f;
#pragma unroll
  for (int s = 0; s < PS; ++s) acc += part[((size_t)wid * PS + s) * 64 + lane];
  int beg = lower_bound(batch, N, wid);
  int end = lower_bound(batch, N, wid + 1);
  float p = (end > beg) ? acc / (float)(end - beg) : 0.0f;
  float l0 = wave_sum64(p * Wfc[lane * 2 + 0]);
  float l1 = wave_sum64(p * Wfc[lane * 2 + 1]);
  if (lane == 0) {
    l0 += bfc[0];
    l1 += bfc[1];
    float m = fmaxf(l0, l1);
    float ls = m + logf(expf(l0 - m) + expf(l1 - m));
    out[wid * 2 + 0] = l0 - ls;
    out[wid * 2 + 1] = l1 - ls;
  }
}

// ---------------------------------------------------------------- launch

static inline int cdiv(int a, int b) { return (a + b - 1) / b; }

extern "C" void kernel_launch(void* const* d_in, const int* in_sizes, int n_in,
                              void* d_out, int out_size, void* d_ws, size_t ws_size,
                              hipStream_t stream) {
  const float* x      = (const float*)d_in[0];
  const int*   ei     = (const int*)d_in[1];
  const int*   batch  = (const int*)d_in[2];
  const float* W1     = (const float*)d_in[3];
  const float* b1     = (const float*)d_in[4];
  const float* W2     = (const float*)d_in[5];
  const float* a_src2 = (const float*)d_in[6];
  const float* a_dst2 = (const float*)d_in[7];
  const float* b2     = (const float*)d_in[8];
  const float* W3     = (const float*)d_in[9];
  const float* a_src3 = (const float*)d_in[10];
  const float* a_dst3 = (const float*)d_in[11];
  const float* b3     = (const float*)d_in[12];
  const float* Wfc    = (const float*)d_in[13];
  const float* bfc    = (const float*)d_in[14];
  float* out = (float*)d_out;

  const int N = in_sizes[2];       // 50000
  const int E = in_sizes[1] / 2;   // 800000
  const int G = out_size / 2;      // 512
  const int TOT = E + N;           // edges incl. self-loops
  const int bw  = cdiv(N, NB);     // dst-range per bucket (98)
  const int nWG = cdiv(TOT, CH);   // chunks (104)
  const int M   = NB * nWG;        // count-matrix size

  // workspace layout, fp16 buffers first (16B-aligned offsets)
  char* wsb = (char*)d_ws;
  __half* h1    = (__half*)wsb;                       // N*64 fp16
  __half* h2    = h1 + (size_t)N * 64;                // N*128 fp16 (reused as h3)
  __half* out1h = h2 + (size_t)N * 128;               // N*64 fp16 (x1)
  __half* out2h = out1h + (size_t)N * 64;             // N*128 fp16 (x2)
  __half* out3h = out2h + (size_t)N * 128;            // N*64 fp16 (x3)
  float*  dis   = (float*)(out3h + (size_t)N * 64);   // N
  float*  al_s  = dis + N;                            // N*2 planar
  float*  al_d  = al_s + (size_t)N * 2;               // N*2 planar
  float*  part  = al_d + (size_t)N * 2;               // G*PS*64
  int* counts   = (int*)(part + (size_t)G * PS * 64); // M
  int* off      = counts + M;                         // M
  int* btot     = off + M;                            // NB
  int* bbase    = btot + NB;                          // NB+1
  unsigned int* ebuf = (unsigned int*)(bbase + NB + 1);  // TOT
  int* csr_src  = (int*)(ebuf + TOT);                 // TOT
  int* row_ptr  = csr_src + TOT;                      // N+1

  // ---- CSR build: atomic-free radix bucketing, factored parallel scan
  hist_a<<<nWG, BDIM, 0, stream>>>(ei, E, TOT, bw, counts, nWG);
  scan_bucket<<<cdiv(NB, 4), BDIM, 0, stream>>>(counts, nWG, off, btot);
  scan_tot<<<1, 512, 0, stream>>>(btot, bbase, row_ptr, N, TOT);
  bucket_b<<<nWG, BDIM, 0, stream>>>(ei, E, TOT, bw, off, bbase, nWG, ebuf);
  csr_c<<<NB, BDIM, 0, stream>>>(ebuf, bbase, N, bw, row_ptr, dis, csr_src);

  // ---- GCN layer (h1 pre-scaled by dis[row] in GEMM epilogue)
  gemm_mfma<128, 64, true, 0, true><<<cdiv(N, 64), BDIM, 0, stream>>>(
      x, W1, (_Float16*)h1, dis, nullptr, nullptr, nullptr, nullptr, N);
  gcn_gather<<<cdiv(N, 4), BDIM, 0, stream>>>(h1, row_ptr, csr_src, dis, b1, out1h, N);

  // ---- GAT layer 1 (heads=2, concat; att_coef fused into GEMM epilogue,
  //      softmax fused into accumulate)
  gemm_mfma<64, 128, false, 2, false><<<cdiv(N, 64), BDIM, 0, stream>>>(
      out1h, W2, (_Float16*)h2, nullptr, a_src2, a_dst2, al_s, al_d, N);
  gat_fused2<<<cdiv(N, 4), BDIM, 0, stream>>>(h2, row_ptr, csr_src, al_s, al_d,
                                              b2, out2h, N);

  // ---- GAT layer 2 (heads=1, mean == identity)
  __half* h3 = h2;  // h2 dead after gat_fused2
  gemm_mfma<128, 64, false, 1, false><<<cdiv(N, 64), BDIM, 0, stream>>>(
      out2h, W3, (_Float16*)h3, nullptr, a_src3, a_dst3, al_s, al_d, N);
  gat_fused1<<<cdiv(N, 4), BDIM, 0, stream>>>(h3, row_ptr, csr_src, al_s, al_d,
                                              b3, out3h, N);

  // ---- global mean pool + fc + log_softmax (atomic-free; batch is sorted)
  pool_partial<<<cdiv(G * PS, 4), BDIM, 0, stream>>>(out3h, batch, part, N, G);
  pool_head<<<cdiv(G, 4), BDIM, 0, stream>>>(part, batch, Wfc, bfc, out, N, G);
}